// Round 1
// 592.394 us; speedup vs baseline: 1.0528x; 1.0528x over previous
//
#include <hip/hip_runtime.h>

// Hetero-GNN: 5 layers of relu(segsum_temp(x)@Wt + segmean_inter(x)@Wi + x@Wr + b)
// (aggregation commuted past the matmuls).
//
// R10 (on top of R9's dense-CSR build + split gather/GEMM):
//  - k_scatter: two-pass re-read (no per-edge register arrays -> no scratch
//    spill), payload packed to one int (src<<7 | dst&127) -> ebuf halves,
//    512-thread blocks x EPT=32 (16384 edges/block, 196 blocks) -> per-bucket
//    chunks ~21 edges -> write amp ~1.3x (was 4x / 101 MB).
//  - k_fill3: reads packed int ebuf (half the fetch).
//  - k_gemm_blk / k_gemm_last: split each node across TWO WAVES (wave parity
//    selects the output-channel half; readfirstlane keeps the weight base
//    SGPR-uniform so weight reads stay scalar loads). acc[64] -> acc[32]
//    (last) kills the scratch spill (VGPR_Count was 56 < 64 accs); wave count
//    doubles -> latency hiding.

#define VO 8192    // overflow list capacity (pairs), temp relation
#define EPT 32     // edges per thread in k_scatter (512 thr -> 16384/block)
#define FCAP 10240 // staged edges per bucket in k_fill3 (40 KB LDS)

typedef float vf4 __attribute__((ext_vector_type(4)));

__device__ inline void f4add(float4& a, const float4& v) {
    a.x += v.x; a.y += v.y; a.z += v.z; a.w += v.w;
}

// ---------------- build: hist -> scan -> scatter -> dense fill ----------------

__global__ void k_hist(const int* __restrict__ dst, int E, int* __restrict__ gh,
                       int NB, int shift) {
    __shared__ int sh[1024];
    for (int j = threadIdx.x; j < NB; j += blockDim.x) sh[j] = 0;
    __syncthreads();
    for (int i = blockIdx.x * blockDim.x + threadIdx.x; i < E; i += gridDim.x * blockDim.x)
        atomicAdd(&sh[dst[i] >> shift], 1);
    __syncthreads();
    for (int j = threadIdx.x; j < NB; j += blockDim.x)
        if (sh[j]) atomicAdd(&gh[j], sh[j]);
}

__global__ void k_scan_b(const int* __restrict__ gh, int NB, int* __restrict__ boff,
                         int* __restrict__ cur) {
    __shared__ int sh[1024];
    int t = threadIdx.x;
    sh[t] = (t < NB) ? gh[t] : 0;
    __syncthreads();
    for (int off = 1; off < 1024; off <<= 1) {
        int v = (t >= off) ? sh[t - off] : 0;
        __syncthreads();
        sh[t] += v;
        __syncthreads();
    }
    if (t < NB) {
        int ex = t ? sh[t - 1] : 0;
        boff[t] = ex;
        cur[t] = ex;
    }
    if (t == 0) boff[NB] = sh[NB - 1];
}

// two-pass scatter: pass A counts into LDS hist, allocate bucket bases from
// global cur, pass B re-reads edges and places packed (src<<shift | dst&mask).
// No per-edge register state -> no scratch; reads are coalesced twice.
__global__ __launch_bounds__(512) void k_scatter(const int* __restrict__ src,
                                                 const int* __restrict__ dst, int E,
                                                 int shift, int NB, int* __restrict__ cur,
                                                 int* __restrict__ ebuf) {
    __shared__ int lh[1024];
    __shared__ int lb[1024];
    int span = blockDim.x * EPT;
    int lo = blockIdx.x * span;
    int hi = min(E, lo + span);
    for (int j = threadIdx.x; j < NB; j += blockDim.x) lh[j] = 0;
    __syncthreads();
    // pass A: count
    for (int e = lo + threadIdx.x; e < hi; e += blockDim.x)
        atomicAdd(&lh[dst[e] >> shift], 1);
    __syncthreads();
    // allocate global bases per bucket
    for (int j = threadIdx.x; j < NB; j += blockDim.x) {
        int c = lh[j];
        lb[j] = c ? atomicAdd(&cur[j], c) : 0;
    }
    __syncthreads();
    // pass B: re-read + place
    int mask = (1 << shift) - 1;
    for (int e = lo + threadIdx.x; e < hi; e += blockDim.x) {
        int s = src[e];
        int d = dst[e];
        int pos = atomicAdd(&lb[d >> shift], 1);
        ebuf[pos] = (s << shift) | (d & mask);
    }
}

// dense CSR fill: one block per 128-node bucket. Two streaming passes over the
// bucket's packed ebuf segment; LDS staging -> coalesced full-line csr writes.
__global__ __launch_bounds__(256) void k_fill3(const int* __restrict__ ebuf,
                                               const int* __restrict__ boff, int NB,
                                               int* __restrict__ rs, int* __restrict__ csr,
                                               int N) {
    __shared__ int hist[128];
    __shared__ int offs[129];
    __shared__ int curl[128];
    __shared__ int stage[FCAP];
    int b = blockIdx.x;
    if (b >= NB) return;
    int lo = boff[b], hi = boff[b + 1];
    int cnt = hi - lo;
    int base = b << 7;
    int t = threadIdx.x;
    for (int i = t; i < 128; i += 256) { hist[i] = 0; curl[i] = 0; }
    __syncthreads();
    // pass 1: count
    for (int e = lo + t; e < hi; e += 256) {
        int v = ebuf[e];
        atomicAdd(&hist[v & 127], 1);
    }
    __syncthreads();
    if (t == 0) {
        int run = 0;
        for (int i = 0; i < 128; ++i) { offs[i] = run; run += hist[i]; }
        offs[128] = run;
    }
    __syncthreads();
    // rs offsets (exact; dst < N so nodes >= N have count 0)
    for (int i = t; i < 128; i += 256) {
        int g = base + i;
        if (g < N) rs[g] = lo + offs[i];
    }
    if (b == NB - 1 && t == 0) rs[N] = hi;
    // pass 2: place
    bool staged = (cnt <= FCAP);
    for (int e = lo + t; e < hi; e += 256) {
        int v = ebuf[e];
        int dl = v & 127;
        int sidx = (int)(((unsigned)v) >> 7);
        int p = offs[dl] + atomicAdd(&curl[dl], 1);
        if (staged) stage[p] = sidx;
        else csr[lo + p] = sidx;
    }
    __syncthreads();
    if (staged)
        for (int i = t; i < cnt; i += 256) csr[lo + i] = stage[i];
}

// temp relation (100k edges): padded one-pass fill
__global__ void k_fill2(const int* __restrict__ src, const int* __restrict__ dst, int E,
                        int* __restrict__ cnt, int* __restrict__ csr, int C,
                        int* __restrict__ ovf, int* __restrict__ ovf_n) {
    int i = blockIdx.x * blockDim.x + threadIdx.x;
    if (i >= E) return;
    int s = src[i];
    int d = dst[i];
    int slot = atomicAdd(&cnt[d], 1);
    if (slot < C) {
        csr[(size_t)d * C + slot] = s;
    } else {
        int p = atomicAdd(ovf_n, 1);
        if (p < VO) { ovf[2 * p] = d; ovf[2 * p + 1] = s; }
    }
}

__global__ void k_pad_x(const float* __restrict__ x, float* __restrict__ x8, int N) {
    int i = blockIdx.x * blockDim.x + threadIdx.x;
    if (i >= N * 8) return;
    int n = i >> 3, c = i & 7;
    x8[i] = (c < 6) ? x[n * 6 + c] : 0.0f;
}

// ---------------- gathers ----------------

template <int CHV, int U, bool MASK>
__device__ inline void g_grp(const float* __restrict__ x, int sv, int it0, int nb,
                             int q, int r, float4& acc) {
    const int R = 64 / CHV;
    int s[U];
    float4 v[U];
#pragma unroll
    for (int u = 0; u < U; ++u) s[u] = __shfl(sv, (it0 + u) * R + r, 64);
#pragma unroll
    for (int u = 0; u < U; ++u) v[u] = *(const float4*)(x + (size_t)s[u] * (CHV * 4) + q * 4);
#pragma unroll
    for (int u = 0; u < U; ++u) {
        if (MASK) {
            float m = ((it0 + u) * R + r < nb) ? 1.0f : 0.0f;
            acc.x = fmaf(m, v[u].x, acc.x);
            acc.y = fmaf(m, v[u].y, acc.y);
            acc.z = fmaf(m, v[u].z, acc.z);
            acc.w = fmaf(m, v[u].w, acc.w);
        } else {
            f4add(acc, v[u]);
        }
    }
}

template <int CHV, int U>
__device__ inline float4 gather_one(const float* __restrict__ x, const int* __restrict__ csr,
                                    size_t rowbase, int cnt_c, int lane, int q, int r) {
    const int R = 64 / CHV;
    float4 acc = make_float4(0.f, 0.f, 0.f, 0.f);
    for (int base = 0; base < cnt_c; base += 64) {
        int nb = min(64, cnt_c - base);
        int sv = (lane < nb) ? csr[rowbase + base + lane] : 0;
        int it = 0;
        while ((it + U) * R <= nb) {
            g_grp<CHV, U, false>(x, sv, it, nb, q, r, acc);
            it += U;
        }
        if (it * R < nb) g_grp<CHV, U, true>(x, sv, it, nb, q, r, acc);
    }
    return acc;
}

// 32-ch asm gather: 4 row loads in flight, ONE vmcnt(0).
__device__ inline float4 gather_asm4(const float* __restrict__ x, const int* __restrict__ csr,
                                     size_t rowbase, int cnt_c, int lane, int q, int r) {
    float4 acc = make_float4(0.f, 0.f, 0.f, 0.f);
    for (int base = 0; base < cnt_c; base += 64) {
        int nb = min(64, cnt_c - base);
        int sv = (lane < nb) ? csr[rowbase + base + lane] : 0;
        for (int it = 0; it * 8 < nb; it += 4) {
            int s0 = __shfl(sv, (it + 0) * 8 + r, 64);
            int s1 = __shfl(sv, (it + 1) * 8 + r, 64);
            int s2 = __shfl(sv, (it + 2) * 8 + r, 64);
            int s3 = __shfl(sv, (it + 3) * 8 + r, 64);
            const float* a0 = x + (size_t)s0 * 32 + q * 4;
            const float* a1 = x + (size_t)s1 * 32 + q * 4;
            const float* a2 = x + (size_t)s2 * 32 + q * 4;
            const float* a3 = x + (size_t)s3 * 32 + q * 4;
            vf4 v0, v1, v2, v3;
            asm volatile(
                "global_load_dwordx4 %0, %4, off\n\t"
                "global_load_dwordx4 %1, %5, off\n\t"
                "global_load_dwordx4 %2, %6, off\n\t"
                "global_load_dwordx4 %3, %7, off\n\t"
                "s_waitcnt vmcnt(0)"
                : "=&v"(v0), "=&v"(v1), "=&v"(v2), "=&v"(v3)
                : "v"(a0), "v"(a1), "v"(a2), "v"(a3)
                : "memory");
            if ((it + 4) * 8 <= nb) {
                acc.x += v0.x + v1.x + v2.x + v3.x;
                acc.y += v0.y + v1.y + v2.y + v3.y;
                acc.z += v0.z + v1.z + v2.z + v3.z;
                acc.w += v0.w + v1.w + v2.w + v3.w;
            } else {
                float m0 = ((it + 0) * 8 + r < nb) ? 1.0f : 0.0f;
                float m1 = ((it + 1) * 8 + r < nb) ? 1.0f : 0.0f;
                float m2 = ((it + 2) * 8 + r < nb) ? 1.0f : 0.0f;
                float m3 = ((it + 3) * 8 + r < nb) ? 1.0f : 0.0f;
                acc.x = fmaf(m0, v0.x, fmaf(m1, v1.x, fmaf(m2, v2.x, fmaf(m3, v3.x, acc.x))));
                acc.y = fmaf(m0, v0.y, fmaf(m1, v1.y, fmaf(m2, v2.y, fmaf(m3, v3.y, acc.y))));
                acc.z = fmaf(m0, v0.z, fmaf(m1, v1.z, fmaf(m2, v2.z, fmaf(m3, v3.z, acc.z))));
                acc.w = fmaf(m0, v0.w, fmaf(m1, v1.w, fmaf(m2, v2.w, fmaf(m3, v3.w, acc.w))));
            }
        }
    }
    return acc;
}

__device__ inline float4 gather_asm1(const float* __restrict__ x, const int* __restrict__ csr,
                                     size_t rowbase, int cnt_c, int lane, int q, int r) {
    float4 acc = make_float4(0.f, 0.f, 0.f, 0.f);
    for (int base = 0; base < cnt_c; base += 64) {
        int nb = min(64, cnt_c - base);
        int sv = (lane < nb) ? csr[rowbase + base + lane] : 0;
        for (int it = 0; it * 8 < nb; ++it) {
            int s0 = __shfl(sv, it * 8 + r, 64);
            const float* a0 = x + (size_t)s0 * 32 + q * 4;
            vf4 v0;
            asm volatile(
                "global_load_dwordx4 %0, %1, off\n\t"
                "s_waitcnt vmcnt(0)"
                : "=&v"(v0)
                : "v"(a0)
                : "memory");
            float m0 = (it * 8 + r < nb) ? 1.0f : 0.0f;
            acc.x = fmaf(m0, v0.x, acc.x);
            acc.y = fmaf(m0, v0.y, acc.y);
            acc.z = fmaf(m0, v0.z, acc.z);
            acc.w = fmaf(m0, v0.w, acc.w);
        }
    }
    return acc;
}

template <int CHV>
__device__ inline void ovf_add(const float* __restrict__ x, const int* __restrict__ ovf, int n,
                               int g, int q, int r, float4& acc) {
    for (int j = 0; j < n; ++j) {
        int d = ovf[2 * j];
        if (d == g) {
            int s = ovf[2 * j + 1];
            if (r == 0) f4add(acc, *(const float4*)(x + (size_t)s * (CHV * 4) + q * 4));
        }
    }
}

template <int CHV>
__device__ inline void reduce4(float4& a) {
#pragma unroll
    for (int st = CHV; st < 64; st <<= 1) {
        a.x += __shfl_xor(a.x, st, 64);
        a.y += __shfl_xor(a.y, st, 64);
        a.z += __shfl_xor(a.z, st, 64);
        a.w += __shfl_xor(a.w, st, 64);
    }
}

// head gather: 8ch padded rows -> agg8[n][16] = [aggi*inv | aggt]
__global__ __launch_bounds__(256) void k_gather_head(
    const float* __restrict__ x8, const int* __restrict__ csr_i, const int* __restrict__ rs,
    const int* __restrict__ csr_t, const int* __restrict__ cnt_t, int Ct,
    const int* __restrict__ ovf_t, const int* __restrict__ ovfn,
    float* __restrict__ agg8, int N) {
    int tid = blockIdx.x * blockDim.x + threadIdx.x;
    int g = tid >> 6;
    if (g >= N) return;
    int lane = threadIdx.x & 63;
    int q = lane & 1, r = lane >> 1;
    int e0 = rs[g], e1 = rs[g + 1];
    int cif = e1 - e0;
    int ctf = cnt_t[g], ct = min(ctf, Ct);
    float4 ai = gather_one<2, 2>(x8, csr_i, (size_t)e0, cif, lane, q, r);
    float4 at = gather_one<2, 1>(x8, csr_t, (size_t)g * Ct, ct, lane, q, r);
    if (ctf > Ct) ovf_add<2>(x8, ovf_t, min(ovfn[1], VO), g, q, r, at);
    reduce4<2>(ai);
    reduce4<2>(at);
    float inv = 1.0f / (float)max(cif, 1);
    if (r == 0) {
        *(float4*)(agg8 + (size_t)g * 16 + q * 4) =
            make_float4(ai.x * inv, ai.y * inv, ai.z * inv, ai.w * inv);
    } else if (r == 1) {
        *(float4*)(agg8 + (size_t)g * 16 + 8 + q * 4) = at;
    }
}

// hidden gather: 32ch rows -> agg[n][64] = [aggi*inv | aggt]
__global__ __launch_bounds__(256) void k_gather32(
    const float* __restrict__ hin, const int* __restrict__ csr_i, const int* __restrict__ rs,
    const int* __restrict__ csr_t, const int* __restrict__ cnt_t, int Ct,
    const int* __restrict__ ovf_t, const int* __restrict__ ovfn,
    float* __restrict__ agg, int N) {
    int tid = blockIdx.x * blockDim.x + threadIdx.x;
    int g = tid >> 6;
    if (g >= N) return;
    int lane = threadIdx.x & 63;
    int q = lane & 7, r = lane >> 3;
    int e0 = rs[g], e1 = rs[g + 1];
    int cif = e1 - e0;
    int ctf = cnt_t[g], ct = min(ctf, Ct);
    float4 ai = gather_asm4(hin, csr_i, (size_t)e0, cif, lane, q, r);
    float4 at = gather_asm1(hin, csr_t, (size_t)g * Ct, ct, lane, q, r);
    if (ctf > Ct) ovf_add<8>(hin, ovf_t, min(ovfn[1], VO), g, q, r, at);
    reduce4<8>(ai);
    reduce4<8>(at);
    float inv = 1.0f / (float)max(cif, 1);
    if (r == 0) {
        *(float4*)(agg + (size_t)g * 64 + q * 4) =
            make_float4(ai.x * inv, ai.y * inv, ai.z * inv, ai.w * inv);
    } else if (r == 1) {
        *(float4*)(agg + (size_t)g * 64 + 32 + q * 4) = at;
    }
}

// ---------------- per-node GEMM kernels (weights wave-uniform) ----------------

// seg: 32 input channels; OC outputs with row stride STR (W column offset
// already applied by caller). Weights stay SGPR-loaded (W wave-uniform).
template <int OC, int STR>
__device__ inline void gemm_seg2(const float* __restrict__ seg, const float* __restrict__ W,
                                 float* acc) {
#pragma unroll 2
    for (int k4 = 0; k4 < 8; ++k4) {
        float4 a = ((const float4*)seg)[k4];
        float av[4] = {a.x, a.y, a.z, a.w};
#pragma unroll
        for (int i = 0; i < 4; ++i) {
            const float* Wk = W + (k4 * 4 + i) * STR;
#pragma unroll
            for (int c = 0; c < OC; ++c) acc[c] = fmaf(av[i], Wk[c], acc[c]);
        }
    }
}

__global__ __launch_bounds__(256) void k_gemm_head(
    const float* __restrict__ agg8, const float* __restrict__ x8,
    const float* __restrict__ Wt, const float* __restrict__ Wi, const float* __restrict__ Wr,
    const float* __restrict__ b, float* __restrict__ hout, int N) {
    int n = blockIdx.x * blockDim.x + threadIdx.x;
    if (n >= N) return;
    float acc[32];
#pragma unroll
    for (int c = 0; c < 32; ++c) acc[c] = b[c];
    float4 ai0 = ((const float4*)(agg8 + (size_t)n * 16))[0];
    float4 ai1 = ((const float4*)(agg8 + (size_t)n * 16))[1];
    float4 at0 = ((const float4*)(agg8 + (size_t)n * 16 + 8))[0];
    float4 at1 = ((const float4*)(agg8 + (size_t)n * 16 + 8))[1];
    float4 xv0 = ((const float4*)(x8 + (size_t)n * 8))[0];
    float4 xv1 = ((const float4*)(x8 + (size_t)n * 8))[1];
    float a_i[6] = {ai0.x, ai0.y, ai0.z, ai0.w, ai1.x, ai1.y};
    float a_t[6] = {at0.x, at0.y, at0.z, at0.w, at1.x, at1.y};
    float a_x[6] = {xv0.x, xv0.y, xv0.z, xv0.w, xv1.x, xv1.y};
#pragma unroll
    for (int k = 0; k < 6; ++k) {
        const float* Wtk = Wt + k * 32;
        const float* Wik = Wi + k * 32;
        const float* Wrk = Wr + k * 32;
#pragma unroll
        for (int c = 0; c < 32; ++c)
            acc[c] = fmaf(a_t[k], Wtk[c], fmaf(a_i[k], Wik[c], fmaf(a_x[k], Wrk[c], acc[c])));
    }
    float* O = hout + (size_t)n * 32;
#pragma unroll
    for (int c4 = 0; c4 < 8; ++c4)
        ((float4*)O)[c4] = make_float4(fmaxf(acc[c4 * 4 + 0], 0.f), fmaxf(acc[c4 * 4 + 1], 0.f),
                                       fmaxf(acc[c4 * 4 + 2], 0.f), fmaxf(acc[c4 * 4 + 3], 0.f));
}

// wave-pair split: wave parity selects output-channel half (co SGPR-uniform),
// node n = 64*(wavepair) + lane. acc[16] -> no spill, 2x waves in flight.
__global__ __launch_bounds__(256) void k_gemm_blk(
    const float* __restrict__ agg, const float* __restrict__ hin,
    const float* __restrict__ Wt, const float* __restrict__ Wi, const float* __restrict__ Wr,
    const float* __restrict__ b, float* __restrict__ hout, int N) {
    int tid = blockIdx.x * blockDim.x + threadIdx.x;
    int lane = tid & 63;
    int n = ((tid >> 7) << 6) + lane;
    if (n >= N) return;
    int co = __builtin_amdgcn_readfirstlane(((tid >> 6) & 1) << 4);
    float acc[16];
#pragma unroll
    for (int c = 0; c < 16; ++c) acc[c] = b[co + c];
    const float* Ai = agg + (size_t)n * 64;
    const float* At = Ai + 32;
    const float* H = hin + (size_t)n * 32;
    gemm_seg2<16, 32>(At, Wt + co, acc);
    gemm_seg2<16, 32>(Ai, Wi + co, acc);
    gemm_seg2<16, 32>(H, Wr + co, acc);
    float* O = hout + (size_t)n * 32 + co;
    const float* Hc = H + co;
#pragma unroll
    for (int c4 = 0; c4 < 4; ++c4) {
        float4 hv = ((const float4*)Hc)[c4];
        ((float4*)O)[c4] = make_float4(fmaxf(acc[c4 * 4 + 0], 0.f) + hv.x,
                                       fmaxf(acc[c4 * 4 + 1], 0.f) + hv.y,
                                       fmaxf(acc[c4 * 4 + 2], 0.f) + hv.z,
                                       fmaxf(acc[c4 * 4 + 3], 0.f) + hv.w);
    }
}

__global__ __launch_bounds__(256) void k_gemm_last(
    const float* __restrict__ agg, const float* __restrict__ hin,
    const float* __restrict__ Wt, const float* __restrict__ Wi, const float* __restrict__ Wr,
    const float* __restrict__ b, const float* __restrict__ proj, float* __restrict__ out, int N) {
    int tid = blockIdx.x * blockDim.x + threadIdx.x;
    int lane = tid & 63;
    int n = ((tid >> 7) << 6) + lane;
    if (n >= N) return;
    int co = __builtin_amdgcn_readfirstlane(((tid >> 6) & 1) << 5);
    float acc[32];
#pragma unroll
    for (int c = 0; c < 32; ++c) acc[c] = b[co + c];
    const float* Ai = agg + (size_t)n * 64;
    const float* At = Ai + 32;
    const float* H = hin + (size_t)n * 32;
    gemm_seg2<32, 64>(At, Wt + co, acc);
    gemm_seg2<32, 64>(Ai, Wi + co, acc);
    gemm_seg2<32, 64>(H, Wr + co, acc);
#pragma unroll
    for (int c = 0; c < 32; ++c) acc[c] = fmaxf(acc[c], 0.f);
    gemm_seg2<32, 64>(H, proj + co, acc);
    float* O = out + (size_t)n * 64 + co;
#pragma unroll
    for (int c4 = 0; c4 < 8; ++c4)
        ((float4*)O)[c4] = make_float4(acc[c4 * 4 + 0], acc[c4 * 4 + 1],
                                       acc[c4 * 4 + 2], acc[c4 * 4 + 3]);
}

// ---------------- launch ----------------

static inline size_t align256(size_t x) { return (x + 255) & ~(size_t)255; }

extern "C" void kernel_launch(void* const* d_in, const int* in_sizes, int n_in,
                              void* d_out, int out_size, void* d_ws, size_t ws_size,
                              hipStream_t stream) {
    const float* x_stroke = (const float*)d_in[0];
    const int* ei_temp = (const int*)d_in[1];
    const int* ei_inter = (const int*)d_in[2];
    const float* head_Wt = (const float*)d_in[3];
    const float* head_Wi = (const float*)d_in[4];
    const float* head_Wr = (const float*)d_in[5];
    const float* head_b = (const float*)d_in[6];
    const float* blk_Wt = (const float*)d_in[7];
    const float* blk_Wi = (const float*)d_in[8];
    const float* blk_Wr = (const float*)d_in[9];
    const float* blk_b = (const float*)d_in[10];
    const float* last_Wt = (const float*)d_in[11];
    const float* last_Wi = (const float*)d_in[12];
    const float* last_Wr = (const float*)d_in[13];
    const float* last_b = (const float*)d_in[14];
    const float* last_proj = (const float*)d_in[15];

    const int N = in_sizes[0] / 6;
    const int Et = in_sizes[1] / 2;
    const int Ei = in_sizes[2] / 2;

    const int* temp_src = ei_temp;
    const int* temp_dst = ei_temp + Et;
    const int* int_src = ei_inter;
    const int* int_dst = ei_inter + Ei;

    const int shift = 7;                      // 128-node buckets
    const int NB = ((N - 1) >> shift) + 1;    // assumes N <= 131072

    char* p = (char*)d_ws;
    size_t off = 0;
    auto carve = [&](size_t bytes) {
        char* r = p + off;
        off = align256(off + bytes);
        return r;
    };
    int* cnt_t = (int*)carve((size_t)N * 4);
    int* ovfn = (int*)carve(2 * 4);
    int* ovf_t = (int*)carve((size_t)VO * 8);
    int* gh = (int*)carve((size_t)NB * 4);
    int* boff = (int*)carve((size_t)(NB + 1) * 4);
    int* cur = (int*)carve((size_t)NB * 4);
    int* rs = (int*)carve((size_t)(N + 1) * 4);
    float* x8 = (float*)carve((size_t)N * 8 * 4);
    float* bufA = (float*)carve((size_t)N * 32 * 4);
    float* bufD = (float*)carve((size_t)N * 32 * 4);
    float* agg = (float*)carve((size_t)N * 64 * 4);   // also holds agg8 [N,16]
    int* ebuf = (int*)carve((size_t)Ei * 4);          // packed (src<<7 | dst&127)
    int* csr_i = (int*)carve((size_t)Ei * 4);         // dense
    const int Ct = 16;
    int* csr_t = (int*)carve((size_t)N * Ct * 4);
    (void)ws_size;

    const int B = 256;
    auto blocks = [&](long long work) { return (int)((work + B - 1) / B); };

    hipMemsetAsync(cnt_t, 0, (size_t)N * 4, stream);
    hipMemsetAsync(ovfn, 0, 2 * 4, stream);
    hipMemsetAsync(gh, 0, (size_t)NB * 4, stream);

    k_hist<<<256, B, 0, stream>>>(int_dst, Ei, gh, NB, shift);
    k_scan_b<<<1, 1024, 0, stream>>>(gh, NB, boff, cur);
    const int SB = 512;
    const long long sspan = (long long)SB * EPT;
    k_scatter<<<(int)((Ei + sspan - 1) / sspan), SB, 0, stream>>>(int_src, int_dst, Ei,
                                                                  shift, NB, cur, ebuf);
    k_fill3<<<NB, B, 0, stream>>>(ebuf, boff, NB, rs, csr_i, N);
    k_fill2<<<blocks(Et), B, 0, stream>>>(temp_src, temp_dst, Et, cnt_t, csr_t, Ct, ovf_t, &ovfn[1]);
    k_pad_x<<<blocks((long long)N * 8), B, 0, stream>>>(x_stroke, x8, N);

    // head
    k_gather_head<<<blocks((long long)N * 64), B, 0, stream>>>(
        x8, csr_i, rs, csr_t, cnt_t, Ct, ovf_t, ovfn, agg, N);
    k_gemm_head<<<blocks(N), B, 0, stream>>>(agg, x8, head_Wt, head_Wi, head_Wr, head_b, bufA, N);

    // split-GEMM grid: 2 waves per 64 nodes
    const int gw = 2 * ((N + 63) >> 6);
    const int gblocks = ((gw << 6) + B - 1) / B;

    // 3 hidden residual blocks
    float* hin = bufA;
    float* hout = bufD;
    for (int i = 0; i < 3; ++i) {
        k_gather32<<<blocks((long long)N * 64), B, 0, stream>>>(
            hin, csr_i, rs, csr_t, cnt_t, Ct, ovf_t, ovfn, agg, N);
        k_gemm_blk<<<gblocks, B, 0, stream>>>(
            agg, hin, blk_Wt + (size_t)i * 32 * 32, blk_Wi + (size_t)i * 32 * 32,
            blk_Wr + (size_t)i * 32 * 32, blk_b + (size_t)i * 32, hout, N);
        float* t = hin; hin = hout; hout = t;
    }

    // last
    k_gather32<<<blocks((long long)N * 64), B, 0, stream>>>(
        hin, csr_i, rs, csr_t, cnt_t, Ct, ovf_t, ovfn, agg, N);
    k_gemm_last<<<gblocks, B, 0, stream>>>(agg, hin, last_Wt, last_Wi, last_Wr, last_b,
                                           last_proj, (float*)d_out, N);
}

// Round 2
// 589.125 us; speedup vs baseline: 1.0587x; 1.0055x over previous
//
#include <hip/hip_runtime.h>

// Hetero-GNN: 5 layers of relu(segsum_temp(x)@Wt + segmean_inter(x)@Wi + x@Wr + b)
// (aggregation commuted past the matmuls).
//
// R11 (on top of R10):
//  - k_scatter: EPT 32 -> 16 (391 blocks instead of 196). Counters showed
//    occupancy 10-14%, VALU 2%, HBM 14% -> pure latency starvation with <1
//    block/CU. Doubling the grid doubles resident waves; per-bucket chunk
//    drops 21 -> ~10.5 edges (write amp +~10%, acceptable: writes are only
//    ~7 us of BW).
//  - k_fill3: thread-0 serial 128-scan -> 128-thread Hillis-Steele LDS scan.

#define VO 8192    // overflow list capacity (pairs), temp relation
#define EPT 16     // edges per thread in k_scatter (512 thr -> 8192/block)
#define FCAP 10240 // staged edges per bucket in k_fill3 (40 KB LDS)

typedef float vf4 __attribute__((ext_vector_type(4)));

__device__ inline void f4add(float4& a, const float4& v) {
    a.x += v.x; a.y += v.y; a.z += v.z; a.w += v.w;
}

// ---------------- build: hist -> scan -> scatter -> dense fill ----------------

__global__ void k_hist(const int* __restrict__ dst, int E, int* __restrict__ gh,
                       int NB, int shift) {
    __shared__ int sh[1024];
    for (int j = threadIdx.x; j < NB; j += blockDim.x) sh[j] = 0;
    __syncthreads();
    for (int i = blockIdx.x * blockDim.x + threadIdx.x; i < E; i += gridDim.x * blockDim.x)
        atomicAdd(&sh[dst[i] >> shift], 1);
    __syncthreads();
    for (int j = threadIdx.x; j < NB; j += blockDim.x)
        if (sh[j]) atomicAdd(&gh[j], sh[j]);
}

__global__ void k_scan_b(const int* __restrict__ gh, int NB, int* __restrict__ boff,
                         int* __restrict__ cur) {
    __shared__ int sh[1024];
    int t = threadIdx.x;
    sh[t] = (t < NB) ? gh[t] : 0;
    __syncthreads();
    for (int off = 1; off < 1024; off <<= 1) {
        int v = (t >= off) ? sh[t - off] : 0;
        __syncthreads();
        sh[t] += v;
        __syncthreads();
    }
    if (t < NB) {
        int ex = t ? sh[t - 1] : 0;
        boff[t] = ex;
        cur[t] = ex;
    }
    if (t == 0) boff[NB] = sh[NB - 1];
}

// two-pass scatter: pass A counts into LDS hist, allocate bucket bases from
// global cur, pass B re-reads edges and places packed (src<<shift | dst&mask).
// No per-edge register state -> no scratch; reads are coalesced twice (pass-B
// re-read hits L2: each block's chunk is 64 KB).
__global__ __launch_bounds__(512) void k_scatter(const int* __restrict__ src,
                                                 const int* __restrict__ dst, int E,
                                                 int shift, int NB, int* __restrict__ cur,
                                                 int* __restrict__ ebuf) {
    __shared__ int lh[1024];
    __shared__ int lb[1024];
    int span = blockDim.x * EPT;
    int lo = blockIdx.x * span;
    int hi = min(E, lo + span);
    for (int j = threadIdx.x; j < NB; j += blockDim.x) lh[j] = 0;
    __syncthreads();
    // pass A: count
    for (int e = lo + threadIdx.x; e < hi; e += blockDim.x)
        atomicAdd(&lh[dst[e] >> shift], 1);
    __syncthreads();
    // allocate global bases per bucket
    for (int j = threadIdx.x; j < NB; j += blockDim.x) {
        int c = lh[j];
        lb[j] = c ? atomicAdd(&cur[j], c) : 0;
    }
    __syncthreads();
    // pass B: re-read + place
    int mask = (1 << shift) - 1;
    for (int e = lo + threadIdx.x; e < hi; e += blockDim.x) {
        int s = src[e];
        int d = dst[e];
        int pos = atomicAdd(&lb[d >> shift], 1);
        ebuf[pos] = (s << shift) | (d & mask);
    }
}

// dense CSR fill: one block per 128-node bucket. Two streaming passes over the
// bucket's packed ebuf segment; LDS staging -> coalesced full-line csr writes.
__global__ __launch_bounds__(256) void k_fill3(const int* __restrict__ ebuf,
                                               const int* __restrict__ boff, int NB,
                                               int* __restrict__ rs, int* __restrict__ csr,
                                               int N) {
    __shared__ int hist[128];
    __shared__ int offs[129];
    __shared__ int curl[128];
    __shared__ int scn[128];
    __shared__ int stage[FCAP];
    int b = blockIdx.x;
    if (b >= NB) return;
    int lo = boff[b], hi = boff[b + 1];
    int cnt = hi - lo;
    int base = b << 7;
    int t = threadIdx.x;
    for (int i = t; i < 128; i += 256) { hist[i] = 0; curl[i] = 0; }
    __syncthreads();
    // pass 1: count
    for (int e = lo + t; e < hi; e += 256) {
        int v = ebuf[e];
        atomicAdd(&hist[v & 127], 1);
    }
    __syncthreads();
    // parallel exclusive scan of hist -> offs (Hillis-Steele over 128)
    if (t < 128) scn[t] = hist[t];
    __syncthreads();
    for (int off = 1; off < 128; off <<= 1) {
        int v = (t >= off && t < 128) ? scn[t - off] : 0;
        __syncthreads();
        if (t < 128) scn[t] += v;
        __syncthreads();
    }
    if (t < 128) offs[t] = scn[t] - hist[t];
    if (t == 0) offs[128] = scn[127];
    __syncthreads();
    // rs offsets (exact; dst < N so nodes >= N have count 0)
    for (int i = t; i < 128; i += 256) {
        int g = base + i;
        if (g < N) rs[g] = lo + offs[i];
    }
    if (b == NB - 1 && t == 0) rs[N] = hi;
    // pass 2: place
    bool staged = (cnt <= FCAP);
    for (int e = lo + t; e < hi; e += 256) {
        int v = ebuf[e];
        int dl = v & 127;
        int sidx = (int)(((unsigned)v) >> 7);
        int p = offs[dl] + atomicAdd(&curl[dl], 1);
        if (staged) stage[p] = sidx;
        else csr[lo + p] = sidx;
    }
    __syncthreads();
    if (staged)
        for (int i = t; i < cnt; i += 256) csr[lo + i] = stage[i];
}

// temp relation (100k edges): padded one-pass fill
__global__ void k_fill2(const int* __restrict__ src, const int* __restrict__ dst, int E,
                        int* __restrict__ cnt, int* __restrict__ csr, int C,
                        int* __restrict__ ovf, int* __restrict__ ovf_n) {
    int i = blockIdx.x * blockDim.x + threadIdx.x;
    if (i >= E) return;
    int s = src[i];
    int d = dst[i];
    int slot = atomicAdd(&cnt[d], 1);
    if (slot < C) {
        csr[(size_t)d * C + slot] = s;
    } else {
        int p = atomicAdd(ovf_n, 1);
        if (p < VO) { ovf[2 * p] = d; ovf[2 * p + 1] = s; }
    }
}

__global__ void k_pad_x(const float* __restrict__ x, float* __restrict__ x8, int N) {
    int i = blockIdx.x * blockDim.x + threadIdx.x;
    if (i >= N * 8) return;
    int n = i >> 3, c = i & 7;
    x8[i] = (c < 6) ? x[n * 6 + c] : 0.0f;
}

// ---------------- gathers ----------------

template <int CHV, int U, bool MASK>
__device__ inline void g_grp(const float* __restrict__ x, int sv, int it0, int nb,
                             int q, int r, float4& acc) {
    const int R = 64 / CHV;
    int s[U];
    float4 v[U];
#pragma unroll
    for (int u = 0; u < U; ++u) s[u] = __shfl(sv, (it0 + u) * R + r, 64);
#pragma unroll
    for (int u = 0; u < U; ++u) v[u] = *(const float4*)(x + (size_t)s[u] * (CHV * 4) + q * 4);
#pragma unroll
    for (int u = 0; u < U; ++u) {
        if (MASK) {
            float m = ((it0 + u) * R + r < nb) ? 1.0f : 0.0f;
            acc.x = fmaf(m, v[u].x, acc.x);
            acc.y = fmaf(m, v[u].y, acc.y);
            acc.z = fmaf(m, v[u].z, acc.z);
            acc.w = fmaf(m, v[u].w, acc.w);
        } else {
            f4add(acc, v[u]);
        }
    }
}

template <int CHV, int U>
__device__ inline float4 gather_one(const float* __restrict__ x, const int* __restrict__ csr,
                                    size_t rowbase, int cnt_c, int lane, int q, int r) {
    const int R = 64 / CHV;
    float4 acc = make_float4(0.f, 0.f, 0.f, 0.f);
    for (int base = 0; base < cnt_c; base += 64) {
        int nb = min(64, cnt_c - base);
        int sv = (lane < nb) ? csr[rowbase + base + lane] : 0;
        int it = 0;
        while ((it + U) * R <= nb) {
            g_grp<CHV, U, false>(x, sv, it, nb, q, r, acc);
            it += U;
        }
        if (it * R < nb) g_grp<CHV, U, true>(x, sv, it, nb, q, r, acc);
    }
    return acc;
}

// 32-ch asm gather: 4 row loads in flight, ONE vmcnt(0).
__device__ inline float4 gather_asm4(const float* __restrict__ x, const int* __restrict__ csr,
                                     size_t rowbase, int cnt_c, int lane, int q, int r) {
    float4 acc = make_float4(0.f, 0.f, 0.f, 0.f);
    for (int base = 0; base < cnt_c; base += 64) {
        int nb = min(64, cnt_c - base);
        int sv = (lane < nb) ? csr[rowbase + base + lane] : 0;
        for (int it = 0; it * 8 < nb; it += 4) {
            int s0 = __shfl(sv, (it + 0) * 8 + r, 64);
            int s1 = __shfl(sv, (it + 1) * 8 + r, 64);
            int s2 = __shfl(sv, (it + 2) * 8 + r, 64);
            int s3 = __shfl(sv, (it + 3) * 8 + r, 64);
            const float* a0 = x + (size_t)s0 * 32 + q * 4;
            const float* a1 = x + (size_t)s1 * 32 + q * 4;
            const float* a2 = x + (size_t)s2 * 32 + q * 4;
            const float* a3 = x + (size_t)s3 * 32 + q * 4;
            vf4 v0, v1, v2, v3;
            asm volatile(
                "global_load_dwordx4 %0, %4, off\n\t"
                "global_load_dwordx4 %1, %5, off\n\t"
                "global_load_dwordx4 %2, %6, off\n\t"
                "global_load_dwordx4 %3, %7, off\n\t"
                "s_waitcnt vmcnt(0)"
                : "=&v"(v0), "=&v"(v1), "=&v"(v2), "=&v"(v3)
                : "v"(a0), "v"(a1), "v"(a2), "v"(a3)
                : "memory");
            if ((it + 4) * 8 <= nb) {
                acc.x += v0.x + v1.x + v2.x + v3.x;
                acc.y += v0.y + v1.y + v2.y + v3.y;
                acc.z += v0.z + v1.z + v2.z + v3.z;
                acc.w += v0.w + v1.w + v2.w + v3.w;
            } else {
                float m0 = ((it + 0) * 8 + r < nb) ? 1.0f : 0.0f;
                float m1 = ((it + 1) * 8 + r < nb) ? 1.0f : 0.0f;
                float m2 = ((it + 2) * 8 + r < nb) ? 1.0f : 0.0f;
                float m3 = ((it + 3) * 8 + r < nb) ? 1.0f : 0.0f;
                acc.x = fmaf(m0, v0.x, fmaf(m1, v1.x, fmaf(m2, v2.x, fmaf(m3, v3.x, acc.x))));
                acc.y = fmaf(m0, v0.y, fmaf(m1, v1.y, fmaf(m2, v2.y, fmaf(m3, v3.y, acc.y))));
                acc.z = fmaf(m0, v0.z, fmaf(m1, v1.z, fmaf(m2, v2.z, fmaf(m3, v3.z, acc.z))));
                acc.w = fmaf(m0, v0.w, fmaf(m1, v1.w, fmaf(m2, v2.w, fmaf(m3, v3.w, acc.w))));
            }
        }
    }
    return acc;
}

__device__ inline float4 gather_asm1(const float* __restrict__ x, const int* __restrict__ csr,
                                     size_t rowbase, int cnt_c, int lane, int q, int r) {
    float4 acc = make_float4(0.f, 0.f, 0.f, 0.f);
    for (int base = 0; base < cnt_c; base += 64) {
        int nb = min(64, cnt_c - base);
        int sv = (lane < nb) ? csr[rowbase + base + lane] : 0;
        for (int it = 0; it * 8 < nb; ++it) {
            int s0 = __shfl(sv, it * 8 + r, 64);
            const float* a0 = x + (size_t)s0 * 32 + q * 4;
            vf4 v0;
            asm volatile(
                "global_load_dwordx4 %0, %1, off\n\t"
                "s_waitcnt vmcnt(0)"
                : "=&v"(v0)
                : "v"(a0)
                : "memory");
            float m0 = (it * 8 + r < nb) ? 1.0f : 0.0f;
            acc.x = fmaf(m0, v0.x, acc.x);
            acc.y = fmaf(m0, v0.y, acc.y);
            acc.z = fmaf(m0, v0.z, acc.z);
            acc.w = fmaf(m0, v0.w, acc.w);
        }
    }
    return acc;
}

template <int CHV>
__device__ inline void ovf_add(const float* __restrict__ x, const int* __restrict__ ovf, int n,
                               int g, int q, int r, float4& acc) {
    for (int j = 0; j < n; ++j) {
        int d = ovf[2 * j];
        if (d == g) {
            int s = ovf[2 * j + 1];
            if (r == 0) f4add(acc, *(const float4*)(x + (size_t)s * (CHV * 4) + q * 4));
        }
    }
}

template <int CHV>
__device__ inline void reduce4(float4& a) {
#pragma unroll
    for (int st = CHV; st < 64; st <<= 1) {
        a.x += __shfl_xor(a.x, st, 64);
        a.y += __shfl_xor(a.y, st, 64);
        a.z += __shfl_xor(a.z, st, 64);
        a.w += __shfl_xor(a.w, st, 64);
    }
}

// head gather: 8ch padded rows -> agg8[n][16] = [aggi*inv | aggt]
__global__ __launch_bounds__(256) void k_gather_head(
    const float* __restrict__ x8, const int* __restrict__ csr_i, const int* __restrict__ rs,
    const int* __restrict__ csr_t, const int* __restrict__ cnt_t, int Ct,
    const int* __restrict__ ovf_t, const int* __restrict__ ovfn,
    float* __restrict__ agg8, int N) {
    int tid = blockIdx.x * blockDim.x + threadIdx.x;
    int g = tid >> 6;
    if (g >= N) return;
    int lane = threadIdx.x & 63;
    int q = lane & 1, r = lane >> 1;
    int e0 = rs[g], e1 = rs[g + 1];
    int cif = e1 - e0;
    int ctf = cnt_t[g], ct = min(ctf, Ct);
    float4 ai = gather_one<2, 2>(x8, csr_i, (size_t)e0, cif, lane, q, r);
    float4 at = gather_one<2, 1>(x8, csr_t, (size_t)g * Ct, ct, lane, q, r);
    if (ctf > Ct) ovf_add<2>(x8, ovf_t, min(ovfn[1], VO), g, q, r, at);
    reduce4<2>(ai);
    reduce4<2>(at);
    float inv = 1.0f / (float)max(cif, 1);
    if (r == 0) {
        *(float4*)(agg8 + (size_t)g * 16 + q * 4) =
            make_float4(ai.x * inv, ai.y * inv, ai.z * inv, ai.w * inv);
    } else if (r == 1) {
        *(float4*)(agg8 + (size_t)g * 16 + 8 + q * 4) = at;
    }
}

// hidden gather: 32ch rows -> agg[n][64] = [aggi*inv | aggt]
__global__ __launch_bounds__(256) void k_gather32(
    const float* __restrict__ hin, const int* __restrict__ csr_i, const int* __restrict__ rs,
    const int* __restrict__ csr_t, const int* __restrict__ cnt_t, int Ct,
    const int* __restrict__ ovf_t, const int* __restrict__ ovfn,
    float* __restrict__ agg, int N) {
    int tid = blockIdx.x * blockDim.x + threadIdx.x;
    int g = tid >> 6;
    if (g >= N) return;
    int lane = threadIdx.x & 63;
    int q = lane & 7, r = lane >> 3;
    int e0 = rs[g], e1 = rs[g + 1];
    int cif = e1 - e0;
    int ctf = cnt_t[g], ct = min(ctf, Ct);
    float4 ai = gather_asm4(hin, csr_i, (size_t)e0, cif, lane, q, r);
    float4 at = gather_asm1(hin, csr_t, (size_t)g * Ct, ct, lane, q, r);
    if (ctf > Ct) ovf_add<8>(hin, ovf_t, min(ovfn[1], VO), g, q, r, at);
    reduce4<8>(ai);
    reduce4<8>(at);
    float inv = 1.0f / (float)max(cif, 1);
    if (r == 0) {
        *(float4*)(agg + (size_t)g * 64 + q * 4) =
            make_float4(ai.x * inv, ai.y * inv, ai.z * inv, ai.w * inv);
    } else if (r == 1) {
        *(float4*)(agg + (size_t)g * 64 + 32 + q * 4) = at;
    }
}

// ---------------- per-node GEMM kernels (weights wave-uniform) ----------------

// seg: 32 input channels; OC outputs with row stride STR (W column offset
// already applied by caller). Weights stay SGPR-loaded (W wave-uniform).
template <int OC, int STR>
__device__ inline void gemm_seg2(const float* __restrict__ seg, const float* __restrict__ W,
                                 float* acc) {
#pragma unroll 2
    for (int k4 = 0; k4 < 8; ++k4) {
        float4 a = ((const float4*)seg)[k4];
        float av[4] = {a.x, a.y, a.z, a.w};
#pragma unroll
        for (int i = 0; i < 4; ++i) {
            const float* Wk = W + (k4 * 4 + i) * STR;
#pragma unroll
            for (int c = 0; c < OC; ++c) acc[c] = fmaf(av[i], Wk[c], acc[c]);
        }
    }
}

__global__ __launch_bounds__(256) void k_gemm_head(
    const float* __restrict__ agg8, const float* __restrict__ x8,
    const float* __restrict__ Wt, const float* __restrict__ Wi, const float* __restrict__ Wr,
    const float* __restrict__ b, float* __restrict__ hout, int N) {
    int n = blockIdx.x * blockDim.x + threadIdx.x;
    if (n >= N) return;
    float acc[32];
#pragma unroll
    for (int c = 0; c < 32; ++c) acc[c] = b[c];
    float4 ai0 = ((const float4*)(agg8 + (size_t)n * 16))[0];
    float4 ai1 = ((const float4*)(agg8 + (size_t)n * 16))[1];
    float4 at0 = ((const float4*)(agg8 + (size_t)n * 16 + 8))[0];
    float4 at1 = ((const float4*)(agg8 + (size_t)n * 16 + 8))[1];
    float4 xv0 = ((const float4*)(x8 + (size_t)n * 8))[0];
    float4 xv1 = ((const float4*)(x8 + (size_t)n * 8))[1];
    float a_i[6] = {ai0.x, ai0.y, ai0.z, ai0.w, ai1.x, ai1.y};
    float a_t[6] = {at0.x, at0.y, at0.z, at0.w, at1.x, at1.y};
    float a_x[6] = {xv0.x, xv0.y, xv0.z, xv0.w, xv1.x, xv1.y};
#pragma unroll
    for (int k = 0; k < 6; ++k) {
        const float* Wtk = Wt + k * 32;
        const float* Wik = Wi + k * 32;
        const float* Wrk = Wr + k * 32;
#pragma unroll
        for (int c = 0; c < 32; ++c)
            acc[c] = fmaf(a_t[k], Wtk[c], fmaf(a_i[k], Wik[c], fmaf(a_x[k], Wrk[c], acc[c])));
    }
    float* O = hout + (size_t)n * 32;
#pragma unroll
    for (int c4 = 0; c4 < 8; ++c4)
        ((float4*)O)[c4] = make_float4(fmaxf(acc[c4 * 4 + 0], 0.f), fmaxf(acc[c4 * 4 + 1], 0.f),
                                       fmaxf(acc[c4 * 4 + 2], 0.f), fmaxf(acc[c4 * 4 + 3], 0.f));
}

// wave-pair split: wave parity selects output-channel half (co SGPR-uniform),
// node n = 64*(wavepair) + lane. acc[16] -> no spill, 2x waves in flight.
__global__ __launch_bounds__(256) void k_gemm_blk(
    const float* __restrict__ agg, const float* __restrict__ hin,
    const float* __restrict__ Wt, const float* __restrict__ Wi, const float* __restrict__ Wr,
    const float* __restrict__ b, float* __restrict__ hout, int N) {
    int tid = blockIdx.x * blockDim.x + threadIdx.x;
    int lane = tid & 63;
    int n = ((tid >> 7) << 6) + lane;
    if (n >= N) return;
    int co = __builtin_amdgcn_readfirstlane(((tid >> 6) & 1) << 4);
    float acc[16];
#pragma unroll
    for (int c = 0; c < 16; ++c) acc[c] = b[co + c];
    const float* Ai = agg + (size_t)n * 64;
    const float* At = Ai + 32;
    const float* H = hin + (size_t)n * 32;
    gemm_seg2<16, 32>(At, Wt + co, acc);
    gemm_seg2<16, 32>(Ai, Wi + co, acc);
    gemm_seg2<16, 32>(H, Wr + co, acc);
    float* O = hout + (size_t)n * 32 + co;
    const float* Hc = H + co;
#pragma unroll
    for (int c4 = 0; c4 < 4; ++c4) {
        float4 hv = ((const float4*)Hc)[c4];
        ((float4*)O)[c4] = make_float4(fmaxf(acc[c4 * 4 + 0], 0.f) + hv.x,
                                       fmaxf(acc[c4 * 4 + 1], 0.f) + hv.y,
                                       fmaxf(acc[c4 * 4 + 2], 0.f) + hv.z,
                                       fmaxf(acc[c4 * 4 + 3], 0.f) + hv.w);
    }
}

__global__ __launch_bounds__(256) void k_gemm_last(
    const float* __restrict__ agg, const float* __restrict__ hin,
    const float* __restrict__ Wt, const float* __restrict__ Wi, const float* __restrict__ Wr,
    const float* __restrict__ b, const float* __restrict__ proj, float* __restrict__ out, int N) {
    int tid = blockIdx.x * blockDim.x + threadIdx.x;
    int lane = tid & 63;
    int n = ((tid >> 7) << 6) + lane;
    if (n >= N) return;
    int co = __builtin_amdgcn_readfirstlane(((tid >> 6) & 1) << 5);
    float acc[32];
#pragma unroll
    for (int c = 0; c < 32; ++c) acc[c] = b[co + c];
    const float* Ai = agg + (size_t)n * 64;
    const float* At = Ai + 32;
    const float* H = hin + (size_t)n * 32;
    gemm_seg2<32, 64>(At, Wt + co, acc);
    gemm_seg2<32, 64>(Ai, Wi + co, acc);
    gemm_seg2<32, 64>(H, Wr + co, acc);
#pragma unroll
    for (int c = 0; c < 32; ++c) acc[c] = fmaxf(acc[c], 0.f);
    gemm_seg2<32, 64>(H, proj + co, acc);
    float* O = out + (size_t)n * 64 + co;
#pragma unroll
    for (int c4 = 0; c4 < 8; ++c4)
        ((float4*)O)[c4] = make_float4(acc[c4 * 4 + 0], acc[c4 * 4 + 1],
                                       acc[c4 * 4 + 2], acc[c4 * 4 + 3]);
}

// ---------------- launch ----------------

static inline size_t align256(size_t x) { return (x + 255) & ~(size_t)255; }

extern "C" void kernel_launch(void* const* d_in, const int* in_sizes, int n_in,
                              void* d_out, int out_size, void* d_ws, size_t ws_size,
                              hipStream_t stream) {
    const float* x_stroke = (const float*)d_in[0];
    const int* ei_temp = (const int*)d_in[1];
    const int* ei_inter = (const int*)d_in[2];
    const float* head_Wt = (const float*)d_in[3];
    const float* head_Wi = (const float*)d_in[4];
    const float* head_Wr = (const float*)d_in[5];
    const float* head_b = (const float*)d_in[6];
    const float* blk_Wt = (const float*)d_in[7];
    const float* blk_Wi = (const float*)d_in[8];
    const float* blk_Wr = (const float*)d_in[9];
    const float* blk_b = (const float*)d_in[10];
    const float* last_Wt = (const float*)d_in[11];
    const float* last_Wi = (const float*)d_in[12];
    const float* last_Wr = (const float*)d_in[13];
    const float* last_b = (const float*)d_in[14];
    const float* last_proj = (const float*)d_in[15];

    const int N = in_sizes[0] / 6;
    const int Et = in_sizes[1] / 2;
    const int Ei = in_sizes[2] / 2;

    const int* temp_src = ei_temp;
    const int* temp_dst = ei_temp + Et;
    const int* int_src = ei_inter;
    const int* int_dst = ei_inter + Ei;

    const int shift = 7;                      // 128-node buckets
    const int NB = ((N - 1) >> shift) + 1;    // assumes N <= 131072

    char* p = (char*)d_ws;
    size_t off = 0;
    auto carve = [&](size_t bytes) {
        char* r = p + off;
        off = align256(off + bytes);
        return r;
    };
    int* cnt_t = (int*)carve((size_t)N * 4);
    int* ovfn = (int*)carve(2 * 4);
    int* ovf_t = (int*)carve((size_t)VO * 8);
    int* gh = (int*)carve((size_t)NB * 4);
    int* boff = (int*)carve((size_t)(NB + 1) * 4);
    int* cur = (int*)carve((size_t)NB * 4);
    int* rs = (int*)carve((size_t)(N + 1) * 4);
    float* x8 = (float*)carve((size_t)N * 8 * 4);
    float* bufA = (float*)carve((size_t)N * 32 * 4);
    float* bufD = (float*)carve((size_t)N * 32 * 4);
    float* agg = (float*)carve((size_t)N * 64 * 4);   // also holds agg8 [N,16]
    int* ebuf = (int*)carve((size_t)Ei * 4);          // packed (src<<7 | dst&127)
    int* csr_i = (int*)carve((size_t)Ei * 4);         // dense
    const int Ct = 16;
    int* csr_t = (int*)carve((size_t)N * Ct * 4);
    (void)ws_size;

    const int B = 256;
    auto blocks = [&](long long work) { return (int)((work + B - 1) / B); };

    hipMemsetAsync(cnt_t, 0, (size_t)N * 4, stream);
    hipMemsetAsync(ovfn, 0, 2 * 4, stream);
    hipMemsetAsync(gh, 0, (size_t)NB * 4, stream);

    k_hist<<<256, B, 0, stream>>>(int_dst, Ei, gh, NB, shift);
    k_scan_b<<<1, 1024, 0, stream>>>(gh, NB, boff, cur);
    const int SB = 512;
    const long long sspan = (long long)SB * EPT;
    k_scatter<<<(int)((Ei + sspan - 1) / sspan), SB, 0, stream>>>(int_src, int_dst, Ei,
                                                                  shift, NB, cur, ebuf);
    k_fill3<<<NB, B, 0, stream>>>(ebuf, boff, NB, rs, csr_i, N);
    k_fill2<<<blocks(Et), B, 0, stream>>>(temp_src, temp_dst, Et, cnt_t, csr_t, Ct, ovf_t, &ovfn[1]);
    k_pad_x<<<blocks((long long)N * 8), B, 0, stream>>>(x_stroke, x8, N);

    // head
    k_gather_head<<<blocks((long long)N * 64), B, 0, stream>>>(
        x8, csr_i, rs, csr_t, cnt_t, Ct, ovf_t, ovfn, agg, N);
    k_gemm_head<<<blocks(N), B, 0, stream>>>(agg, x8, head_Wt, head_Wi, head_Wr, head_b, bufA, N);

    // split-GEMM grid: 2 waves per 64 nodes
    const int gw = 2 * ((N + 63) >> 6);
    const int gblocks = ((gw << 6) + B - 1) / B;

    // 3 hidden residual blocks
    float* hin = bufA;
    float* hout = bufD;
    for (int i = 0; i < 3; ++i) {
        k_gather32<<<blocks((long long)N * 64), B, 0, stream>>>(
            hin, csr_i, rs, csr_t, cnt_t, Ct, ovf_t, ovfn, agg, N);
        k_gemm_blk<<<gblocks, B, 0, stream>>>(
            agg, hin, blk_Wt + (size_t)i * 32 * 32, blk_Wi + (size_t)i * 32 * 32,
            blk_Wr + (size_t)i * 32 * 32, blk_b + (size_t)i * 32, hout, N);
        float* t = hin; hin = hout; hout = t;
    }

    // last
    k_gather32<<<blocks((long long)N * 64), B, 0, stream>>>(
        hin, csr_i, rs, csr_t, cnt_t, Ct, ovf_t, ovfn, agg, N);
    k_gemm_last<<<gblocks, B, 0, stream>>>(agg, hin, last_Wt, last_Wi, last_Wr, last_b,
                                           last_proj, (float*)d_out, N);
}

// Round 3
// 581.234 us; speedup vs baseline: 1.0730x; 1.0136x over previous
//
#include <hip/hip_runtime.h>

// Hetero-GNN: 5 layers of relu(segsum_temp(x)@Wt + segmean_inter(x)@Wi + x@Wr + b)
// (aggregation commuted past the matmuls).
//
// R12 (on top of R11):
//  - k_scatter: LDS write-combining (CUB-style). R11 post-mortem: more waves
//    made it SLOWER (65-68 us, WRITE +40%) -> not latency-bound; theory is
//    scattered per-edge 4B global stores (64 L2 transactions per wave store,
//    HBM partial-line RMW). New scheme: count -> in-block scan -> global
//    chunk alloc -> rank into bucket-major 32KB LDS stage -> per-wave burst
//    copy-out (contiguous run per bucket). Same chunk geometry, ~64x fewer
//    write transactions.

#define VO 8192        // overflow list capacity (pairs), temp relation
#define FCAP 10240     // staged edges per bucket in k_fill3 (40 KB LDS)
#define SCAT_THR 512
#define SCAT_SPAN 8192 // edges per scatter block (32 KB LDS stage)

typedef float vf4 __attribute__((ext_vector_type(4)));

__device__ inline void f4add(float4& a, const float4& v) {
    a.x += v.x; a.y += v.y; a.z += v.z; a.w += v.w;
}

// ---------------- build: hist -> scan -> scatter -> dense fill ----------------

__global__ void k_hist(const int* __restrict__ dst, int E, int* __restrict__ gh,
                       int NB, int shift) {
    __shared__ int sh[1024];
    for (int j = threadIdx.x; j < NB; j += blockDim.x) sh[j] = 0;
    __syncthreads();
    for (int i = blockIdx.x * blockDim.x + threadIdx.x; i < E; i += gridDim.x * blockDim.x)
        atomicAdd(&sh[dst[i] >> shift], 1);
    __syncthreads();
    for (int j = threadIdx.x; j < NB; j += blockDim.x)
        if (sh[j]) atomicAdd(&gh[j], sh[j]);
}

__global__ void k_scan_b(const int* __restrict__ gh, int NB, int* __restrict__ boff,
                         int* __restrict__ cur) {
    __shared__ int sh[1024];
    int t = threadIdx.x;
    sh[t] = (t < NB) ? gh[t] : 0;
    __syncthreads();
    for (int off = 1; off < 1024; off <<= 1) {
        int v = (t >= off) ? sh[t - off] : 0;
        __syncthreads();
        sh[t] += v;
        __syncthreads();
    }
    if (t < NB) {
        int ex = t ? sh[t - 1] : 0;
        boff[t] = ex;
        cur[t] = ex;
    }
    if (t == 0) boff[NB] = sh[NB - 1];
}

// write-combined scatter: count -> scan -> chunk alloc -> rank into LDS stage
// (bucket-major) -> burst copy-out. Packed payload (src<<shift | dst&mask).
__global__ __launch_bounds__(512) void k_scatter(const int* __restrict__ src,
                                                 const int* __restrict__ dst, int E,
                                                 int shift, int NB, int* __restrict__ cur,
                                                 int* __restrict__ ebuf) {
    __shared__ int lh[1024];     // per-bucket counts
    __shared__ int lb[1024];     // per-bucket global base (chunk alloc)
    __shared__ int lstart[1024]; // per-bucket LDS stage start (exclusive scan)
    __shared__ int lcur[1024];   // ranking cursors
    __shared__ int wsum[8];
    __shared__ int stage[SCAT_SPAN];
    const int t = threadIdx.x;
    const int lane = t & 63;
    const int wv = t >> 6;
    int lo = blockIdx.x * SCAT_SPAN;
    int hi = min(E, lo + SCAT_SPAN);
    for (int j = t; j < 1024; j += 512) lh[j] = 0;
    __syncthreads();
    // pass A: count
    for (int e = lo + t; e < hi; e += 512)
        atomicAdd(&lh[dst[e] >> shift], 1);
    __syncthreads();
    // exclusive scan of lh[0..1023] -> lstart (2 elems/thread, wave shfl scan)
    int a0 = lh[2 * t], a1 = lh[2 * t + 1];
    int ts = a0 + a1;
    int run = ts;
#pragma unroll
    for (int off = 1; off < 64; off <<= 1) {
        int v = __shfl_up(run, off, 64);
        if (lane >= off) run += v;
    }
    if (lane == 63) wsum[wv] = run;
    __syncthreads();
    int wpre = 0;
#pragma unroll
    for (int w = 0; w < 8; ++w) wpre += (w < wv) ? wsum[w] : 0;
    int excl = wpre + run - ts;
    lstart[2 * t] = excl;
    lstart[2 * t + 1] = excl + a0;
    lcur[2 * t] = excl;
    lcur[2 * t + 1] = excl + a0;
    // global chunk alloc (contiguous per bucket via cur[] cursors)
    for (int j = t; j < NB; j += 512) {
        int c = lh[j];
        lb[j] = c ? atomicAdd(&cur[j], c) : 0;
    }
    __syncthreads();
    // pass B: re-read + rank into bucket-major LDS stage
    const int mask = (1 << shift) - 1;
    for (int e = lo + t; e < hi; e += 512) {
        int s = src[e];
        int d = dst[e];
        int p = atomicAdd(&lcur[d >> shift], 1);
        stage[p] = (s << shift) | (d & mask);
    }
    __syncthreads();
    // copy-out: each wave streams whole bucket runs -> contiguous global bursts
    for (int j = wv; j < NB; j += 8) {
        int c = lh[j];
        int sb = lstart[j];
        int gb = lb[j];
        for (int i = lane; i < c; i += 64)
            ebuf[gb + i] = stage[sb + i];
    }
}

// dense CSR fill: one block per 128-node bucket. Two streaming passes over the
// bucket's packed ebuf segment; LDS staging -> coalesced full-line csr writes.
__global__ __launch_bounds__(256) void k_fill3(const int* __restrict__ ebuf,
                                               const int* __restrict__ boff, int NB,
                                               int* __restrict__ rs, int* __restrict__ csr,
                                               int N) {
    __shared__ int hist[128];
    __shared__ int offs[129];
    __shared__ int curl[128];
    __shared__ int scn[128];
    __shared__ int stage[FCAP];
    int b = blockIdx.x;
    if (b >= NB) return;
    int lo = boff[b], hi = boff[b + 1];
    int cnt = hi - lo;
    int base = b << 7;
    int t = threadIdx.x;
    for (int i = t; i < 128; i += 256) { hist[i] = 0; curl[i] = 0; }
    __syncthreads();
    // pass 1: count
    for (int e = lo + t; e < hi; e += 256) {
        int v = ebuf[e];
        atomicAdd(&hist[v & 127], 1);
    }
    __syncthreads();
    // parallel exclusive scan of hist -> offs (Hillis-Steele over 128)
    if (t < 128) scn[t] = hist[t];
    __syncthreads();
    for (int off = 1; off < 128; off <<= 1) {
        int v = (t >= off && t < 128) ? scn[t - off] : 0;
        __syncthreads();
        if (t < 128) scn[t] += v;
        __syncthreads();
    }
    if (t < 128) offs[t] = scn[t] - hist[t];
    if (t == 0) offs[128] = scn[127];
    __syncthreads();
    // rs offsets (exact; dst < N so nodes >= N have count 0)
    for (int i = t; i < 128; i += 256) {
        int g = base + i;
        if (g < N) rs[g] = lo + offs[i];
    }
    if (b == NB - 1 && t == 0) rs[N] = hi;
    // pass 2: place
    bool staged = (cnt <= FCAP);
    for (int e = lo + t; e < hi; e += 256) {
        int v = ebuf[e];
        int dl = v & 127;
        int sidx = (int)(((unsigned)v) >> 7);
        int p = offs[dl] + atomicAdd(&curl[dl], 1);
        if (staged) stage[p] = sidx;
        else csr[lo + p] = sidx;
    }
    __syncthreads();
    if (staged)
        for (int i = t; i < cnt; i += 256) csr[lo + i] = stage[i];
}

// temp relation (100k edges): padded one-pass fill
__global__ void k_fill2(const int* __restrict__ src, const int* __restrict__ dst, int E,
                        int* __restrict__ cnt, int* __restrict__ csr, int C,
                        int* __restrict__ ovf, int* __restrict__ ovf_n) {
    int i = blockIdx.x * blockDim.x + threadIdx.x;
    if (i >= E) return;
    int s = src[i];
    int d = dst[i];
    int slot = atomicAdd(&cnt[d], 1);
    if (slot < C) {
        csr[(size_t)d * C + slot] = s;
    } else {
        int p = atomicAdd(ovf_n, 1);
        if (p < VO) { ovf[2 * p] = d; ovf[2 * p + 1] = s; }
    }
}

__global__ void k_pad_x(const float* __restrict__ x, float* __restrict__ x8, int N) {
    int i = blockIdx.x * blockDim.x + threadIdx.x;
    if (i >= N * 8) return;
    int n = i >> 3, c = i & 7;
    x8[i] = (c < 6) ? x[n * 6 + c] : 0.0f;
}

// ---------------- gathers ----------------

template <int CHV, int U, bool MASK>
__device__ inline void g_grp(const float* __restrict__ x, int sv, int it0, int nb,
                             int q, int r, float4& acc) {
    const int R = 64 / CHV;
    int s[U];
    float4 v[U];
#pragma unroll
    for (int u = 0; u < U; ++u) s[u] = __shfl(sv, (it0 + u) * R + r, 64);
#pragma unroll
    for (int u = 0; u < U; ++u) v[u] = *(const float4*)(x + (size_t)s[u] * (CHV * 4) + q * 4);
#pragma unroll
    for (int u = 0; u < U; ++u) {
        if (MASK) {
            float m = ((it0 + u) * R + r < nb) ? 1.0f : 0.0f;
            acc.x = fmaf(m, v[u].x, acc.x);
            acc.y = fmaf(m, v[u].y, acc.y);
            acc.z = fmaf(m, v[u].z, acc.z);
            acc.w = fmaf(m, v[u].w, acc.w);
        } else {
            f4add(acc, v[u]);
        }
    }
}

template <int CHV, int U>
__device__ inline float4 gather_one(const float* __restrict__ x, const int* __restrict__ csr,
                                    size_t rowbase, int cnt_c, int lane, int q, int r) {
    const int R = 64 / CHV;
    float4 acc = make_float4(0.f, 0.f, 0.f, 0.f);
    for (int base = 0; base < cnt_c; base += 64) {
        int nb = min(64, cnt_c - base);
        int sv = (lane < nb) ? csr[rowbase + base + lane] : 0;
        int it = 0;
        while ((it + U) * R <= nb) {
            g_grp<CHV, U, false>(x, sv, it, nb, q, r, acc);
            it += U;
        }
        if (it * R < nb) g_grp<CHV, U, true>(x, sv, it, nb, q, r, acc);
    }
    return acc;
}

// 32-ch asm gather: 4 row loads in flight, ONE vmcnt(0).
__device__ inline float4 gather_asm4(const float* __restrict__ x, const int* __restrict__ csr,
                                     size_t rowbase, int cnt_c, int lane, int q, int r) {
    float4 acc = make_float4(0.f, 0.f, 0.f, 0.f);
    for (int base = 0; base < cnt_c; base += 64) {
        int nb = min(64, cnt_c - base);
        int sv = (lane < nb) ? csr[rowbase + base + lane] : 0;
        for (int it = 0; it * 8 < nb; it += 4) {
            int s0 = __shfl(sv, (it + 0) * 8 + r, 64);
            int s1 = __shfl(sv, (it + 1) * 8 + r, 64);
            int s2 = __shfl(sv, (it + 2) * 8 + r, 64);
            int s3 = __shfl(sv, (it + 3) * 8 + r, 64);
            const float* a0 = x + (size_t)s0 * 32 + q * 4;
            const float* a1 = x + (size_t)s1 * 32 + q * 4;
            const float* a2 = x + (size_t)s2 * 32 + q * 4;
            const float* a3 = x + (size_t)s3 * 32 + q * 4;
            vf4 v0, v1, v2, v3;
            asm volatile(
                "global_load_dwordx4 %0, %4, off\n\t"
                "global_load_dwordx4 %1, %5, off\n\t"
                "global_load_dwordx4 %2, %6, off\n\t"
                "global_load_dwordx4 %3, %7, off\n\t"
                "s_waitcnt vmcnt(0)"
                : "=&v"(v0), "=&v"(v1), "=&v"(v2), "=&v"(v3)
                : "v"(a0), "v"(a1), "v"(a2), "v"(a3)
                : "memory");
            if ((it + 4) * 8 <= nb) {
                acc.x += v0.x + v1.x + v2.x + v3.x;
                acc.y += v0.y + v1.y + v2.y + v3.y;
                acc.z += v0.z + v1.z + v2.z + v3.z;
                acc.w += v0.w + v1.w + v2.w + v3.w;
            } else {
                float m0 = ((it + 0) * 8 + r < nb) ? 1.0f : 0.0f;
                float m1 = ((it + 1) * 8 + r < nb) ? 1.0f : 0.0f;
                float m2 = ((it + 2) * 8 + r < nb) ? 1.0f : 0.0f;
                float m3 = ((it + 3) * 8 + r < nb) ? 1.0f : 0.0f;
                acc.x = fmaf(m0, v0.x, fmaf(m1, v1.x, fmaf(m2, v2.x, fmaf(m3, v3.x, acc.x))));
                acc.y = fmaf(m0, v0.y, fmaf(m1, v1.y, fmaf(m2, v2.y, fmaf(m3, v3.y, acc.y))));
                acc.z = fmaf(m0, v0.z, fmaf(m1, v1.z, fmaf(m2, v2.z, fmaf(m3, v3.z, acc.z))));
                acc.w = fmaf(m0, v0.w, fmaf(m1, v1.w, fmaf(m2, v2.w, fmaf(m3, v3.w, acc.w))));
            }
        }
    }
    return acc;
}

__device__ inline float4 gather_asm1(const float* __restrict__ x, const int* __restrict__ csr,
                                     size_t rowbase, int cnt_c, int lane, int q, int r) {
    float4 acc = make_float4(0.f, 0.f, 0.f, 0.f);
    for (int base = 0; base < cnt_c; base += 64) {
        int nb = min(64, cnt_c - base);
        int sv = (lane < nb) ? csr[rowbase + base + lane] : 0;
        for (int it = 0; it * 8 < nb; ++it) {
            int s0 = __shfl(sv, it * 8 + r, 64);
            const float* a0 = x + (size_t)s0 * 32 + q * 4;
            vf4 v0;
            asm volatile(
                "global_load_dwordx4 %0, %1, off\n\t"
                "s_waitcnt vmcnt(0)"
                : "=&v"(v0)
                : "v"(a0)
                : "memory");
            float m0 = (it * 8 + r < nb) ? 1.0f : 0.0f;
            acc.x = fmaf(m0, v0.x, acc.x);
            acc.y = fmaf(m0, v0.y, acc.y);
            acc.z = fmaf(m0, v0.z, acc.z);
            acc.w = fmaf(m0, v0.w, acc.w);
        }
    }
    return acc;
}

template <int CHV>
__device__ inline void ovf_add(const float* __restrict__ x, const int* __restrict__ ovf, int n,
                               int g, int q, int r, float4& acc) {
    for (int j = 0; j < n; ++j) {
        int d = ovf[2 * j];
        if (d == g) {
            int s = ovf[2 * j + 1];
            if (r == 0) f4add(acc, *(const float4*)(x + (size_t)s * (CHV * 4) + q * 4));
        }
    }
}

template <int CHV>
__device__ inline void reduce4(float4& a) {
#pragma unroll
    for (int st = CHV; st < 64; st <<= 1) {
        a.x += __shfl_xor(a.x, st, 64);
        a.y += __shfl_xor(a.y, st, 64);
        a.z += __shfl_xor(a.z, st, 64);
        a.w += __shfl_xor(a.w, st, 64);
    }
}

// head gather: 8ch padded rows -> agg8[n][16] = [aggi*inv | aggt]
__global__ __launch_bounds__(256) void k_gather_head(
    const float* __restrict__ x8, const int* __restrict__ csr_i, const int* __restrict__ rs,
    const int* __restrict__ csr_t, const int* __restrict__ cnt_t, int Ct,
    const int* __restrict__ ovf_t, const int* __restrict__ ovfn,
    float* __restrict__ agg8, int N) {
    int tid = blockIdx.x * blockDim.x + threadIdx.x;
    int g = tid >> 6;
    if (g >= N) return;
    int lane = threadIdx.x & 63;
    int q = lane & 1, r = lane >> 1;
    int e0 = rs[g], e1 = rs[g + 1];
    int cif = e1 - e0;
    int ctf = cnt_t[g], ct = min(ctf, Ct);
    float4 ai = gather_one<2, 2>(x8, csr_i, (size_t)e0, cif, lane, q, r);
    float4 at = gather_one<2, 1>(x8, csr_t, (size_t)g * Ct, ct, lane, q, r);
    if (ctf > Ct) ovf_add<2>(x8, ovf_t, min(ovfn[1], VO), g, q, r, at);
    reduce4<2>(ai);
    reduce4<2>(at);
    float inv = 1.0f / (float)max(cif, 1);
    if (r == 0) {
        *(float4*)(agg8 + (size_t)g * 16 + q * 4) =
            make_float4(ai.x * inv, ai.y * inv, ai.z * inv, ai.w * inv);
    } else if (r == 1) {
        *(float4*)(agg8 + (size_t)g * 16 + 8 + q * 4) = at;
    }
}

// hidden gather: 32ch rows -> agg[n][64] = [aggi*inv | aggt]
__global__ __launch_bounds__(256) void k_gather32(
    const float* __restrict__ hin, const int* __restrict__ csr_i, const int* __restrict__ rs,
    const int* __restrict__ csr_t, const int* __restrict__ cnt_t, int Ct,
    const int* __restrict__ ovf_t, const int* __restrict__ ovfn,
    float* __restrict__ agg, int N) {
    int tid = blockIdx.x * blockDim.x + threadIdx.x;
    int g = tid >> 6;
    if (g >= N) return;
    int lane = threadIdx.x & 63;
    int q = lane & 7, r = lane >> 3;
    int e0 = rs[g], e1 = rs[g + 1];
    int cif = e1 - e0;
    int ctf = cnt_t[g], ct = min(ctf, Ct);
    float4 ai = gather_asm4(hin, csr_i, (size_t)e0, cif, lane, q, r);
    float4 at = gather_asm1(hin, csr_t, (size_t)g * Ct, ct, lane, q, r);
    if (ctf > Ct) ovf_add<8>(hin, ovf_t, min(ovfn[1], VO), g, q, r, at);
    reduce4<8>(ai);
    reduce4<8>(at);
    float inv = 1.0f / (float)max(cif, 1);
    if (r == 0) {
        *(float4*)(agg + (size_t)g * 64 + q * 4) =
            make_float4(ai.x * inv, ai.y * inv, ai.z * inv, ai.w * inv);
    } else if (r == 1) {
        *(float4*)(agg + (size_t)g * 64 + 32 + q * 4) = at;
    }
}

// ---------------- per-node GEMM kernels (weights wave-uniform) ----------------

// seg: 32 input channels; OC outputs with row stride STR (W column offset
// already applied by caller). Weights stay SGPR-loaded (W wave-uniform).
template <int OC, int STR>
__device__ inline void gemm_seg2(const float* __restrict__ seg, const float* __restrict__ W,
                                 float* acc) {
#pragma unroll 2
    for (int k4 = 0; k4 < 8; ++k4) {
        float4 a = ((const float4*)seg)[k4];
        float av[4] = {a.x, a.y, a.z, a.w};
#pragma unroll
        for (int i = 0; i < 4; ++i) {
            const float* Wk = W + (k4 * 4 + i) * STR;
#pragma unroll
            for (int c = 0; c < OC; ++c) acc[c] = fmaf(av[i], Wk[c], acc[c]);
        }
    }
}

__global__ __launch_bounds__(256) void k_gemm_head(
    const float* __restrict__ agg8, const float* __restrict__ x8,
    const float* __restrict__ Wt, const float* __restrict__ Wi, const float* __restrict__ Wr,
    const float* __restrict__ b, float* __restrict__ hout, int N) {
    int n = blockIdx.x * blockDim.x + threadIdx.x;
    if (n >= N) return;
    float acc[32];
#pragma unroll
    for (int c = 0; c < 32; ++c) acc[c] = b[c];
    float4 ai0 = ((const float4*)(agg8 + (size_t)n * 16))[0];
    float4 ai1 = ((const float4*)(agg8 + (size_t)n * 16))[1];
    float4 at0 = ((const float4*)(agg8 + (size_t)n * 16 + 8))[0];
    float4 at1 = ((const float4*)(agg8 + (size_t)n * 16 + 8))[1];
    float4 xv0 = ((const float4*)(x8 + (size_t)n * 8))[0];
    float4 xv1 = ((const float4*)(x8 + (size_t)n * 8))[1];
    float a_i[6] = {ai0.x, ai0.y, ai0.z, ai0.w, ai1.x, ai1.y};
    float a_t[6] = {at0.x, at0.y, at0.z, at0.w, at1.x, at1.y};
    float a_x[6] = {xv0.x, xv0.y, xv0.z, xv0.w, xv1.x, xv1.y};
#pragma unroll
    for (int k = 0; k < 6; ++k) {
        const float* Wtk = Wt + k * 32;
        const float* Wik = Wi + k * 32;
        const float* Wrk = Wr + k * 32;
#pragma unroll
        for (int c = 0; c < 32; ++c)
            acc[c] = fmaf(a_t[k], Wtk[c], fmaf(a_i[k], Wik[c], fmaf(a_x[k], Wrk[c], acc[c])));
    }
    float* O = hout + (size_t)n * 32;
#pragma unroll
    for (int c4 = 0; c4 < 8; ++c4)
        ((float4*)O)[c4] = make_float4(fmaxf(acc[c4 * 4 + 0], 0.f), fmaxf(acc[c4 * 4 + 1], 0.f),
                                       fmaxf(acc[c4 * 4 + 2], 0.f), fmaxf(acc[c4 * 4 + 3], 0.f));
}

// wave-pair split: wave parity selects output-channel half (co SGPR-uniform),
// node n = 64*(wavepair) + lane. acc[16] -> no spill, 2x waves in flight.
__global__ __launch_bounds__(256) void k_gemm_blk(
    const float* __restrict__ agg, const float* __restrict__ hin,
    const float* __restrict__ Wt, const float* __restrict__ Wi, const float* __restrict__ Wr,
    const float* __restrict__ b, float* __restrict__ hout, int N) {
    int tid = blockIdx.x * blockDim.x + threadIdx.x;
    int lane = tid & 63;
    int n = ((tid >> 7) << 6) + lane;
    if (n >= N) return;
    int co = __builtin_amdgcn_readfirstlane(((tid >> 6) & 1) << 4);
    float acc[16];
#pragma unroll
    for (int c = 0; c < 16; ++c) acc[c] = b[co + c];
    const float* Ai = agg + (size_t)n * 64;
    const float* At = Ai + 32;
    const float* H = hin + (size_t)n * 32;
    gemm_seg2<16, 32>(At, Wt + co, acc);
    gemm_seg2<16, 32>(Ai, Wi + co, acc);
    gemm_seg2<16, 32>(H, Wr + co, acc);
    float* O = hout + (size_t)n * 32 + co;
    const float* Hc = H + co;
#pragma unroll
    for (int c4 = 0; c4 < 4; ++c4) {
        float4 hv = ((const float4*)Hc)[c4];
        ((float4*)O)[c4] = make_float4(fmaxf(acc[c4 * 4 + 0], 0.f) + hv.x,
                                       fmaxf(acc[c4 * 4 + 1], 0.f) + hv.y,
                                       fmaxf(acc[c4 * 4 + 2], 0.f) + hv.z,
                                       fmaxf(acc[c4 * 4 + 3], 0.f) + hv.w);
    }
}

__global__ __launch_bounds__(256) void k_gemm_last(
    const float* __restrict__ agg, const float* __restrict__ hin,
    const float* __restrict__ Wt, const float* __restrict__ Wi, const float* __restrict__ Wr,
    const float* __restrict__ b, const float* __restrict__ proj, float* __restrict__ out, int N) {
    int tid = blockIdx.x * blockDim.x + threadIdx.x;
    int lane = tid & 63;
    int n = ((tid >> 7) << 6) + lane;
    if (n >= N) return;
    int co = __builtin_amdgcn_readfirstlane(((tid >> 6) & 1) << 5);
    float acc[32];
#pragma unroll
    for (int c = 0; c < 32; ++c) acc[c] = b[co + c];
    const float* Ai = agg + (size_t)n * 64;
    const float* At = Ai + 32;
    const float* H = hin + (size_t)n * 32;
    gemm_seg2<32, 64>(At, Wt + co, acc);
    gemm_seg2<32, 64>(Ai, Wi + co, acc);
    gemm_seg2<32, 64>(H, Wr + co, acc);
#pragma unroll
    for (int c = 0; c < 32; ++c) acc[c] = fmaxf(acc[c], 0.f);
    gemm_seg2<32, 64>(H, proj + co, acc);
    float* O = out + (size_t)n * 64 + co;
#pragma unroll
    for (int c4 = 0; c4 < 8; ++c4)
        ((float4*)O)[c4] = make_float4(acc[c4 * 4 + 0], acc[c4 * 4 + 1],
                                       acc[c4 * 4 + 2], acc[c4 * 4 + 3]);
}

// ---------------- launch ----------------

static inline size_t align256(size_t x) { return (x + 255) & ~(size_t)255; }

extern "C" void kernel_launch(void* const* d_in, const int* in_sizes, int n_in,
                              void* d_out, int out_size, void* d_ws, size_t ws_size,
                              hipStream_t stream) {
    const float* x_stroke = (const float*)d_in[0];
    const int* ei_temp = (const int*)d_in[1];
    const int* ei_inter = (const int*)d_in[2];
    const float* head_Wt = (const float*)d_in[3];
    const float* head_Wi = (const float*)d_in[4];
    const float* head_Wr = (const float*)d_in[5];
    const float* head_b = (const float*)d_in[6];
    const float* blk_Wt = (const float*)d_in[7];
    const float* blk_Wi = (const float*)d_in[8];
    const float* blk_Wr = (const float*)d_in[9];
    const float* blk_b = (const float*)d_in[10];
    const float* last_Wt = (const float*)d_in[11];
    const float* last_Wi = (const float*)d_in[12];
    const float* last_Wr = (const float*)d_in[13];
    const float* last_b = (const float*)d_in[14];
    const float* last_proj = (const float*)d_in[15];

    const int N = in_sizes[0] / 6;
    const int Et = in_sizes[1] / 2;
    const int Ei = in_sizes[2] / 2;

    const int* temp_src = ei_temp;
    const int* temp_dst = ei_temp + Et;
    const int* int_src = ei_inter;
    const int* int_dst = ei_inter + Ei;

    const int shift = 7;                      // 128-node buckets
    const int NB = ((N - 1) >> shift) + 1;    // assumes N <= 131072

    char* p = (char*)d_ws;
    size_t off = 0;
    auto carve = [&](size_t bytes) {
        char* r = p + off;
        off = align256(off + bytes);
        return r;
    };
    int* cnt_t = (int*)carve((size_t)N * 4);
    int* ovfn = (int*)carve(2 * 4);
    int* ovf_t = (int*)carve((size_t)VO * 8);
    int* gh = (int*)carve((size_t)NB * 4);
    int* boff = (int*)carve((size_t)(NB + 1) * 4);
    int* cur = (int*)carve((size_t)NB * 4);
    int* rs = (int*)carve((size_t)(N + 1) * 4);
    float* x8 = (float*)carve((size_t)N * 8 * 4);
    float* bufA = (float*)carve((size_t)N * 32 * 4);
    float* bufD = (float*)carve((size_t)N * 32 * 4);
    float* agg = (float*)carve((size_t)N * 64 * 4);   // also holds agg8 [N,16]
    int* ebuf = (int*)carve((size_t)Ei * 4);          // packed (src<<7 | dst&127)
    int* csr_i = (int*)carve((size_t)Ei * 4);         // dense
    const int Ct = 16;
    int* csr_t = (int*)carve((size_t)N * Ct * 4);
    (void)ws_size;

    const int B = 256;
    auto blocks = [&](long long work) { return (int)((work + B - 1) / B); };

    hipMemsetAsync(cnt_t, 0, (size_t)N * 4, stream);
    hipMemsetAsync(ovfn, 0, 2 * 4, stream);
    hipMemsetAsync(gh, 0, (size_t)NB * 4, stream);

    k_hist<<<256, B, 0, stream>>>(int_dst, Ei, gh, NB, shift);
    k_scan_b<<<1, 1024, 0, stream>>>(gh, NB, boff, cur);
    k_scatter<<<(int)((Ei + SCAT_SPAN - 1) / SCAT_SPAN), SCAT_THR, 0, stream>>>(
        int_src, int_dst, Ei, shift, NB, cur, ebuf);
    k_fill3<<<NB, B, 0, stream>>>(ebuf, boff, NB, rs, csr_i, N);
    k_fill2<<<blocks(Et), B, 0, stream>>>(temp_src, temp_dst, Et, cnt_t, csr_t, Ct, ovf_t, &ovfn[1]);
    k_pad_x<<<blocks((long long)N * 8), B, 0, stream>>>(x_stroke, x8, N);

    // head
    k_gather_head<<<blocks((long long)N * 64), B, 0, stream>>>(
        x8, csr_i, rs, csr_t, cnt_t, Ct, ovf_t, ovfn, agg, N);
    k_gemm_head<<<blocks(N), B, 0, stream>>>(agg, x8, head_Wt, head_Wi, head_Wr, head_b, bufA, N);

    // split-GEMM grid: 2 waves per 64 nodes
    const int gw = 2 * ((N + 63) >> 6);
    const int gblocks = ((gw << 6) + B - 1) / B;

    // 3 hidden residual blocks
    float* hin = bufA;
    float* hout = bufD;
    for (int i = 0; i < 3; ++i) {
        k_gather32<<<blocks((long long)N * 64), B, 0, stream>>>(
            hin, csr_i, rs, csr_t, cnt_t, Ct, ovf_t, ovfn, agg, N);
        k_gemm_blk<<<gblocks, B, 0, stream>>>(
            agg, hin, blk_Wt + (size_t)i * 32 * 32, blk_Wi + (size_t)i * 32 * 32,
            blk_Wr + (size_t)i * 32 * 32, blk_b + (size_t)i * 32, hout, N);
        float* t = hin; hin = hout; hout = t;
    }

    // last
    k_gather32<<<blocks((long long)N * 64), B, 0, stream>>>(
        hin, csr_i, rs, csr_t, cnt_t, Ct, ovf_t, ovfn, agg, N);
    k_gemm_last<<<gblocks, B, 0, stream>>>(agg, hin, last_Wt, last_Wi, last_Wr, last_b,
                                           last_proj, (float*)d_out, N);
}

// Round 4
// 577.257 us; speedup vs baseline: 1.0804x; 1.0069x over previous
//
#include <hip/hip_runtime.h>
#include <hip/hip_fp16.h>

// Hetero-GNN: 5 layers of relu(segsum_temp(x)@Wt + segmean_inter(x)@Wi + x@Wr + b)
// (aggregation commuted past the matmuls).
//
// R13 (on top of R12):
//  - fp16 gather staging: each hidden GEMM writes its output BOTH fp32 (for
//    linear reads: residual/Wr) and fp16 (h16, 64-B rows) -- the 4 hidden
//    gathers read h16. R3 counters: k_gather32 FETCH=163 MB/dispatch (12.8 MB
//    footprint re-fetched ~32x, random rows, > per-XCD L2) -> halving row
//    bytes halves traffic AND fits 6.4 MB in L2 better.
//  - 3 memsets fused into 1 (cnt_t/ovfn/gh carved contiguously).

#define VO 8192        // overflow list capacity (pairs), temp relation
#define FCAP 10240     // staged edges per bucket in k_fill3 (40 KB LDS)
#define SCAT_THR 512
#define SCAT_SPAN 8192 // edges per scatter block (32 KB LDS stage)

typedef float vf4 __attribute__((ext_vector_type(4)));
typedef float vf2 __attribute__((ext_vector_type(2)));

__device__ inline void f4add(float4& a, const float4& v) {
    a.x += v.x; a.y += v.y; a.z += v.z; a.w += v.w;
}

__device__ inline float4 cvt8(vf2 v) {
    union { vf2 f; __half2 h[2]; } u;
    u.f = v;
    float2 a = __half22float2(u.h[0]);
    float2 b = __half22float2(u.h[1]);
    return make_float4(a.x, a.y, b.x, b.y);
}

// ---------------- build: hist -> scan -> scatter -> dense fill ----------------

__global__ void k_hist(const int* __restrict__ dst, int E, int* __restrict__ gh,
                       int NB, int shift) {
    __shared__ int sh[1024];
    for (int j = threadIdx.x; j < NB; j += blockDim.x) sh[j] = 0;
    __syncthreads();
    for (int i = blockIdx.x * blockDim.x + threadIdx.x; i < E; i += gridDim.x * blockDim.x)
        atomicAdd(&sh[dst[i] >> shift], 1);
    __syncthreads();
    for (int j = threadIdx.x; j < NB; j += blockDim.x)
        if (sh[j]) atomicAdd(&gh[j], sh[j]);
}

__global__ void k_scan_b(const int* __restrict__ gh, int NB, int* __restrict__ boff,
                         int* __restrict__ cur) {
    __shared__ int sh[1024];
    int t = threadIdx.x;
    sh[t] = (t < NB) ? gh[t] : 0;
    __syncthreads();
    for (int off = 1; off < 1024; off <<= 1) {
        int v = (t >= off) ? sh[t - off] : 0;
        __syncthreads();
        sh[t] += v;
        __syncthreads();
    }
    if (t < NB) {
        int ex = t ? sh[t - 1] : 0;
        boff[t] = ex;
        cur[t] = ex;
    }
    if (t == 0) boff[NB] = sh[NB - 1];
}

// write-combined scatter: count -> scan -> chunk alloc -> rank into LDS stage
// (bucket-major) -> burst copy-out. Packed payload (src<<shift | dst&mask).
__global__ __launch_bounds__(512) void k_scatter(const int* __restrict__ src,
                                                 const int* __restrict__ dst, int E,
                                                 int shift, int NB, int* __restrict__ cur,
                                                 int* __restrict__ ebuf) {
    __shared__ int lh[1024];     // per-bucket counts
    __shared__ int lb[1024];     // per-bucket global base (chunk alloc)
    __shared__ int lstart[1024]; // per-bucket LDS stage start (exclusive scan)
    __shared__ int lcur[1024];   // ranking cursors
    __shared__ int wsum[8];
    __shared__ int stage[SCAT_SPAN];
    const int t = threadIdx.x;
    const int lane = t & 63;
    const int wv = t >> 6;
    int lo = blockIdx.x * SCAT_SPAN;
    int hi = min(E, lo + SCAT_SPAN);
    for (int j = t; j < 1024; j += 512) lh[j] = 0;
    __syncthreads();
    // pass A: count
    for (int e = lo + t; e < hi; e += 512)
        atomicAdd(&lh[dst[e] >> shift], 1);
    __syncthreads();
    // exclusive scan of lh[0..1023] -> lstart (2 elems/thread, wave shfl scan)
    int a0 = lh[2 * t], a1 = lh[2 * t + 1];
    int ts = a0 + a1;
    int run = ts;
#pragma unroll
    for (int off = 1; off < 64; off <<= 1) {
        int v = __shfl_up(run, off, 64);
        if (lane >= off) run += v;
    }
    if (lane == 63) wsum[wv] = run;
    __syncthreads();
    int wpre = 0;
#pragma unroll
    for (int w = 0; w < 8; ++w) wpre += (w < wv) ? wsum[w] : 0;
    int excl = wpre + run - ts;
    lstart[2 * t] = excl;
    lstart[2 * t + 1] = excl + a0;
    lcur[2 * t] = excl;
    lcur[2 * t + 1] = excl + a0;
    // global chunk alloc (contiguous per bucket via cur[] cursors)
    for (int j = t; j < NB; j += 512) {
        int c = lh[j];
        lb[j] = c ? atomicAdd(&cur[j], c) : 0;
    }
    __syncthreads();
    // pass B: re-read + rank into bucket-major LDS stage
    const int mask = (1 << shift) - 1;
    for (int e = lo + t; e < hi; e += 512) {
        int s = src[e];
        int d = dst[e];
        int p = atomicAdd(&lcur[d >> shift], 1);
        stage[p] = (s << shift) | (d & mask);
    }
    __syncthreads();
    // copy-out: each wave streams whole bucket runs -> contiguous global bursts
    for (int j = wv; j < NB; j += 8) {
        int c = lh[j];
        int sb = lstart[j];
        int gb = lb[j];
        for (int i = lane; i < c; i += 64)
            ebuf[gb + i] = stage[sb + i];
    }
}

// dense CSR fill: one block per 128-node bucket. Two streaming passes over the
// bucket's packed ebuf segment; LDS staging -> coalesced full-line csr writes.
__global__ __launch_bounds__(256) void k_fill3(const int* __restrict__ ebuf,
                                               const int* __restrict__ boff, int NB,
                                               int* __restrict__ rs, int* __restrict__ csr,
                                               int N) {
    __shared__ int hist[128];
    __shared__ int offs[129];
    __shared__ int curl[128];
    __shared__ int scn[128];
    __shared__ int stage[FCAP];
    int b = blockIdx.x;
    if (b >= NB) return;
    int lo = boff[b], hi = boff[b + 1];
    int cnt = hi - lo;
    int base = b << 7;
    int t = threadIdx.x;
    for (int i = t; i < 128; i += 256) { hist[i] = 0; curl[i] = 0; }
    __syncthreads();
    // pass 1: count
    for (int e = lo + t; e < hi; e += 256) {
        int v = ebuf[e];
        atomicAdd(&hist[v & 127], 1);
    }
    __syncthreads();
    // parallel exclusive scan of hist -> offs (Hillis-Steele over 128)
    if (t < 128) scn[t] = hist[t];
    __syncthreads();
    for (int off = 1; off < 128; off <<= 1) {
        int v = (t >= off && t < 128) ? scn[t - off] : 0;
        __syncthreads();
        if (t < 128) scn[t] += v;
        __syncthreads();
    }
    if (t < 128) offs[t] = scn[t] - hist[t];
    if (t == 0) offs[128] = scn[127];
    __syncthreads();
    // rs offsets (exact; dst < N so nodes >= N have count 0)
    for (int i = t; i < 128; i += 256) {
        int g = base + i;
        if (g < N) rs[g] = lo + offs[i];
    }
    if (b == NB - 1 && t == 0) rs[N] = hi;
    // pass 2: place
    bool staged = (cnt <= FCAP);
    for (int e = lo + t; e < hi; e += 256) {
        int v = ebuf[e];
        int dl = v & 127;
        int sidx = (int)(((unsigned)v) >> 7);
        int p = offs[dl] + atomicAdd(&curl[dl], 1);
        if (staged) stage[p] = sidx;
        else csr[lo + p] = sidx;
    }
    __syncthreads();
    if (staged)
        for (int i = t; i < cnt; i += 256) csr[lo + i] = stage[i];
}

// temp relation (100k edges): padded one-pass fill
__global__ void k_fill2(const int* __restrict__ src, const int* __restrict__ dst, int E,
                        int* __restrict__ cnt, int* __restrict__ csr, int C,
                        int* __restrict__ ovf, int* __restrict__ ovf_n) {
    int i = blockIdx.x * blockDim.x + threadIdx.x;
    if (i >= E) return;
    int s = src[i];
    int d = dst[i];
    int slot = atomicAdd(&cnt[d], 1);
    if (slot < C) {
        csr[(size_t)d * C + slot] = s;
    } else {
        int p = atomicAdd(ovf_n, 1);
        if (p < VO) { ovf[2 * p] = d; ovf[2 * p + 1] = s; }
    }
}

__global__ void k_pad_x(const float* __restrict__ x, float* __restrict__ x8, int N) {
    int i = blockIdx.x * blockDim.x + threadIdx.x;
    if (i >= N * 8) return;
    int n = i >> 3, c = i & 7;
    x8[i] = (c < 6) ? x[n * 6 + c] : 0.0f;
}

// ---------------- gathers ----------------

template <int CHV, int U, bool MASK>
__device__ inline void g_grp(const float* __restrict__ x, int sv, int it0, int nb,
                             int q, int r, float4& acc) {
    const int R = 64 / CHV;
    int s[U];
    float4 v[U];
#pragma unroll
    for (int u = 0; u < U; ++u) s[u] = __shfl(sv, (it0 + u) * R + r, 64);
#pragma unroll
    for (int u = 0; u < U; ++u) v[u] = *(const float4*)(x + (size_t)s[u] * (CHV * 4) + q * 4);
#pragma unroll
    for (int u = 0; u < U; ++u) {
        if (MASK) {
            float m = ((it0 + u) * R + r < nb) ? 1.0f : 0.0f;
            acc.x = fmaf(m, v[u].x, acc.x);
            acc.y = fmaf(m, v[u].y, acc.y);
            acc.z = fmaf(m, v[u].z, acc.z);
            acc.w = fmaf(m, v[u].w, acc.w);
        } else {
            f4add(acc, v[u]);
        }
    }
}

template <int CHV, int U>
__device__ inline float4 gather_one(const float* __restrict__ x, const int* __restrict__ csr,
                                    size_t rowbase, int cnt_c, int lane, int q, int r) {
    const int R = 64 / CHV;
    float4 acc = make_float4(0.f, 0.f, 0.f, 0.f);
    for (int base = 0; base < cnt_c; base += 64) {
        int nb = min(64, cnt_c - base);
        int sv = (lane < nb) ? csr[rowbase + base + lane] : 0;
        int it = 0;
        while ((it + U) * R <= nb) {
            g_grp<CHV, U, false>(x, sv, it, nb, q, r, acc);
            it += U;
        }
        if (it * R < nb) g_grp<CHV, U, true>(x, sv, it, nb, q, r, acc);
    }
    return acc;
}

// fp16-row gather: 4 row loads (dwordx2) in flight, ONE vmcnt(0).
__device__ inline float4 gather_asm4_h16(const __half* __restrict__ x,
                                         const int* __restrict__ csr, size_t rowbase,
                                         int cnt_c, int lane, int q, int r) {
    float4 acc = make_float4(0.f, 0.f, 0.f, 0.f);
    for (int base = 0; base < cnt_c; base += 64) {
        int nb = min(64, cnt_c - base);
        int sv = (lane < nb) ? csr[rowbase + base + lane] : 0;
        for (int it = 0; it * 8 < nb; it += 4) {
            int s0 = __shfl(sv, (it + 0) * 8 + r, 64);
            int s1 = __shfl(sv, (it + 1) * 8 + r, 64);
            int s2 = __shfl(sv, (it + 2) * 8 + r, 64);
            int s3 = __shfl(sv, (it + 3) * 8 + r, 64);
            const __half* a0 = x + (size_t)s0 * 32 + q * 4;
            const __half* a1 = x + (size_t)s1 * 32 + q * 4;
            const __half* a2 = x + (size_t)s2 * 32 + q * 4;
            const __half* a3 = x + (size_t)s3 * 32 + q * 4;
            vf2 w0, w1, w2, w3;
            asm volatile(
                "global_load_dwordx2 %0, %4, off\n\t"
                "global_load_dwordx2 %1, %5, off\n\t"
                "global_load_dwordx2 %2, %6, off\n\t"
                "global_load_dwordx2 %3, %7, off\n\t"
                "s_waitcnt vmcnt(0)"
                : "=&v"(w0), "=&v"(w1), "=&v"(w2), "=&v"(w3)
                : "v"(a0), "v"(a1), "v"(a2), "v"(a3)
                : "memory");
            float4 v0 = cvt8(w0), v1 = cvt8(w1), v2 = cvt8(w2), v3 = cvt8(w3);
            if ((it + 4) * 8 <= nb) {
                acc.x += v0.x + v1.x + v2.x + v3.x;
                acc.y += v0.y + v1.y + v2.y + v3.y;
                acc.z += v0.z + v1.z + v2.z + v3.z;
                acc.w += v0.w + v1.w + v2.w + v3.w;
            } else {
                float m0 = ((it + 0) * 8 + r < nb) ? 1.0f : 0.0f;
                float m1 = ((it + 1) * 8 + r < nb) ? 1.0f : 0.0f;
                float m2 = ((it + 2) * 8 + r < nb) ? 1.0f : 0.0f;
                float m3 = ((it + 3) * 8 + r < nb) ? 1.0f : 0.0f;
                acc.x = fmaf(m0, v0.x, fmaf(m1, v1.x, fmaf(m2, v2.x, fmaf(m3, v3.x, acc.x))));
                acc.y = fmaf(m0, v0.y, fmaf(m1, v1.y, fmaf(m2, v2.y, fmaf(m3, v3.y, acc.y))));
                acc.z = fmaf(m0, v0.z, fmaf(m1, v1.z, fmaf(m2, v2.z, fmaf(m3, v3.z, acc.z))));
                acc.w = fmaf(m0, v0.w, fmaf(m1, v1.w, fmaf(m2, v2.w, fmaf(m3, v3.w, acc.w))));
            }
        }
    }
    return acc;
}

__device__ inline float4 gather_asm1_h16(const __half* __restrict__ x,
                                         const int* __restrict__ csr, size_t rowbase,
                                         int cnt_c, int lane, int q, int r) {
    float4 acc = make_float4(0.f, 0.f, 0.f, 0.f);
    for (int base = 0; base < cnt_c; base += 64) {
        int nb = min(64, cnt_c - base);
        int sv = (lane < nb) ? csr[rowbase + base + lane] : 0;
        for (int it = 0; it * 8 < nb; ++it) {
            int s0 = __shfl(sv, it * 8 + r, 64);
            const __half* a0 = x + (size_t)s0 * 32 + q * 4;
            vf2 w0;
            asm volatile(
                "global_load_dwordx2 %0, %1, off\n\t"
                "s_waitcnt vmcnt(0)"
                : "=&v"(w0)
                : "v"(a0)
                : "memory");
            float4 v0 = cvt8(w0);
            float m0 = (it * 8 + r < nb) ? 1.0f : 0.0f;
            acc.x = fmaf(m0, v0.x, acc.x);
            acc.y = fmaf(m0, v0.y, acc.y);
            acc.z = fmaf(m0, v0.z, acc.z);
            acc.w = fmaf(m0, v0.w, acc.w);
        }
    }
    return acc;
}

template <int CHV>
__device__ inline void ovf_add(const float* __restrict__ x, const int* __restrict__ ovf, int n,
                               int g, int q, int r, float4& acc) {
    for (int j = 0; j < n; ++j) {
        int d = ovf[2 * j];
        if (d == g) {
            int s = ovf[2 * j + 1];
            if (r == 0) f4add(acc, *(const float4*)(x + (size_t)s * (CHV * 4) + q * 4));
        }
    }
}

template <int CHV>
__device__ inline void reduce4(float4& a) {
#pragma unroll
    for (int st = CHV; st < 64; st <<= 1) {
        a.x += __shfl_xor(a.x, st, 64);
        a.y += __shfl_xor(a.y, st, 64);
        a.z += __shfl_xor(a.z, st, 64);
        a.w += __shfl_xor(a.w, st, 64);
    }
}

// head gather: 8ch padded rows -> agg8[n][16] = [aggi*inv | aggt]
__global__ __launch_bounds__(256) void k_gather_head(
    const float* __restrict__ x8, const int* __restrict__ csr_i, const int* __restrict__ rs,
    const int* __restrict__ csr_t, const int* __restrict__ cnt_t, int Ct,
    const int* __restrict__ ovf_t, const int* __restrict__ ovfn,
    float* __restrict__ agg8, int N) {
    int tid = blockIdx.x * blockDim.x + threadIdx.x;
    int g = tid >> 6;
    if (g >= N) return;
    int lane = threadIdx.x & 63;
    int q = lane & 1, r = lane >> 1;
    int e0 = rs[g], e1 = rs[g + 1];
    int cif = e1 - e0;
    int ctf = cnt_t[g], ct = min(ctf, Ct);
    float4 ai = gather_one<2, 2>(x8, csr_i, (size_t)e0, cif, lane, q, r);
    float4 at = gather_one<2, 1>(x8, csr_t, (size_t)g * Ct, ct, lane, q, r);
    if (ctf > Ct) ovf_add<2>(x8, ovf_t, min(ovfn[1], VO), g, q, r, at);
    reduce4<2>(ai);
    reduce4<2>(at);
    float inv = 1.0f / (float)max(cif, 1);
    if (r == 0) {
        *(float4*)(agg8 + (size_t)g * 16 + q * 4) =
            make_float4(ai.x * inv, ai.y * inv, ai.z * inv, ai.w * inv);
    } else if (r == 1) {
        *(float4*)(agg8 + (size_t)g * 16 + 8 + q * 4) = at;
    }
}

// hidden gather: fp16 32ch rows -> agg[n][64] = [aggi*inv | aggt]
__global__ __launch_bounds__(256) void k_gather32(
    const __half* __restrict__ h16, const float* __restrict__ hin,
    const int* __restrict__ csr_i, const int* __restrict__ rs,
    const int* __restrict__ csr_t, const int* __restrict__ cnt_t, int Ct,
    const int* __restrict__ ovf_t, const int* __restrict__ ovfn,
    float* __restrict__ agg, int N) {
    int tid = blockIdx.x * blockDim.x + threadIdx.x;
    int g = tid >> 6;
    if (g >= N) return;
    int lane = threadIdx.x & 63;
    int q = lane & 7, r = lane >> 3;
    int e0 = rs[g], e1 = rs[g + 1];
    int cif = e1 - e0;
    int ctf = cnt_t[g], ct = min(ctf, Ct);
    float4 ai = gather_asm4_h16(h16, csr_i, (size_t)e0, cif, lane, q, r);
    float4 at = gather_asm1_h16(h16, csr_t, (size_t)g * Ct, ct, lane, q, r);
    if (ctf > Ct) ovf_add<8>(hin, ovf_t, min(ovfn[1], VO), g, q, r, at);
    reduce4<8>(ai);
    reduce4<8>(at);
    float inv = 1.0f / (float)max(cif, 1);
    if (r == 0) {
        *(float4*)(agg + (size_t)g * 64 + q * 4) =
            make_float4(ai.x * inv, ai.y * inv, ai.z * inv, ai.w * inv);
    } else if (r == 1) {
        *(float4*)(agg + (size_t)g * 64 + 32 + q * 4) = at;
    }
}

// ---------------- per-node GEMM kernels (weights wave-uniform) ----------------

// seg: 32 input channels; OC outputs with row stride STR (W column offset
// already applied by caller). Weights stay SGPR-loaded (W wave-uniform).
template <int OC, int STR>
__device__ inline void gemm_seg2(const float* __restrict__ seg, const float* __restrict__ W,
                                 float* acc) {
#pragma unroll 2
    for (int k4 = 0; k4 < 8; ++k4) {
        float4 a = ((const float4*)seg)[k4];
        float av[4] = {a.x, a.y, a.z, a.w};
#pragma unroll
        for (int i = 0; i < 4; ++i) {
            const float* Wk = W + (k4 * 4 + i) * STR;
#pragma unroll
            for (int c = 0; c < OC; ++c) acc[c] = fmaf(av[i], Wk[c], acc[c]);
        }
    }
}

__global__ __launch_bounds__(256) void k_gemm_head(
    const float* __restrict__ agg8, const float* __restrict__ x8,
    const float* __restrict__ Wt, const float* __restrict__ Wi, const float* __restrict__ Wr,
    const float* __restrict__ b, float* __restrict__ hout, __half* __restrict__ h16, int N) {
    int n = blockIdx.x * blockDim.x + threadIdx.x;
    if (n >= N) return;
    float acc[32];
#pragma unroll
    for (int c = 0; c < 32; ++c) acc[c] = b[c];
    float4 ai0 = ((const float4*)(agg8 + (size_t)n * 16))[0];
    float4 ai1 = ((const float4*)(agg8 + (size_t)n * 16))[1];
    float4 at0 = ((const float4*)(agg8 + (size_t)n * 16 + 8))[0];
    float4 at1 = ((const float4*)(agg8 + (size_t)n * 16 + 8))[1];
    float4 xv0 = ((const float4*)(x8 + (size_t)n * 8))[0];
    float4 xv1 = ((const float4*)(x8 + (size_t)n * 8))[1];
    float a_i[6] = {ai0.x, ai0.y, ai0.z, ai0.w, ai1.x, ai1.y};
    float a_t[6] = {at0.x, at0.y, at0.z, at0.w, at1.x, at1.y};
    float a_x[6] = {xv0.x, xv0.y, xv0.z, xv0.w, xv1.x, xv1.y};
#pragma unroll
    for (int k = 0; k < 6; ++k) {
        const float* Wtk = Wt + k * 32;
        const float* Wik = Wi + k * 32;
        const float* Wrk = Wr + k * 32;
#pragma unroll
        for (int c = 0; c < 32; ++c)
            acc[c] = fmaf(a_t[k], Wtk[c], fmaf(a_i[k], Wik[c], fmaf(a_x[k], Wrk[c], acc[c])));
    }
    float rv[32];
#pragma unroll
    for (int c = 0; c < 32; ++c) rv[c] = fmaxf(acc[c], 0.f);
    float* O = hout + (size_t)n * 32;
#pragma unroll
    for (int c4 = 0; c4 < 8; ++c4)
        ((float4*)O)[c4] = make_float4(rv[c4 * 4 + 0], rv[c4 * 4 + 1],
                                       rv[c4 * 4 + 2], rv[c4 * 4 + 3]);
    __half2 hp[16];
#pragma unroll
    for (int i = 0; i < 16; ++i) hp[i] = __float22half2_rn(make_float2(rv[2 * i], rv[2 * i + 1]));
    uint4* D = (uint4*)(h16 + (size_t)n * 32);
    const uint4* S = (const uint4*)hp;
#pragma unroll
    for (int i = 0; i < 4; ++i) D[i] = S[i];
}

// wave-pair split: wave parity selects output-channel half (co SGPR-uniform),
// node n = 64*(wavepair) + lane. acc[16] -> no spill, 2x waves in flight.
__global__ __launch_bounds__(256) void k_gemm_blk(
    const float* __restrict__ agg, const float* __restrict__ hin,
    const float* __restrict__ Wt, const float* __restrict__ Wi, const float* __restrict__ Wr,
    const float* __restrict__ b, float* __restrict__ hout, __half* __restrict__ h16, int N) {
    int tid = blockIdx.x * blockDim.x + threadIdx.x;
    int lane = tid & 63;
    int n = ((tid >> 7) << 6) + lane;
    if (n >= N) return;
    int co = __builtin_amdgcn_readfirstlane(((tid >> 6) & 1) << 4);
    float acc[16];
#pragma unroll
    for (int c = 0; c < 16; ++c) acc[c] = b[co + c];
    const float* Ai = agg + (size_t)n * 64;
    const float* At = Ai + 32;
    const float* H = hin + (size_t)n * 32;
    gemm_seg2<16, 32>(At, Wt + co, acc);
    gemm_seg2<16, 32>(Ai, Wi + co, acc);
    gemm_seg2<16, 32>(H, Wr + co, acc);
    const float* Hc = H + co;
    float rv[16];
#pragma unroll
    for (int c4 = 0; c4 < 4; ++c4) {
        float4 hv = ((const float4*)Hc)[c4];
        rv[c4 * 4 + 0] = fmaxf(acc[c4 * 4 + 0], 0.f) + hv.x;
        rv[c4 * 4 + 1] = fmaxf(acc[c4 * 4 + 1], 0.f) + hv.y;
        rv[c4 * 4 + 2] = fmaxf(acc[c4 * 4 + 2], 0.f) + hv.z;
        rv[c4 * 4 + 3] = fmaxf(acc[c4 * 4 + 3], 0.f) + hv.w;
    }
    float* O = hout + (size_t)n * 32 + co;
#pragma unroll
    for (int c4 = 0; c4 < 4; ++c4)
        ((float4*)O)[c4] = make_float4(rv[c4 * 4 + 0], rv[c4 * 4 + 1],
                                       rv[c4 * 4 + 2], rv[c4 * 4 + 3]);
    __half2 hp[8];
#pragma unroll
    for (int i = 0; i < 8; ++i) hp[i] = __float22half2_rn(make_float2(rv[2 * i], rv[2 * i + 1]));
    uint4* D = (uint4*)(h16 + (size_t)n * 32 + co);
    const uint4* S = (const uint4*)hp;
#pragma unroll
    for (int i = 0; i < 2; ++i) D[i] = S[i];
}

__global__ __launch_bounds__(256) void k_gemm_last(
    const float* __restrict__ agg, const float* __restrict__ hin,
    const float* __restrict__ Wt, const float* __restrict__ Wi, const float* __restrict__ Wr,
    const float* __restrict__ b, const float* __restrict__ proj, float* __restrict__ out, int N) {
    int tid = blockIdx.x * blockDim.x + threadIdx.x;
    int lane = tid & 63;
    int n = ((tid >> 7) << 6) + lane;
    if (n >= N) return;
    int co = __builtin_amdgcn_readfirstlane(((tid >> 6) & 1) << 5);
    float acc[32];
#pragma unroll
    for (int c = 0; c < 32; ++c) acc[c] = b[co + c];
    const float* Ai = agg + (size_t)n * 64;
    const float* At = Ai + 32;
    const float* H = hin + (size_t)n * 32;
    gemm_seg2<32, 64>(At, Wt + co, acc);
    gemm_seg2<32, 64>(Ai, Wi + co, acc);
    gemm_seg2<32, 64>(H, Wr + co, acc);
#pragma unroll
    for (int c = 0; c < 32; ++c) acc[c] = fmaxf(acc[c], 0.f);
    gemm_seg2<32, 64>(H, proj + co, acc);
    float* O = out + (size_t)n * 64 + co;
#pragma unroll
    for (int c4 = 0; c4 < 8; ++c4)
        ((float4*)O)[c4] = make_float4(acc[c4 * 4 + 0], acc[c4 * 4 + 1],
                                       acc[c4 * 4 + 2], acc[c4 * 4 + 3]);
}

// ---------------- launch ----------------

static inline size_t align256(size_t x) { return (x + 255) & ~(size_t)255; }

extern "C" void kernel_launch(void* const* d_in, const int* in_sizes, int n_in,
                              void* d_out, int out_size, void* d_ws, size_t ws_size,
                              hipStream_t stream) {
    const float* x_stroke = (const float*)d_in[0];
    const int* ei_temp = (const int*)d_in[1];
    const int* ei_inter = (const int*)d_in[2];
    const float* head_Wt = (const float*)d_in[3];
    const float* head_Wi = (const float*)d_in[4];
    const float* head_Wr = (const float*)d_in[5];
    const float* head_b = (const float*)d_in[6];
    const float* blk_Wt = (const float*)d_in[7];
    const float* blk_Wi = (const float*)d_in[8];
    const float* blk_Wr = (const float*)d_in[9];
    const float* blk_b = (const float*)d_in[10];
    const float* last_Wt = (const float*)d_in[11];
    const float* last_Wi = (const float*)d_in[12];
    const float* last_Wr = (const float*)d_in[13];
    const float* last_b = (const float*)d_in[14];
    const float* last_proj = (const float*)d_in[15];

    const int N = in_sizes[0] / 6;
    const int Et = in_sizes[1] / 2;
    const int Ei = in_sizes[2] / 2;

    const int* temp_src = ei_temp;
    const int* temp_dst = ei_temp + Et;
    const int* int_src = ei_inter;
    const int* int_dst = ei_inter + Ei;

    const int shift = 7;                      // 128-node buckets
    const int NB = ((N - 1) >> shift) + 1;    // assumes N <= 131072

    char* p = (char*)d_ws;
    size_t off = 0;
    auto carve = [&](size_t bytes) {
        char* r = p + off;
        off = align256(off + bytes);
        return r;
    };
    // zero-init block: cnt_t, ovfn, gh contiguous -> ONE memset
    int* cnt_t = (int*)carve((size_t)N * 4);
    int* ovfn = (int*)carve(2 * 4);
    int* gh = (int*)carve((size_t)NB * 4);
    size_t zspan = (size_t)((char*)gh + (size_t)NB * 4 - (char*)cnt_t);
    int* ovf_t = (int*)carve((size_t)VO * 8);
    int* boff = (int*)carve((size_t)(NB + 1) * 4);
    int* cur = (int*)carve((size_t)NB * 4);
    int* rs = (int*)carve((size_t)(N + 1) * 4);
    float* x8 = (float*)carve((size_t)N * 8 * 4);
    float* bufA = (float*)carve((size_t)N * 32 * 4);
    float* bufD = (float*)carve((size_t)N * 32 * 4);
    float* agg = (float*)carve((size_t)N * 64 * 4);   // also holds agg8 [N,16]
    __half* h16 = (__half*)carve((size_t)N * 32 * 2); // fp16 gather staging
    int* ebuf = (int*)carve((size_t)Ei * 4);          // packed (src<<7 | dst&127)
    int* csr_i = (int*)carve((size_t)Ei * 4);         // dense
    const int Ct = 16;
    int* csr_t = (int*)carve((size_t)N * Ct * 4);
    (void)ws_size;

    const int B = 256;
    auto blocks = [&](long long work) { return (int)((work + B - 1) / B); };

    hipMemsetAsync(cnt_t, 0, zspan, stream);

    k_hist<<<256, B, 0, stream>>>(int_dst, Ei, gh, NB, shift);
    k_scan_b<<<1, 1024, 0, stream>>>(gh, NB, boff, cur);
    k_scatter<<<(int)((Ei + SCAT_SPAN - 1) / SCAT_SPAN), SCAT_THR, 0, stream>>>(
        int_src, int_dst, Ei, shift, NB, cur, ebuf);
    k_fill3<<<NB, B, 0, stream>>>(ebuf, boff, NB, rs, csr_i, N);
    k_fill2<<<blocks(Et), B, 0, stream>>>(temp_src, temp_dst, Et, cnt_t, csr_t, Ct, ovf_t, &ovfn[1]);
    k_pad_x<<<blocks((long long)N * 8), B, 0, stream>>>(x_stroke, x8, N);

    // head
    k_gather_head<<<blocks((long long)N * 64), B, 0, stream>>>(
        x8, csr_i, rs, csr_t, cnt_t, Ct, ovf_t, ovfn, agg, N);
    k_gemm_head<<<blocks(N), B, 0, stream>>>(agg, x8, head_Wt, head_Wi, head_Wr, head_b,
                                             bufA, h16, N);

    // split-GEMM grid: 2 waves per 64 nodes
    const int gw = 2 * ((N + 63) >> 6);
    const int gblocks = ((gw << 6) + B - 1) / B;

    // 3 hidden residual blocks
    float* hin = bufA;
    float* hout = bufD;
    for (int i = 0; i < 3; ++i) {
        k_gather32<<<blocks((long long)N * 64), B, 0, stream>>>(
            h16, hin, csr_i, rs, csr_t, cnt_t, Ct, ovf_t, ovfn, agg, N);
        k_gemm_blk<<<gblocks, B, 0, stream>>>(
            agg, hin, blk_Wt + (size_t)i * 32 * 32, blk_Wi + (size_t)i * 32 * 32,
            blk_Wr + (size_t)i * 32 * 32, blk_b + (size_t)i * 32, hout, h16, N);
        float* t = hin; hin = hout; hout = t;
    }

    // last
    k_gather32<<<blocks((long long)N * 64), B, 0, stream>>>(
        h16, hin, csr_i, rs, csr_t, cnt_t, Ct, ovf_t, ovfn, agg, N);
    k_gemm_last<<<gblocks, B, 0, stream>>>(agg, hin, last_Wt, last_Wi, last_Wr, last_b,
                                           last_proj, (float*)d_out, N);
}

// Round 5
// 563.867 us; speedup vs baseline: 1.1061x; 1.0237x over previous
//
#include <hip/hip_runtime.h>
#include <hip/hip_fp16.h>

// Hetero-GNN: 5 layers of relu(segsum_temp(x)@Wt + segmean_inter(x)@Wi + x@Wr + b)
// (aggregation commuted past the matmuls).
//
// R14 (on top of R13):
//  - k_gemm_last: 4-way wave split, acc[16]. R4 counters showed VGPR_Count=28
//    with acc[32] -> accumulator STILL in scratch (28 < 32; VALU 20%, occ 28%,
//    54.7 us). Empirical rule from this codebase: acc[16] promotes (k_gemm_blk
//    left top-5), acc[32] doesn't. co = (wave&3)*16, readfirstlane-uniform.
//  - k_gemm_head: same treatment (acc[32] -> 2-way split acc[16]).

#define VO 8192        // overflow list capacity (pairs), temp relation
#define FCAP 10240     // staged edges per bucket in k_fill3 (40 KB LDS)
#define SCAT_THR 512
#define SCAT_SPAN 8192 // edges per scatter block (32 KB LDS stage)

typedef float vf4 __attribute__((ext_vector_type(4)));
typedef float vf2 __attribute__((ext_vector_type(2)));

__device__ inline void f4add(float4& a, const float4& v) {
    a.x += v.x; a.y += v.y; a.z += v.z; a.w += v.w;
}

__device__ inline float4 cvt8(vf2 v) {
    union { vf2 f; __half2 h[2]; } u;
    u.f = v;
    float2 a = __half22float2(u.h[0]);
    float2 b = __half22float2(u.h[1]);
    return make_float4(a.x, a.y, b.x, b.y);
}

// ---------------- build: hist -> scan -> scatter -> dense fill ----------------

__global__ void k_hist(const int* __restrict__ dst, int E, int* __restrict__ gh,
                       int NB, int shift) {
    __shared__ int sh[1024];
    for (int j = threadIdx.x; j < NB; j += blockDim.x) sh[j] = 0;
    __syncthreads();
    for (int i = blockIdx.x * blockDim.x + threadIdx.x; i < E; i += gridDim.x * blockDim.x)
        atomicAdd(&sh[dst[i] >> shift], 1);
    __syncthreads();
    for (int j = threadIdx.x; j < NB; j += blockDim.x)
        if (sh[j]) atomicAdd(&gh[j], sh[j]);
}

__global__ void k_scan_b(const int* __restrict__ gh, int NB, int* __restrict__ boff,
                         int* __restrict__ cur) {
    __shared__ int sh[1024];
    int t = threadIdx.x;
    sh[t] = (t < NB) ? gh[t] : 0;
    __syncthreads();
    for (int off = 1; off < 1024; off <<= 1) {
        int v = (t >= off) ? sh[t - off] : 0;
        __syncthreads();
        sh[t] += v;
        __syncthreads();
    }
    if (t < NB) {
        int ex = t ? sh[t - 1] : 0;
        boff[t] = ex;
        cur[t] = ex;
    }
    if (t == 0) boff[NB] = sh[NB - 1];
}

// write-combined scatter: count -> scan -> chunk alloc -> rank into LDS stage
// (bucket-major) -> burst copy-out. Packed payload (src<<shift | dst&mask).
__global__ __launch_bounds__(512) void k_scatter(const int* __restrict__ src,
                                                 const int* __restrict__ dst, int E,
                                                 int shift, int NB, int* __restrict__ cur,
                                                 int* __restrict__ ebuf) {
    __shared__ int lh[1024];     // per-bucket counts
    __shared__ int lb[1024];     // per-bucket global base (chunk alloc)
    __shared__ int lstart[1024]; // per-bucket LDS stage start (exclusive scan)
    __shared__ int lcur[1024];   // ranking cursors
    __shared__ int wsum[8];
    __shared__ int stage[SCAT_SPAN];
    const int t = threadIdx.x;
    const int lane = t & 63;
    const int wv = t >> 6;
    int lo = blockIdx.x * SCAT_SPAN;
    int hi = min(E, lo + SCAT_SPAN);
    for (int j = t; j < 1024; j += 512) lh[j] = 0;
    __syncthreads();
    // pass A: count
    for (int e = lo + t; e < hi; e += 512)
        atomicAdd(&lh[dst[e] >> shift], 1);
    __syncthreads();
    // exclusive scan of lh[0..1023] -> lstart (2 elems/thread, wave shfl scan)
    int a0 = lh[2 * t], a1 = lh[2 * t + 1];
    int ts = a0 + a1;
    int run = ts;
#pragma unroll
    for (int off = 1; off < 64; off <<= 1) {
        int v = __shfl_up(run, off, 64);
        if (lane >= off) run += v;
    }
    if (lane == 63) wsum[wv] = run;
    __syncthreads();
    int wpre = 0;
#pragma unroll
    for (int w = 0; w < 8; ++w) wpre += (w < wv) ? wsum[w] : 0;
    int excl = wpre + run - ts;
    lstart[2 * t] = excl;
    lstart[2 * t + 1] = excl + a0;
    lcur[2 * t] = excl;
    lcur[2 * t + 1] = excl + a0;
    // global chunk alloc (contiguous per bucket via cur[] cursors)
    for (int j = t; j < NB; j += 512) {
        int c = lh[j];
        lb[j] = c ? atomicAdd(&cur[j], c) : 0;
    }
    __syncthreads();
    // pass B: re-read + rank into bucket-major LDS stage
    const int mask = (1 << shift) - 1;
    for (int e = lo + t; e < hi; e += 512) {
        int s = src[e];
        int d = dst[e];
        int p = atomicAdd(&lcur[d >> shift], 1);
        stage[p] = (s << shift) | (d & mask);
    }
    __syncthreads();
    // copy-out: each wave streams whole bucket runs -> contiguous global bursts
    for (int j = wv; j < NB; j += 8) {
        int c = lh[j];
        int sb = lstart[j];
        int gb = lb[j];
        for (int i = lane; i < c; i += 64)
            ebuf[gb + i] = stage[sb + i];
    }
}

// dense CSR fill: one block per 128-node bucket. Two streaming passes over the
// bucket's packed ebuf segment; LDS staging -> coalesced full-line csr writes.
__global__ __launch_bounds__(256) void k_fill3(const int* __restrict__ ebuf,
                                               const int* __restrict__ boff, int NB,
                                               int* __restrict__ rs, int* __restrict__ csr,
                                               int N) {
    __shared__ int hist[128];
    __shared__ int offs[129];
    __shared__ int curl[128];
    __shared__ int scn[128];
    __shared__ int stage[FCAP];
    int b = blockIdx.x;
    if (b >= NB) return;
    int lo = boff[b], hi = boff[b + 1];
    int cnt = hi - lo;
    int base = b << 7;
    int t = threadIdx.x;
    for (int i = t; i < 128; i += 256) { hist[i] = 0; curl[i] = 0; }
    __syncthreads();
    // pass 1: count
    for (int e = lo + t; e < hi; e += 256) {
        int v = ebuf[e];
        atomicAdd(&hist[v & 127], 1);
    }
    __syncthreads();
    // parallel exclusive scan of hist -> offs (Hillis-Steele over 128)
    if (t < 128) scn[t] = hist[t];
    __syncthreads();
    for (int off = 1; off < 128; off <<= 1) {
        int v = (t >= off && t < 128) ? scn[t - off] : 0;
        __syncthreads();
        if (t < 128) scn[t] += v;
        __syncthreads();
    }
    if (t < 128) offs[t] = scn[t] - hist[t];
    if (t == 0) offs[128] = scn[127];
    __syncthreads();
    // rs offsets (exact; dst < N so nodes >= N have count 0)
    for (int i = t; i < 128; i += 256) {
        int g = base + i;
        if (g < N) rs[g] = lo + offs[i];
    }
    if (b == NB - 1 && t == 0) rs[N] = hi;
    // pass 2: place
    bool staged = (cnt <= FCAP);
    for (int e = lo + t; e < hi; e += 256) {
        int v = ebuf[e];
        int dl = v & 127;
        int sidx = (int)(((unsigned)v) >> 7);
        int p = offs[dl] + atomicAdd(&curl[dl], 1);
        if (staged) stage[p] = sidx;
        else csr[lo + p] = sidx;
    }
    __syncthreads();
    if (staged)
        for (int i = t; i < cnt; i += 256) csr[lo + i] = stage[i];
}

// temp relation (100k edges): padded one-pass fill
__global__ void k_fill2(const int* __restrict__ src, const int* __restrict__ dst, int E,
                        int* __restrict__ cnt, int* __restrict__ csr, int C,
                        int* __restrict__ ovf, int* __restrict__ ovf_n) {
    int i = blockIdx.x * blockDim.x + threadIdx.x;
    if (i >= E) return;
    int s = src[i];
    int d = dst[i];
    int slot = atomicAdd(&cnt[d], 1);
    if (slot < C) {
        csr[(size_t)d * C + slot] = s;
    } else {
        int p = atomicAdd(ovf_n, 1);
        if (p < VO) { ovf[2 * p] = d; ovf[2 * p + 1] = s; }
    }
}

__global__ void k_pad_x(const float* __restrict__ x, float* __restrict__ x8, int N) {
    int i = blockIdx.x * blockDim.x + threadIdx.x;
    if (i >= N * 8) return;
    int n = i >> 3, c = i & 7;
    x8[i] = (c < 6) ? x[n * 6 + c] : 0.0f;
}

// ---------------- gathers ----------------

template <int CHV, int U, bool MASK>
__device__ inline void g_grp(const float* __restrict__ x, int sv, int it0, int nb,
                             int q, int r, float4& acc) {
    const int R = 64 / CHV;
    int s[U];
    float4 v[U];
#pragma unroll
    for (int u = 0; u < U; ++u) s[u] = __shfl(sv, (it0 + u) * R + r, 64);
#pragma unroll
    for (int u = 0; u < U; ++u) v[u] = *(const float4*)(x + (size_t)s[u] * (CHV * 4) + q * 4);
#pragma unroll
    for (int u = 0; u < U; ++u) {
        if (MASK) {
            float m = ((it0 + u) * R + r < nb) ? 1.0f : 0.0f;
            acc.x = fmaf(m, v[u].x, acc.x);
            acc.y = fmaf(m, v[u].y, acc.y);
            acc.z = fmaf(m, v[u].z, acc.z);
            acc.w = fmaf(m, v[u].w, acc.w);
        } else {
            f4add(acc, v[u]);
        }
    }
}

template <int CHV, int U>
__device__ inline float4 gather_one(const float* __restrict__ x, const int* __restrict__ csr,
                                    size_t rowbase, int cnt_c, int lane, int q, int r) {
    const int R = 64 / CHV;
    float4 acc = make_float4(0.f, 0.f, 0.f, 0.f);
    for (int base = 0; base < cnt_c; base += 64) {
        int nb = min(64, cnt_c - base);
        int sv = (lane < nb) ? csr[rowbase + base + lane] : 0;
        int it = 0;
        while ((it + U) * R <= nb) {
            g_grp<CHV, U, false>(x, sv, it, nb, q, r, acc);
            it += U;
        }
        if (it * R < nb) g_grp<CHV, U, true>(x, sv, it, nb, q, r, acc);
    }
    return acc;
}

// fp16-row gather: 4 row loads (dwordx2) in flight, ONE vmcnt(0).
__device__ inline float4 gather_asm4_h16(const __half* __restrict__ x,
                                         const int* __restrict__ csr, size_t rowbase,
                                         int cnt_c, int lane, int q, int r) {
    float4 acc = make_float4(0.f, 0.f, 0.f, 0.f);
    for (int base = 0; base < cnt_c; base += 64) {
        int nb = min(64, cnt_c - base);
        int sv = (lane < nb) ? csr[rowbase + base + lane] : 0;
        for (int it = 0; it * 8 < nb; it += 4) {
            int s0 = __shfl(sv, (it + 0) * 8 + r, 64);
            int s1 = __shfl(sv, (it + 1) * 8 + r, 64);
            int s2 = __shfl(sv, (it + 2) * 8 + r, 64);
            int s3 = __shfl(sv, (it + 3) * 8 + r, 64);
            const __half* a0 = x + (size_t)s0 * 32 + q * 4;
            const __half* a1 = x + (size_t)s1 * 32 + q * 4;
            const __half* a2 = x + (size_t)s2 * 32 + q * 4;
            const __half* a3 = x + (size_t)s3 * 32 + q * 4;
            vf2 w0, w1, w2, w3;
            asm volatile(
                "global_load_dwordx2 %0, %4, off\n\t"
                "global_load_dwordx2 %1, %5, off\n\t"
                "global_load_dwordx2 %2, %6, off\n\t"
                "global_load_dwordx2 %3, %7, off\n\t"
                "s_waitcnt vmcnt(0)"
                : "=&v"(w0), "=&v"(w1), "=&v"(w2), "=&v"(w3)
                : "v"(a0), "v"(a1), "v"(a2), "v"(a3)
                : "memory");
            float4 v0 = cvt8(w0), v1 = cvt8(w1), v2 = cvt8(w2), v3 = cvt8(w3);
            if ((it + 4) * 8 <= nb) {
                acc.x += v0.x + v1.x + v2.x + v3.x;
                acc.y += v0.y + v1.y + v2.y + v3.y;
                acc.z += v0.z + v1.z + v2.z + v3.z;
                acc.w += v0.w + v1.w + v2.w + v3.w;
            } else {
                float m0 = ((it + 0) * 8 + r < nb) ? 1.0f : 0.0f;
                float m1 = ((it + 1) * 8 + r < nb) ? 1.0f : 0.0f;
                float m2 = ((it + 2) * 8 + r < nb) ? 1.0f : 0.0f;
                float m3 = ((it + 3) * 8 + r < nb) ? 1.0f : 0.0f;
                acc.x = fmaf(m0, v0.x, fmaf(m1, v1.x, fmaf(m2, v2.x, fmaf(m3, v3.x, acc.x))));
                acc.y = fmaf(m0, v0.y, fmaf(m1, v1.y, fmaf(m2, v2.y, fmaf(m3, v3.y, acc.y))));
                acc.z = fmaf(m0, v0.z, fmaf(m1, v1.z, fmaf(m2, v2.z, fmaf(m3, v3.z, acc.z))));
                acc.w = fmaf(m0, v0.w, fmaf(m1, v1.w, fmaf(m2, v2.w, fmaf(m3, v3.w, acc.w))));
            }
        }
    }
    return acc;
}

__device__ inline float4 gather_asm1_h16(const __half* __restrict__ x,
                                         const int* __restrict__ csr, size_t rowbase,
                                         int cnt_c, int lane, int q, int r) {
    float4 acc = make_float4(0.f, 0.f, 0.f, 0.f);
    for (int base = 0; base < cnt_c; base += 64) {
        int nb = min(64, cnt_c - base);
        int sv = (lane < nb) ? csr[rowbase + base + lane] : 0;
        for (int it = 0; it * 8 < nb; ++it) {
            int s0 = __shfl(sv, it * 8 + r, 64);
            const __half* a0 = x + (size_t)s0 * 32 + q * 4;
            vf2 w0;
            asm volatile(
                "global_load_dwordx2 %0, %1, off\n\t"
                "s_waitcnt vmcnt(0)"
                : "=&v"(w0)
                : "v"(a0)
                : "memory");
            float4 v0 = cvt8(w0);
            float m0 = (it * 8 + r < nb) ? 1.0f : 0.0f;
            acc.x = fmaf(m0, v0.x, acc.x);
            acc.y = fmaf(m0, v0.y, acc.y);
            acc.z = fmaf(m0, v0.z, acc.z);
            acc.w = fmaf(m0, v0.w, acc.w);
        }
    }
    return acc;
}

template <int CHV>
__device__ inline void ovf_add(const float* __restrict__ x, const int* __restrict__ ovf, int n,
                               int g, int q, int r, float4& acc) {
    for (int j = 0; j < n; ++j) {
        int d = ovf[2 * j];
        if (d == g) {
            int s = ovf[2 * j + 1];
            if (r == 0) f4add(acc, *(const float4*)(x + (size_t)s * (CHV * 4) + q * 4));
        }
    }
}

template <int CHV>
__device__ inline void reduce4(float4& a) {
#pragma unroll
    for (int st = CHV; st < 64; st <<= 1) {
        a.x += __shfl_xor(a.x, st, 64);
        a.y += __shfl_xor(a.y, st, 64);
        a.z += __shfl_xor(a.z, st, 64);
        a.w += __shfl_xor(a.w, st, 64);
    }
}

// head gather: 8ch padded rows -> agg8[n][16] = [aggi*inv | aggt]
__global__ __launch_bounds__(256) void k_gather_head(
    const float* __restrict__ x8, const int* __restrict__ csr_i, const int* __restrict__ rs,
    const int* __restrict__ csr_t, const int* __restrict__ cnt_t, int Ct,
    const int* __restrict__ ovf_t, const int* __restrict__ ovfn,
    float* __restrict__ agg8, int N) {
    int tid = blockIdx.x * blockDim.x + threadIdx.x;
    int g = tid >> 6;
    if (g >= N) return;
    int lane = threadIdx.x & 63;
    int q = lane & 1, r = lane >> 1;
    int e0 = rs[g], e1 = rs[g + 1];
    int cif = e1 - e0;
    int ctf = cnt_t[g], ct = min(ctf, Ct);
    float4 ai = gather_one<2, 2>(x8, csr_i, (size_t)e0, cif, lane, q, r);
    float4 at = gather_one<2, 1>(x8, csr_t, (size_t)g * Ct, ct, lane, q, r);
    if (ctf > Ct) ovf_add<2>(x8, ovf_t, min(ovfn[1], VO), g, q, r, at);
    reduce4<2>(ai);
    reduce4<2>(at);
    float inv = 1.0f / (float)max(cif, 1);
    if (r == 0) {
        *(float4*)(agg8 + (size_t)g * 16 + q * 4) =
            make_float4(ai.x * inv, ai.y * inv, ai.z * inv, ai.w * inv);
    } else if (r == 1) {
        *(float4*)(agg8 + (size_t)g * 16 + 8 + q * 4) = at;
    }
}

// hidden gather: fp16 32ch rows -> agg[n][64] = [aggi*inv | aggt]
__global__ __launch_bounds__(256) void k_gather32(
    const __half* __restrict__ h16, const float* __restrict__ hin,
    const int* __restrict__ csr_i, const int* __restrict__ rs,
    const int* __restrict__ csr_t, const int* __restrict__ cnt_t, int Ct,
    const int* __restrict__ ovf_t, const int* __restrict__ ovfn,
    float* __restrict__ agg, int N) {
    int tid = blockIdx.x * blockDim.x + threadIdx.x;
    int g = tid >> 6;
    if (g >= N) return;
    int lane = threadIdx.x & 63;
    int q = lane & 7, r = lane >> 3;
    int e0 = rs[g], e1 = rs[g + 1];
    int cif = e1 - e0;
    int ctf = cnt_t[g], ct = min(ctf, Ct);
    float4 ai = gather_asm4_h16(h16, csr_i, (size_t)e0, cif, lane, q, r);
    float4 at = gather_asm1_h16(h16, csr_t, (size_t)g * Ct, ct, lane, q, r);
    if (ctf > Ct) ovf_add<8>(hin, ovf_t, min(ovfn[1], VO), g, q, r, at);
    reduce4<8>(ai);
    reduce4<8>(at);
    float inv = 1.0f / (float)max(cif, 1);
    if (r == 0) {
        *(float4*)(agg + (size_t)g * 64 + q * 4) =
            make_float4(ai.x * inv, ai.y * inv, ai.z * inv, ai.w * inv);
    } else if (r == 1) {
        *(float4*)(agg + (size_t)g * 64 + 32 + q * 4) = at;
    }
}

// ---------------- per-node GEMM kernels (weights wave-uniform) ----------------

// seg: 32 input channels; OC outputs with row stride STR (W column offset
// already applied by caller). Weights stay SGPR-loaded (W wave-uniform).
template <int OC, int STR>
__device__ inline void gemm_seg2(const float* __restrict__ seg, const float* __restrict__ W,
                                 float* acc) {
#pragma unroll 2
    for (int k4 = 0; k4 < 8; ++k4) {
        float4 a = ((const float4*)seg)[k4];
        float av[4] = {a.x, a.y, a.z, a.w};
#pragma unroll
        for (int i = 0; i < 4; ++i) {
            const float* Wk = W + (k4 * 4 + i) * STR;
#pragma unroll
            for (int c = 0; c < OC; ++c) acc[c] = fmaf(av[i], Wk[c], acc[c]);
        }
    }
}

// 2-way wave split head: wave parity selects output-channel half. acc[16].
__global__ __launch_bounds__(256) void k_gemm_head(
    const float* __restrict__ agg8, const float* __restrict__ x8,
    const float* __restrict__ Wt, const float* __restrict__ Wi, const float* __restrict__ Wr,
    const float* __restrict__ b, float* __restrict__ hout, __half* __restrict__ h16, int N) {
    int tid = blockIdx.x * blockDim.x + threadIdx.x;
    int lane = tid & 63;
    int n = ((tid >> 7) << 6) + lane;
    if (n >= N) return;
    int co = __builtin_amdgcn_readfirstlane(((tid >> 6) & 1) << 4);
    float acc[16];
#pragma unroll
    for (int c = 0; c < 16; ++c) acc[c] = b[co + c];
    float4 ai0 = ((const float4*)(agg8 + (size_t)n * 16))[0];
    float4 ai1 = ((const float4*)(agg8 + (size_t)n * 16))[1];
    float4 at0 = ((const float4*)(agg8 + (size_t)n * 16 + 8))[0];
    float4 at1 = ((const float4*)(agg8 + (size_t)n * 16 + 8))[1];
    float4 xv0 = ((const float4*)(x8 + (size_t)n * 8))[0];
    float4 xv1 = ((const float4*)(x8 + (size_t)n * 8))[1];
    float a_i[6] = {ai0.x, ai0.y, ai0.z, ai0.w, ai1.x, ai1.y};
    float a_t[6] = {at0.x, at0.y, at0.z, at0.w, at1.x, at1.y};
    float a_x[6] = {xv0.x, xv0.y, xv0.z, xv0.w, xv1.x, xv1.y};
#pragma unroll
    for (int k = 0; k < 6; ++k) {
        const float* Wtk = Wt + k * 32 + co;
        const float* Wik = Wi + k * 32 + co;
        const float* Wrk = Wr + k * 32 + co;
#pragma unroll
        for (int c = 0; c < 16; ++c)
            acc[c] = fmaf(a_t[k], Wtk[c], fmaf(a_i[k], Wik[c], fmaf(a_x[k], Wrk[c], acc[c])));
    }
    float rv[16];
#pragma unroll
    for (int c = 0; c < 16; ++c) rv[c] = fmaxf(acc[c], 0.f);
    float* O = hout + (size_t)n * 32 + co;
#pragma unroll
    for (int c4 = 0; c4 < 4; ++c4)
        ((float4*)O)[c4] = make_float4(rv[c4 * 4 + 0], rv[c4 * 4 + 1],
                                       rv[c4 * 4 + 2], rv[c4 * 4 + 3]);
    __half2 hp[8];
#pragma unroll
    for (int i = 0; i < 8; ++i) hp[i] = __float22half2_rn(make_float2(rv[2 * i], rv[2 * i + 1]));
    uint4* D = (uint4*)(h16 + (size_t)n * 32 + co);
    const uint4* S = (const uint4*)hp;
#pragma unroll
    for (int i = 0; i < 2; ++i) D[i] = S[i];
}

// wave-pair split: wave parity selects output-channel half (co SGPR-uniform),
// node n = 64*(wavepair) + lane. acc[16] -> no spill, 2x waves in flight.
__global__ __launch_bounds__(256) void k_gemm_blk(
    const float* __restrict__ agg, const float* __restrict__ hin,
    const float* __restrict__ Wt, const float* __restrict__ Wi, const float* __restrict__ Wr,
    const float* __restrict__ b, float* __restrict__ hout, __half* __restrict__ h16, int N) {
    int tid = blockIdx.x * blockDim.x + threadIdx.x;
    int lane = tid & 63;
    int n = ((tid >> 7) << 6) + lane;
    if (n >= N) return;
    int co = __builtin_amdgcn_readfirstlane(((tid >> 6) & 1) << 4);
    float acc[16];
#pragma unroll
    for (int c = 0; c < 16; ++c) acc[c] = b[co + c];
    const float* Ai = agg + (size_t)n * 64;
    const float* At = Ai + 32;
    const float* H = hin + (size_t)n * 32;
    gemm_seg2<16, 32>(At, Wt + co, acc);
    gemm_seg2<16, 32>(Ai, Wi + co, acc);
    gemm_seg2<16, 32>(H, Wr + co, acc);
    const float* Hc = H + co;
    float rv[16];
#pragma unroll
    for (int c4 = 0; c4 < 4; ++c4) {
        float4 hv = ((const float4*)Hc)[c4];
        rv[c4 * 4 + 0] = fmaxf(acc[c4 * 4 + 0], 0.f) + hv.x;
        rv[c4 * 4 + 1] = fmaxf(acc[c4 * 4 + 1], 0.f) + hv.y;
        rv[c4 * 4 + 2] = fmaxf(acc[c4 * 4 + 2], 0.f) + hv.z;
        rv[c4 * 4 + 3] = fmaxf(acc[c4 * 4 + 3], 0.f) + hv.w;
    }
    float* O = hout + (size_t)n * 32 + co;
#pragma unroll
    for (int c4 = 0; c4 < 4; ++c4)
        ((float4*)O)[c4] = make_float4(rv[c4 * 4 + 0], rv[c4 * 4 + 1],
                                       rv[c4 * 4 + 2], rv[c4 * 4 + 3]);
    __half2 hp[8];
#pragma unroll
    for (int i = 0; i < 8; ++i) hp[i] = __float22half2_rn(make_float2(rv[2 * i], rv[2 * i + 1]));
    uint4* D = (uint4*)(h16 + (size_t)n * 32 + co);
    const uint4* S = (const uint4*)hp;
#pragma unroll
    for (int i = 0; i < 2; ++i) D[i] = S[i];
}

// 4-way wave split: wave&3 selects 16-channel output slice of 64. acc[16].
__global__ __launch_bounds__(256) void k_gemm_last(
    const float* __restrict__ agg, const float* __restrict__ hin,
    const float* __restrict__ Wt, const float* __restrict__ Wi, const float* __restrict__ Wr,
    const float* __restrict__ b, const float* __restrict__ proj, float* __restrict__ out, int N) {
    int tid = blockIdx.x * blockDim.x + threadIdx.x;
    int lane = tid & 63;
    int w = tid >> 6;
    int n = ((w >> 2) << 6) + lane;
    if (n >= N) return;
    int co = __builtin_amdgcn_readfirstlane((w & 3) << 4);
    float acc[16];
#pragma unroll
    for (int c = 0; c < 16; ++c) acc[c] = b[co + c];
    const float* Ai = agg + (size_t)n * 64;
    const float* At = Ai + 32;
    const float* H = hin + (size_t)n * 32;
    gemm_seg2<16, 64>(At, Wt + co, acc);
    gemm_seg2<16, 64>(Ai, Wi + co, acc);
    gemm_seg2<16, 64>(H, Wr + co, acc);
#pragma unroll
    for (int c = 0; c < 16; ++c) acc[c] = fmaxf(acc[c], 0.f);
    gemm_seg2<16, 64>(H, proj + co, acc);
    float* O = out + (size_t)n * 64 + co;
#pragma unroll
    for (int c4 = 0; c4 < 4; ++c4)
        ((float4*)O)[c4] = make_float4(acc[c4 * 4 + 0], acc[c4 * 4 + 1],
                                       acc[c4 * 4 + 2], acc[c4 * 4 + 3]);
}

// ---------------- launch ----------------

static inline size_t align256(size_t x) { return (x + 255) & ~(size_t)255; }

extern "C" void kernel_launch(void* const* d_in, const int* in_sizes, int n_in,
                              void* d_out, int out_size, void* d_ws, size_t ws_size,
                              hipStream_t stream) {
    const float* x_stroke = (const float*)d_in[0];
    const int* ei_temp = (const int*)d_in[1];
    const int* ei_inter = (const int*)d_in[2];
    const float* head_Wt = (const float*)d_in[3];
    const float* head_Wi = (const float*)d_in[4];
    const float* head_Wr = (const float*)d_in[5];
    const float* head_b = (const float*)d_in[6];
    const float* blk_Wt = (const float*)d_in[7];
    const float* blk_Wi = (const float*)d_in[8];
    const float* blk_Wr = (const float*)d_in[9];
    const float* blk_b = (const float*)d_in[10];
    const float* last_Wt = (const float*)d_in[11];
    const float* last_Wi = (const float*)d_in[12];
    const float* last_Wr = (const float*)d_in[13];
    const float* last_b = (const float*)d_in[14];
    const float* last_proj = (const float*)d_in[15];

    const int N = in_sizes[0] / 6;
    const int Et = in_sizes[1] / 2;
    const int Ei = in_sizes[2] / 2;

    const int* temp_src = ei_temp;
    const int* temp_dst = ei_temp + Et;
    const int* int_src = ei_inter;
    const int* int_dst = ei_inter + Ei;

    const int shift = 7;                      // 128-node buckets
    const int NB = ((N - 1) >> shift) + 1;    // assumes N <= 131072

    char* p = (char*)d_ws;
    size_t off = 0;
    auto carve = [&](size_t bytes) {
        char* r = p + off;
        off = align256(off + bytes);
        return r;
    };
    // zero-init block: cnt_t, ovfn, gh contiguous -> ONE memset
    int* cnt_t = (int*)carve((size_t)N * 4);
    int* ovfn = (int*)carve(2 * 4);
    int* gh = (int*)carve((size_t)NB * 4);
    size_t zspan = (size_t)((char*)gh + (size_t)NB * 4 - (char*)cnt_t);
    int* ovf_t = (int*)carve((size_t)VO * 8);
    int* boff = (int*)carve((size_t)(NB + 1) * 4);
    int* cur = (int*)carve((size_t)NB * 4);
    int* rs = (int*)carve((size_t)(N + 1) * 4);
    float* x8 = (float*)carve((size_t)N * 8 * 4);
    float* bufA = (float*)carve((size_t)N * 32 * 4);
    float* bufD = (float*)carve((size_t)N * 32 * 4);
    float* agg = (float*)carve((size_t)N * 64 * 4);   // also holds agg8 [N,16]
    __half* h16 = (__half*)carve((size_t)N * 32 * 2); // fp16 gather staging
    int* ebuf = (int*)carve((size_t)Ei * 4);          // packed (src<<7 | dst&127)
    int* csr_i = (int*)carve((size_t)Ei * 4);         // dense
    const int Ct = 16;
    int* csr_t = (int*)carve((size_t)N * Ct * 4);
    (void)ws_size;

    const int B = 256;
    auto blocks = [&](long long work) { return (int)((work + B - 1) / B); };

    hipMemsetAsync(cnt_t, 0, zspan, stream);

    k_hist<<<256, B, 0, stream>>>(int_dst, Ei, gh, NB, shift);
    k_scan_b<<<1, 1024, 0, stream>>>(gh, NB, boff, cur);
    k_scatter<<<(int)((Ei + SCAT_SPAN - 1) / SCAT_SPAN), SCAT_THR, 0, stream>>>(
        int_src, int_dst, Ei, shift, NB, cur, ebuf);
    k_fill3<<<NB, B, 0, stream>>>(ebuf, boff, NB, rs, csr_i, N);
    k_fill2<<<blocks(Et), B, 0, stream>>>(temp_src, temp_dst, Et, cnt_t, csr_t, Ct, ovf_t, &ovfn[1]);
    k_pad_x<<<blocks((long long)N * 8), B, 0, stream>>>(x_stroke, x8, N);

    // wave-split GEMM grids
    const int gw2 = 2 * ((N + 63) >> 6);              // 2 waves per 64 nodes
    const int gblocks2 = ((gw2 << 6) + B - 1) / B;
    const int gw4 = 4 * ((N + 63) >> 6);              // 4 waves per 64 nodes
    const int gblocks4 = ((gw4 << 6) + B - 1) / B;

    // head
    k_gather_head<<<blocks((long long)N * 64), B, 0, stream>>>(
        x8, csr_i, rs, csr_t, cnt_t, Ct, ovf_t, ovfn, agg, N);
    k_gemm_head<<<gblocks2, B, 0, stream>>>(agg, x8, head_Wt, head_Wi, head_Wr, head_b,
                                            bufA, h16, N);

    // 3 hidden residual blocks
    float* hin = bufA;
    float* hout = bufD;
    for (int i = 0; i < 3; ++i) {
        k_gather32<<<blocks((long long)N * 64), B, 0, stream>>>(
            h16, hin, csr_i, rs, csr_t, cnt_t, Ct, ovf_t, ovfn, agg, N);
        k_gemm_blk<<<gblocks2, B, 0, stream>>>(
            agg, hin, blk_Wt + (size_t)i * 32 * 32, blk_Wi + (size_t)i * 32 * 32,
            blk_Wr + (size_t)i * 32 * 32, blk_b + (size_t)i * 32, hout, h16, N);
        float* t = hin; hin = hout; hout = t;
    }

    // last
    k_gather32<<<blocks((long long)N * 64), B, 0, stream>>>(
        h16, hin, csr_i, rs, csr_t, cnt_t, Ct, ovf_t, ovfn, agg, N);
    k_gemm_last<<<gblocks4, B, 0, stream>>>(agg, hin, last_Wt, last_Wi, last_Wr, last_b,
                                            last_proj, (float*)d_out, N);
}

// Round 6
// 529.759 us; speedup vs baseline: 1.1773x; 1.0644x over previous
//
#include <hip/hip_runtime.h>
#include <hip/hip_fp16.h>

// Hetero-GNN: 5 layers of relu(segsum_temp(x)@Wt + segmean_inter(x)@Wi + x@Wr + b)
// (aggregation commuted past the matmuls).
//
// R15 (on top of R14):
//  - k_gather32 restructured wave-per-node -> GROUP-per-node (8 lanes/node,
//    8 nodes/wave). R5 counters: VALU 60%, HBM 32% -> per-wave fixed overhead
//    (2x reduce4 trees, 32-row loop quantization, masked dummy loads) dominated
//    at mean degree 32. New layout: lane q of group r accumulates channels
//    4q..4q+3 of node wave*8+r directly -> NO cross-lane reduction, batches of
//    8 edges (1 coalesced idx load + 8 shfl + 8-deep asm load batch), exact
//    divergence-masked edge counts. 8x fewer waves.

#define VO 8192        // overflow list capacity (pairs), temp relation
#define FCAP 10240     // staged edges per bucket in k_fill3 (40 KB LDS)
#define SCAT_THR 512
#define SCAT_SPAN 8192 // edges per scatter block (32 KB LDS stage)

typedef float vf4 __attribute__((ext_vector_type(4)));
typedef float vf2 __attribute__((ext_vector_type(2)));

__device__ inline void f4add(float4& a, const float4& v) {
    a.x += v.x; a.y += v.y; a.z += v.z; a.w += v.w;
}

__device__ inline float4 cvt8(vf2 v) {
    union { vf2 f; __half2 h[2]; } u;
    u.f = v;
    float2 a = __half22float2(u.h[0]);
    float2 b = __half22float2(u.h[1]);
    return make_float4(a.x, a.y, b.x, b.y);
}

// ---------------- build: hist -> scan -> scatter -> dense fill ----------------

__global__ void k_hist(const int* __restrict__ dst, int E, int* __restrict__ gh,
                       int NB, int shift) {
    __shared__ int sh[1024];
    for (int j = threadIdx.x; j < NB; j += blockDim.x) sh[j] = 0;
    __syncthreads();
    for (int i = blockIdx.x * blockDim.x + threadIdx.x; i < E; i += gridDim.x * blockDim.x)
        atomicAdd(&sh[dst[i] >> shift], 1);
    __syncthreads();
    for (int j = threadIdx.x; j < NB; j += blockDim.x)
        if (sh[j]) atomicAdd(&gh[j], sh[j]);
}

__global__ void k_scan_b(const int* __restrict__ gh, int NB, int* __restrict__ boff,
                         int* __restrict__ cur) {
    __shared__ int sh[1024];
    int t = threadIdx.x;
    sh[t] = (t < NB) ? gh[t] : 0;
    __syncthreads();
    for (int off = 1; off < 1024; off <<= 1) {
        int v = (t >= off) ? sh[t - off] : 0;
        __syncthreads();
        sh[t] += v;
        __syncthreads();
    }
    if (t < NB) {
        int ex = t ? sh[t - 1] : 0;
        boff[t] = ex;
        cur[t] = ex;
    }
    if (t == 0) boff[NB] = sh[NB - 1];
}

// write-combined scatter: count -> scan -> chunk alloc -> rank into LDS stage
// (bucket-major) -> burst copy-out. Packed payload (src<<shift | dst&mask).
__global__ __launch_bounds__(512) void k_scatter(const int* __restrict__ src,
                                                 const int* __restrict__ dst, int E,
                                                 int shift, int NB, int* __restrict__ cur,
                                                 int* __restrict__ ebuf) {
    __shared__ int lh[1024];     // per-bucket counts
    __shared__ int lb[1024];     // per-bucket global base (chunk alloc)
    __shared__ int lstart[1024]; // per-bucket LDS stage start (exclusive scan)
    __shared__ int lcur[1024];   // ranking cursors
    __shared__ int wsum[8];
    __shared__ int stage[SCAT_SPAN];
    const int t = threadIdx.x;
    const int lane = t & 63;
    const int wv = t >> 6;
    int lo = blockIdx.x * SCAT_SPAN;
    int hi = min(E, lo + SCAT_SPAN);
    for (int j = t; j < 1024; j += 512) lh[j] = 0;
    __syncthreads();
    // pass A: count
    for (int e = lo + t; e < hi; e += 512)
        atomicAdd(&lh[dst[e] >> shift], 1);
    __syncthreads();
    // exclusive scan of lh[0..1023] -> lstart (2 elems/thread, wave shfl scan)
    int a0 = lh[2 * t], a1 = lh[2 * t + 1];
    int ts = a0 + a1;
    int run = ts;
#pragma unroll
    for (int off = 1; off < 64; off <<= 1) {
        int v = __shfl_up(run, off, 64);
        if (lane >= off) run += v;
    }
    if (lane == 63) wsum[wv] = run;
    __syncthreads();
    int wpre = 0;
#pragma unroll
    for (int w = 0; w < 8; ++w) wpre += (w < wv) ? wsum[w] : 0;
    int excl = wpre + run - ts;
    lstart[2 * t] = excl;
    lstart[2 * t + 1] = excl + a0;
    lcur[2 * t] = excl;
    lcur[2 * t + 1] = excl + a0;
    // global chunk alloc (contiguous per bucket via cur[] cursors)
    for (int j = t; j < NB; j += 512) {
        int c = lh[j];
        lb[j] = c ? atomicAdd(&cur[j], c) : 0;
    }
    __syncthreads();
    // pass B: re-read + rank into bucket-major LDS stage
    const int mask = (1 << shift) - 1;
    for (int e = lo + t; e < hi; e += 512) {
        int s = src[e];
        int d = dst[e];
        int p = atomicAdd(&lcur[d >> shift], 1);
        stage[p] = (s << shift) | (d & mask);
    }
    __syncthreads();
    // copy-out: each wave streams whole bucket runs -> contiguous global bursts
    for (int j = wv; j < NB; j += 8) {
        int c = lh[j];
        int sb = lstart[j];
        int gb = lb[j];
        for (int i = lane; i < c; i += 64)
            ebuf[gb + i] = stage[sb + i];
    }
}

// dense CSR fill: one block per 128-node bucket. Two streaming passes over the
// bucket's packed ebuf segment; LDS staging -> coalesced full-line csr writes.
__global__ __launch_bounds__(256) void k_fill3(const int* __restrict__ ebuf,
                                               const int* __restrict__ boff, int NB,
                                               int* __restrict__ rs, int* __restrict__ csr,
                                               int N) {
    __shared__ int hist[128];
    __shared__ int offs[129];
    __shared__ int curl[128];
    __shared__ int scn[128];
    __shared__ int stage[FCAP];
    int b = blockIdx.x;
    if (b >= NB) return;
    int lo = boff[b], hi = boff[b + 1];
    int cnt = hi - lo;
    int base = b << 7;
    int t = threadIdx.x;
    for (int i = t; i < 128; i += 256) { hist[i] = 0; curl[i] = 0; }
    __syncthreads();
    // pass 1: count
    for (int e = lo + t; e < hi; e += 256) {
        int v = ebuf[e];
        atomicAdd(&hist[v & 127], 1);
    }
    __syncthreads();
    // parallel exclusive scan of hist -> offs (Hillis-Steele over 128)
    if (t < 128) scn[t] = hist[t];
    __syncthreads();
    for (int off = 1; off < 128; off <<= 1) {
        int v = (t >= off && t < 128) ? scn[t - off] : 0;
        __syncthreads();
        if (t < 128) scn[t] += v;
        __syncthreads();
    }
    if (t < 128) offs[t] = scn[t] - hist[t];
    if (t == 0) offs[128] = scn[127];
    __syncthreads();
    // rs offsets (exact; dst < N so nodes >= N have count 0)
    for (int i = t; i < 128; i += 256) {
        int g = base + i;
        if (g < N) rs[g] = lo + offs[i];
    }
    if (b == NB - 1 && t == 0) rs[N] = hi;
    // pass 2: place
    bool staged = (cnt <= FCAP);
    for (int e = lo + t; e < hi; e += 256) {
        int v = ebuf[e];
        int dl = v & 127;
        int sidx = (int)(((unsigned)v) >> 7);
        int p = offs[dl] + atomicAdd(&curl[dl], 1);
        if (staged) stage[p] = sidx;
        else csr[lo + p] = sidx;
    }
    __syncthreads();
    if (staged)
        for (int i = t; i < cnt; i += 256) csr[lo + i] = stage[i];
}

// temp relation (100k edges): padded one-pass fill
__global__ void k_fill2(const int* __restrict__ src, const int* __restrict__ dst, int E,
                        int* __restrict__ cnt, int* __restrict__ csr, int C,
                        int* __restrict__ ovf, int* __restrict__ ovf_n) {
    int i = blockIdx.x * blockDim.x + threadIdx.x;
    if (i >= E) return;
    int s = src[i];
    int d = dst[i];
    int slot = atomicAdd(&cnt[d], 1);
    if (slot < C) {
        csr[(size_t)d * C + slot] = s;
    } else {
        int p = atomicAdd(ovf_n, 1);
        if (p < VO) { ovf[2 * p] = d; ovf[2 * p + 1] = s; }
    }
}

__global__ void k_pad_x(const float* __restrict__ x, float* __restrict__ x8, int N) {
    int i = blockIdx.x * blockDim.x + threadIdx.x;
    if (i >= N * 8) return;
    int n = i >> 3, c = i & 7;
    x8[i] = (c < 6) ? x[n * 6 + c] : 0.0f;
}

// ---------------- gathers ----------------

template <int CHV, int U, bool MASK>
__device__ inline void g_grp(const float* __restrict__ x, int sv, int it0, int nb,
                             int q, int r, float4& acc) {
    const int R = 64 / CHV;
    int s[U];
    float4 v[U];
#pragma unroll
    for (int u = 0; u < U; ++u) s[u] = __shfl(sv, (it0 + u) * R + r, 64);
#pragma unroll
    for (int u = 0; u < U; ++u) v[u] = *(const float4*)(x + (size_t)s[u] * (CHV * 4) + q * 4);
#pragma unroll
    for (int u = 0; u < U; ++u) {
        if (MASK) {
            float m = ((it0 + u) * R + r < nb) ? 1.0f : 0.0f;
            acc.x = fmaf(m, v[u].x, acc.x);
            acc.y = fmaf(m, v[u].y, acc.y);
            acc.z = fmaf(m, v[u].z, acc.z);
            acc.w = fmaf(m, v[u].w, acc.w);
        } else {
            f4add(acc, v[u]);
        }
    }
}

template <int CHV, int U>
__device__ inline float4 gather_one(const float* __restrict__ x, const int* __restrict__ csr,
                                    size_t rowbase, int cnt_c, int lane, int q, int r) {
    const int R = 64 / CHV;
    float4 acc = make_float4(0.f, 0.f, 0.f, 0.f);
    for (int base = 0; base < cnt_c; base += 64) {
        int nb = min(64, cnt_c - base);
        int sv = (lane < nb) ? csr[rowbase + base + lane] : 0;
        int it = 0;
        while ((it + U) * R <= nb) {
            g_grp<CHV, U, false>(x, sv, it, nb, q, r, acc);
            it += U;
        }
        if (it * R < nb) g_grp<CHV, U, true>(x, sv, it, nb, q, r, acc);
    }
    return acc;
}

// group gather: 8 edges per batch from idxv (lane q of group holds edge base+q
// index), 8 row loads in flight, ONE vmcnt(0). xq = h16 + q*4 (lane's slice).
__device__ inline void gat8_h16(const __half* __restrict__ xq, int idxv, int g8,
                                int base, int cif, float4& acc) {
    int s[8];
#pragma unroll
    for (int j = 0; j < 8; ++j) s[j] = __shfl(idxv, g8 + j, 64);
    const __half* a0 = xq + (size_t)s[0] * 32;
    const __half* a1 = xq + (size_t)s[1] * 32;
    const __half* a2 = xq + (size_t)s[2] * 32;
    const __half* a3 = xq + (size_t)s[3] * 32;
    const __half* a4 = xq + (size_t)s[4] * 32;
    const __half* a5 = xq + (size_t)s[5] * 32;
    const __half* a6 = xq + (size_t)s[6] * 32;
    const __half* a7 = xq + (size_t)s[7] * 32;
    vf2 w0, w1, w2, w3, w4, w5, w6, w7;
    asm volatile(
        "global_load_dwordx2 %0, %8, off\n\t"
        "global_load_dwordx2 %1, %9, off\n\t"
        "global_load_dwordx2 %2, %10, off\n\t"
        "global_load_dwordx2 %3, %11, off\n\t"
        "global_load_dwordx2 %4, %12, off\n\t"
        "global_load_dwordx2 %5, %13, off\n\t"
        "global_load_dwordx2 %6, %14, off\n\t"
        "global_load_dwordx2 %7, %15, off\n\t"
        "s_waitcnt vmcnt(0)"
        : "=&v"(w0), "=&v"(w1), "=&v"(w2), "=&v"(w3),
          "=&v"(w4), "=&v"(w5), "=&v"(w6), "=&v"(w7)
        : "v"(a0), "v"(a1), "v"(a2), "v"(a3), "v"(a4), "v"(a5), "v"(a6), "v"(a7)
        : "memory");
    float4 v0 = cvt8(w0), v1 = cvt8(w1), v2 = cvt8(w2), v3 = cvt8(w3);
    float4 v4 = cvt8(w4), v5 = cvt8(w5), v6 = cvt8(w6), v7 = cvt8(w7);
    if (base + 8 <= cif) {
        acc.x += (v0.x + v1.x) + (v2.x + v3.x) + (v4.x + v5.x) + (v6.x + v7.x);
        acc.y += (v0.y + v1.y) + (v2.y + v3.y) + (v4.y + v5.y) + (v6.y + v7.y);
        acc.z += (v0.z + v1.z) + (v2.z + v3.z) + (v4.z + v5.z) + (v6.z + v7.z);
        acc.w += (v0.w + v1.w) + (v2.w + v3.w) + (v4.w + v5.w) + (v6.w + v7.w);
    } else {
        float4 vv[8] = {v0, v1, v2, v3, v4, v5, v6, v7};
#pragma unroll
        for (int j = 0; j < 8; ++j) {
            float m = (base + j < cif) ? 1.0f : 0.0f;
            acc.x = fmaf(m, vv[j].x, acc.x);
            acc.y = fmaf(m, vv[j].y, acc.y);
            acc.z = fmaf(m, vv[j].z, acc.z);
            acc.w = fmaf(m, vv[j].w, acc.w);
        }
    }
}

template <int CHV>
__device__ inline void ovf_add(const float* __restrict__ x, const int* __restrict__ ovf, int n,
                               int g, int q, int r, float4& acc) {
    for (int j = 0; j < n; ++j) {
        int d = ovf[2 * j];
        if (d == g) {
            int s = ovf[2 * j + 1];
            if (r == 0) f4add(acc, *(const float4*)(x + (size_t)s * (CHV * 4) + q * 4));
        }
    }
}

template <int CHV>
__device__ inline void reduce4(float4& a) {
#pragma unroll
    for (int st = CHV; st < 64; st <<= 1) {
        a.x += __shfl_xor(a.x, st, 64);
        a.y += __shfl_xor(a.y, st, 64);
        a.z += __shfl_xor(a.z, st, 64);
        a.w += __shfl_xor(a.w, st, 64);
    }
}

// head gather: 8ch padded rows -> agg8[n][16] = [aggi*inv | aggt]
__global__ __launch_bounds__(256) void k_gather_head(
    const float* __restrict__ x8, const int* __restrict__ csr_i, const int* __restrict__ rs,
    const int* __restrict__ csr_t, const int* __restrict__ cnt_t, int Ct,
    const int* __restrict__ ovf_t, const int* __restrict__ ovfn,
    float* __restrict__ agg8, int N) {
    int tid = blockIdx.x * blockDim.x + threadIdx.x;
    int g = tid >> 6;
    if (g >= N) return;
    int lane = threadIdx.x & 63;
    int q = lane & 1, r = lane >> 1;
    int e0 = rs[g], e1 = rs[g + 1];
    int cif = e1 - e0;
    int ctf = cnt_t[g], ct = min(ctf, Ct);
    float4 ai = gather_one<2, 2>(x8, csr_i, (size_t)e0, cif, lane, q, r);
    float4 at = gather_one<2, 1>(x8, csr_t, (size_t)g * Ct, ct, lane, q, r);
    if (ctf > Ct) ovf_add<2>(x8, ovf_t, min(ovfn[1], VO), g, q, r, at);
    reduce4<2>(ai);
    reduce4<2>(at);
    float inv = 1.0f / (float)max(cif, 1);
    if (r == 0) {
        *(float4*)(agg8 + (size_t)g * 16 + q * 4) =
            make_float4(ai.x * inv, ai.y * inv, ai.z * inv, ai.w * inv);
    } else if (r == 1) {
        *(float4*)(agg8 + (size_t)g * 16 + 8 + q * 4) = at;
    }
}

// hidden gather, GROUP-per-node: 8 lanes per node, 8 nodes per wave.
// lane (q, r): channels 4q..4q+3 of node wavebase+r. No cross-lane reduction.
__global__ __launch_bounds__(256) void k_gather32(
    const __half* __restrict__ h16, const float* __restrict__ hin,
    const int* __restrict__ csr_i, const int* __restrict__ rs,
    const int* __restrict__ csr_t, const int* __restrict__ cnt_t, int Ct,
    const int* __restrict__ ovf_t, const int* __restrict__ ovfn,
    float* __restrict__ agg, int N) {
    int tid = blockIdx.x * blockDim.x + threadIdx.x;
    int lane = tid & 63;
    int q = lane & 7, r = lane >> 3;
    int g8 = lane & 56;                 // group base lane = r*8
    int nbase = (tid >> 6) << 3;        // 8 nodes per wave
    int n = nbase + r;
    bool valid = (n < N);
    // rs[nbase..nbase+8] via lanes 0..8; cnt_t[nbase..nbase+7] via lanes 0..7
    int rv = 0, cv = 0;
    if (lane < 9) rv = rs[min(nbase + lane, N)];
    if (lane < 8) cv = cnt_t[min(nbase + lane, N - 1)];
    int e0 = __shfl(rv, r, 64);
    int e1 = __shfl(rv, r + 1, 64);
    int ctf = __shfl(cv, r, 64);
    int cif = e1 - e0;
    int ct = min(ctf, Ct);
    const __half* xq = h16 + q * 4;     // lane's 8-byte channel slice
    // inter relation (mean)
    float4 ai = make_float4(0.f, 0.f, 0.f, 0.f);
    for (int base = 0; base < cif; base += 8) {
        int idxv = csr_i[min(e0 + base + q, e1 - 1)];
        gat8_h16(xq, idxv, g8, base, cif, ai);
    }
    // temp relation (sum)
    float4 at = make_float4(0.f, 0.f, 0.f, 0.f);
    for (int base = 0; base < ct; base += 8) {
        int idxv = csr_t[(size_t)n * Ct + min(base + q, ct - 1)];
        gat8_h16(xq, idxv, g8, base, ct, at);
    }
    if (valid && ctf > Ct) {
        int no = min(ovfn[1], VO);
        for (int j = 0; j < no; ++j) {
            int d = ovf_t[2 * j];
            if (d == n) {
                int s = ovf_t[2 * j + 1];
                f4add(at, *(const float4*)(hin + (size_t)s * 32 + q * 4));
            }
        }
    }
    if (valid) {
        float inv = 1.0f / (float)max(cif, 1);
        *(float4*)(agg + (size_t)n * 64 + q * 4) =
            make_float4(ai.x * inv, ai.y * inv, ai.z * inv, ai.w * inv);
        *(float4*)(agg + (size_t)n * 64 + 32 + q * 4) = at;
    }
}

// ---------------- per-node GEMM kernels (weights wave-uniform) ----------------

// seg: 32 input channels; OC outputs with row stride STR (W column offset
// already applied by caller). Weights stay SGPR-loaded (W wave-uniform).
template <int OC, int STR>
__device__ inline void gemm_seg2(const float* __restrict__ seg, const float* __restrict__ W,
                                 float* acc) {
#pragma unroll 2
    for (int k4 = 0; k4 < 8; ++k4) {
        float4 a = ((const float4*)seg)[k4];
        float av[4] = {a.x, a.y, a.z, a.w};
#pragma unroll
        for (int i = 0; i < 4; ++i) {
            const float* Wk = W + (k4 * 4 + i) * STR;
#pragma unroll
            for (int c = 0; c < OC; ++c) acc[c] = fmaf(av[i], Wk[c], acc[c]);
        }
    }
}

// 2-way wave split head: wave parity selects output-channel half. acc[16].
__global__ __launch_bounds__(256) void k_gemm_head(
    const float* __restrict__ agg8, const float* __restrict__ x8,
    const float* __restrict__ Wt, const float* __restrict__ Wi, const float* __restrict__ Wr,
    const float* __restrict__ b, float* __restrict__ hout, __half* __restrict__ h16, int N) {
    int tid = blockIdx.x * blockDim.x + threadIdx.x;
    int lane = tid & 63;
    int n = ((tid >> 7) << 6) + lane;
    if (n >= N) return;
    int co = __builtin_amdgcn_readfirstlane(((tid >> 6) & 1) << 4);
    float acc[16];
#pragma unroll
    for (int c = 0; c < 16; ++c) acc[c] = b[co + c];
    float4 ai0 = ((const float4*)(agg8 + (size_t)n * 16))[0];
    float4 ai1 = ((const float4*)(agg8 + (size_t)n * 16))[1];
    float4 at0 = ((const float4*)(agg8 + (size_t)n * 16 + 8))[0];
    float4 at1 = ((const float4*)(agg8 + (size_t)n * 16 + 8))[1];
    float4 xv0 = ((const float4*)(x8 + (size_t)n * 8))[0];
    float4 xv1 = ((const float4*)(x8 + (size_t)n * 8))[1];
    float a_i[6] = {ai0.x, ai0.y, ai0.z, ai0.w, ai1.x, ai1.y};
    float a_t[6] = {at0.x, at0.y, at0.z, at0.w, at1.x, at1.y};
    float a_x[6] = {xv0.x, xv0.y, xv0.z, xv0.w, xv1.x, xv1.y};
#pragma unroll
    for (int k = 0; k < 6; ++k) {
        const float* Wtk = Wt + k * 32 + co;
        const float* Wik = Wi + k * 32 + co;
        const float* Wrk = Wr + k * 32 + co;
#pragma unroll
        for (int c = 0; c < 16; ++c)
            acc[c] = fmaf(a_t[k], Wtk[c], fmaf(a_i[k], Wik[c], fmaf(a_x[k], Wrk[c], acc[c])));
    }
    float rv[16];
#pragma unroll
    for (int c = 0; c < 16; ++c) rv[c] = fmaxf(acc[c], 0.f);
    float* O = hout + (size_t)n * 32 + co;
#pragma unroll
    for (int c4 = 0; c4 < 4; ++c4)
        ((float4*)O)[c4] = make_float4(rv[c4 * 4 + 0], rv[c4 * 4 + 1],
                                       rv[c4 * 4 + 2], rv[c4 * 4 + 3]);
    __half2 hp[8];
#pragma unroll
    for (int i = 0; i < 8; ++i) hp[i] = __float22half2_rn(make_float2(rv[2 * i], rv[2 * i + 1]));
    uint4* D = (uint4*)(h16 + (size_t)n * 32 + co);
    const uint4* S = (const uint4*)hp;
#pragma unroll
    for (int i = 0; i < 2; ++i) D[i] = S[i];
}

// wave-pair split: wave parity selects output-channel half (co SGPR-uniform),
// node n = 64*(wavepair) + lane. acc[16] -> no spill, 2x waves in flight.
__global__ __launch_bounds__(256) void k_gemm_blk(
    const float* __restrict__ agg, const float* __restrict__ hin,
    const float* __restrict__ Wt, const float* __restrict__ Wi, const float* __restrict__ Wr,
    const float* __restrict__ b, float* __restrict__ hout, __half* __restrict__ h16, int N) {
    int tid = blockIdx.x * blockDim.x + threadIdx.x;
    int lane = tid & 63;
    int n = ((tid >> 7) << 6) + lane;
    if (n >= N) return;
    int co = __builtin_amdgcn_readfirstlane(((tid >> 6) & 1) << 4);
    float acc[16];
#pragma unroll
    for (int c = 0; c < 16; ++c) acc[c] = b[co + c];
    const float* Ai = agg + (size_t)n * 64;
    const float* At = Ai + 32;
    const float* H = hin + (size_t)n * 32;
    gemm_seg2<16, 32>(At, Wt + co, acc);
    gemm_seg2<16, 32>(Ai, Wi + co, acc);
    gemm_seg2<16, 32>(H, Wr + co, acc);
    const float* Hc = H + co;
    float rv[16];
#pragma unroll
    for (int c4 = 0; c4 < 4; ++c4) {
        float4 hv = ((const float4*)Hc)[c4];
        rv[c4 * 4 + 0] = fmaxf(acc[c4 * 4 + 0], 0.f) + hv.x;
        rv[c4 * 4 + 1] = fmaxf(acc[c4 * 4 + 1], 0.f) + hv.y;
        rv[c4 * 4 + 2] = fmaxf(acc[c4 * 4 + 2], 0.f) + hv.z;
        rv[c4 * 4 + 3] = fmaxf(acc[c4 * 4 + 3], 0.f) + hv.w;
    }
    float* O = hout + (size_t)n * 32 + co;
#pragma unroll
    for (int c4 = 0; c4 < 4; ++c4)
        ((float4*)O)[c4] = make_float4(rv[c4 * 4 + 0], rv[c4 * 4 + 1],
                                       rv[c4 * 4 + 2], rv[c4 * 4 + 3]);
    __half2 hp[8];
#pragma unroll
    for (int i = 0; i < 8; ++i) hp[i] = __float22half2_rn(make_float2(rv[2 * i], rv[2 * i + 1]));
    uint4* D = (uint4*)(h16 + (size_t)n * 32 + co);
    const uint4* S = (const uint4*)hp;
#pragma unroll
    for (int i = 0; i < 2; ++i) D[i] = S[i];
}

// 4-way wave split: wave&3 selects 16-channel output slice of 64. acc[16].
__global__ __launch_bounds__(256) void k_gemm_last(
    const float* __restrict__ agg, const float* __restrict__ hin,
    const float* __restrict__ Wt, const float* __restrict__ Wi, const float* __restrict__ Wr,
    const float* __restrict__ b, const float* __restrict__ proj, float* __restrict__ out, int N) {
    int tid = blockIdx.x * blockDim.x + threadIdx.x;
    int lane = tid & 63;
    int w = tid >> 6;
    int n = ((w >> 2) << 6) + lane;
    if (n >= N) return;
    int co = __builtin_amdgcn_readfirstlane((w & 3) << 4);
    float acc[16];
#pragma unroll
    for (int c = 0; c < 16; ++c) acc[c] = b[co + c];
    const float* Ai = agg + (size_t)n * 64;
    const float* At = Ai + 32;
    const float* H = hin + (size_t)n * 32;
    gemm_seg2<16, 64>(At, Wt + co, acc);
    gemm_seg2<16, 64>(Ai, Wi + co, acc);
    gemm_seg2<16, 64>(H, Wr + co, acc);
#pragma unroll
    for (int c = 0; c < 16; ++c) acc[c] = fmaxf(acc[c], 0.f);
    gemm_seg2<16, 64>(H, proj + co, acc);
    float* O = out + (size_t)n * 64 + co;
#pragma unroll
    for (int c4 = 0; c4 < 4; ++c4)
        ((float4*)O)[c4] = make_float4(acc[c4 * 4 + 0], acc[c4 * 4 + 1],
                                       acc[c4 * 4 + 2], acc[c4 * 4 + 3]);
}

// ---------------- launch ----------------

static inline size_t align256(size_t x) { return (x + 255) & ~(size_t)255; }

extern "C" void kernel_launch(void* const* d_in, const int* in_sizes, int n_in,
                              void* d_out, int out_size, void* d_ws, size_t ws_size,
                              hipStream_t stream) {
    const float* x_stroke = (const float*)d_in[0];
    const int* ei_temp = (const int*)d_in[1];
    const int* ei_inter = (const int*)d_in[2];
    const float* head_Wt = (const float*)d_in[3];
    const float* head_Wi = (const float*)d_in[4];
    const float* head_Wr = (const float*)d_in[5];
    const float* head_b = (const float*)d_in[6];
    const float* blk_Wt = (const float*)d_in[7];
    const float* blk_Wi = (const float*)d_in[8];
    const float* blk_Wr = (const float*)d_in[9];
    const float* blk_b = (const float*)d_in[10];
    const float* last_Wt = (const float*)d_in[11];
    const float* last_Wi = (const float*)d_in[12];
    const float* last_Wr = (const float*)d_in[13];
    const float* last_b = (const float*)d_in[14];
    const float* last_proj = (const float*)d_in[15];

    const int N = in_sizes[0] / 6;
    const int Et = in_sizes[1] / 2;
    const int Ei = in_sizes[2] / 2;

    const int* temp_src = ei_temp;
    const int* temp_dst = ei_temp + Et;
    const int* int_src = ei_inter;
    const int* int_dst = ei_inter + Ei;

    const int shift = 7;                      // 128-node buckets
    const int NB = ((N - 1) >> shift) + 1;    // assumes N <= 131072

    char* p = (char*)d_ws;
    size_t off = 0;
    auto carve = [&](size_t bytes) {
        char* r = p + off;
        off = align256(off + bytes);
        return r;
    };
    // zero-init block: cnt_t, ovfn, gh contiguous -> ONE memset
    int* cnt_t = (int*)carve((size_t)N * 4);
    int* ovfn = (int*)carve(2 * 4);
    int* gh = (int*)carve((size_t)NB * 4);
    size_t zspan = (size_t)((char*)gh + (size_t)NB * 4 - (char*)cnt_t);
    int* ovf_t = (int*)carve((size_t)VO * 8);
    int* boff = (int*)carve((size_t)(NB + 1) * 4);
    int* cur = (int*)carve((size_t)NB * 4);
    int* rs = (int*)carve((size_t)(N + 1) * 4);
    float* x8 = (float*)carve((size_t)N * 8 * 4);
    float* bufA = (float*)carve((size_t)N * 32 * 4);
    float* bufD = (float*)carve((size_t)N * 32 * 4);
    float* agg = (float*)carve((size_t)N * 64 * 4);   // also holds agg8 [N,16]
    __half* h16 = (__half*)carve((size_t)N * 32 * 2); // fp16 gather staging
    int* ebuf = (int*)carve((size_t)Ei * 4);          // packed (src<<7 | dst&127)
    int* csr_i = (int*)carve((size_t)Ei * 4);         // dense
    const int Ct = 16;
    int* csr_t = (int*)carve((size_t)N * Ct * 4);
    (void)ws_size;

    const int B = 256;
    auto blocks = [&](long long work) { return (int)((work + B - 1) / B); };

    hipMemsetAsync(cnt_t, 0, zspan, stream);

    k_hist<<<256, B, 0, stream>>>(int_dst, Ei, gh, NB, shift);
    k_scan_b<<<1, 1024, 0, stream>>>(gh, NB, boff, cur);
    k_scatter<<<(int)((Ei + SCAT_SPAN - 1) / SCAT_SPAN), SCAT_THR, 0, stream>>>(
        int_src, int_dst, Ei, shift, NB, cur, ebuf);
    k_fill3<<<NB, B, 0, stream>>>(ebuf, boff, NB, rs, csr_i, N);
    k_fill2<<<blocks(Et), B, 0, stream>>>(temp_src, temp_dst, Et, cnt_t, csr_t, Ct, ovf_t, &ovfn[1]);
    k_pad_x<<<blocks((long long)N * 8), B, 0, stream>>>(x_stroke, x8, N);

    // wave-split GEMM grids
    const int gw2 = 2 * ((N + 63) >> 6);              // 2 waves per 64 nodes
    const int gblocks2 = ((gw2 << 6) + B - 1) / B;
    const int gw4 = 4 * ((N + 63) >> 6);              // 4 waves per 64 nodes
    const int gblocks4 = ((gw4 << 6) + B - 1) / B;
    // group-per-node gather grid: 8 nodes per wave
    const int gatherW = (N + 7) >> 3;
    const int gatherBlocks = (int)(((long long)gatherW * 64 + B - 1) / B);

    // head
    k_gather_head<<<blocks((long long)N * 64), B, 0, stream>>>(
        x8, csr_i, rs, csr_t, cnt_t, Ct, ovf_t, ovfn, agg, N);
    k_gemm_head<<<gblocks2, B, 0, stream>>>(agg, x8, head_Wt, head_Wi, head_Wr, head_b,
                                            bufA, h16, N);

    // 3 hidden residual blocks
    float* hin = bufA;
    float* hout = bufD;
    for (int i = 0; i < 3; ++i) {
        k_gather32<<<gatherBlocks, B, 0, stream>>>(
            h16, hin, csr_i, rs, csr_t, cnt_t, Ct, ovf_t, ovfn, agg, N);
        k_gemm_blk<<<gblocks2, B, 0, stream>>>(
            agg, hin, blk_Wt + (size_t)i * 32 * 32, blk_Wi + (size_t)i * 32 * 32,
            blk_Wr + (size_t)i * 32 * 32, blk_b + (size_t)i * 32, hout, h16, N);
        float* t = hin; hin = hout; hout = t;
    }

    // last
    k_gather32<<<gatherBlocks, B, 0, stream>>>(
        h16, hin, csr_i, rs, csr_t, cnt_t, Ct, ovf_t, ovfn, agg, N);
    k_gemm_last<<<gblocks4, B, 0, stream>>>(agg, hin, last_Wt, last_Wi, last_Wr, last_b,
                                            last_proj, (float*)d_out, N);
}

// Round 7
// 520.263 us; speedup vs baseline: 1.1988x; 1.0183x over previous
//
#include <hip/hip_runtime.h>
#include <hip/hip_fp16.h>

// Hetero-GNN: 5 layers of relu(segsum_temp(x)@Wt + segmean_inter(x)@Wi + x@Wr + b)
// (aggregation commuted past the matmuls).
//
// R16 (on top of R15):
//  - k_gather_head restructured wave-per-node -> THREAD-per-node. R6 counters:
//    HBM 8.7%, VALU 42% at 53 us -> same fixed-overhead disease R15 cured in
//    k_gather32 (reduce trees + 64-row loop quantization at mean degree 32).
//    Rows are only 32 B (x8 fp32), so one lane holds the full 8-ch accumulator
//    pair; walks its contiguous CSR segment in batches of 4 (4 idx + 8 float4
//    loads in flight); zero cross-lane ops; direct float4 stores.

#define VO 8192        // overflow list capacity (pairs), temp relation
#define FCAP 10240     // staged edges per bucket in k_fill3 (40 KB LDS)
#define SCAT_THR 512
#define SCAT_SPAN 8192 // edges per scatter block (32 KB LDS stage)

typedef float vf4 __attribute__((ext_vector_type(4)));
typedef float vf2 __attribute__((ext_vector_type(2)));

__device__ inline void f4add(float4& a, const float4& v) {
    a.x += v.x; a.y += v.y; a.z += v.z; a.w += v.w;
}

__device__ inline float4 cvt8(vf2 v) {
    union { vf2 f; __half2 h[2]; } u;
    u.f = v;
    float2 a = __half22float2(u.h[0]);
    float2 b = __half22float2(u.h[1]);
    return make_float4(a.x, a.y, b.x, b.y);
}

// ---------------- build: hist -> scan -> scatter -> dense fill ----------------

__global__ void k_hist(const int* __restrict__ dst, int E, int* __restrict__ gh,
                       int NB, int shift) {
    __shared__ int sh[1024];
    for (int j = threadIdx.x; j < NB; j += blockDim.x) sh[j] = 0;
    __syncthreads();
    for (int i = blockIdx.x * blockDim.x + threadIdx.x; i < E; i += gridDim.x * blockDim.x)
        atomicAdd(&sh[dst[i] >> shift], 1);
    __syncthreads();
    for (int j = threadIdx.x; j < NB; j += blockDim.x)
        if (sh[j]) atomicAdd(&gh[j], sh[j]);
}

__global__ void k_scan_b(const int* __restrict__ gh, int NB, int* __restrict__ boff,
                         int* __restrict__ cur) {
    __shared__ int sh[1024];
    int t = threadIdx.x;
    sh[t] = (t < NB) ? gh[t] : 0;
    __syncthreads();
    for (int off = 1; off < 1024; off <<= 1) {
        int v = (t >= off) ? sh[t - off] : 0;
        __syncthreads();
        sh[t] += v;
        __syncthreads();
    }
    if (t < NB) {
        int ex = t ? sh[t - 1] : 0;
        boff[t] = ex;
        cur[t] = ex;
    }
    if (t == 0) boff[NB] = sh[NB - 1];
}

// write-combined scatter: count -> scan -> chunk alloc -> rank into LDS stage
// (bucket-major) -> burst copy-out. Packed payload (src<<shift | dst&mask).
__global__ __launch_bounds__(512) void k_scatter(const int* __restrict__ src,
                                                 const int* __restrict__ dst, int E,
                                                 int shift, int NB, int* __restrict__ cur,
                                                 int* __restrict__ ebuf) {
    __shared__ int lh[1024];     // per-bucket counts
    __shared__ int lb[1024];     // per-bucket global base (chunk alloc)
    __shared__ int lstart[1024]; // per-bucket LDS stage start (exclusive scan)
    __shared__ int lcur[1024];   // ranking cursors
    __shared__ int wsum[8];
    __shared__ int stage[SCAT_SPAN];
    const int t = threadIdx.x;
    const int lane = t & 63;
    const int wv = t >> 6;
    int lo = blockIdx.x * SCAT_SPAN;
    int hi = min(E, lo + SCAT_SPAN);
    for (int j = t; j < 1024; j += 512) lh[j] = 0;
    __syncthreads();
    // pass A: count
    for (int e = lo + t; e < hi; e += 512)
        atomicAdd(&lh[dst[e] >> shift], 1);
    __syncthreads();
    // exclusive scan of lh[0..1023] -> lstart (2 elems/thread, wave shfl scan)
    int a0 = lh[2 * t], a1 = lh[2 * t + 1];
    int ts = a0 + a1;
    int run = ts;
#pragma unroll
    for (int off = 1; off < 64; off <<= 1) {
        int v = __shfl_up(run, off, 64);
        if (lane >= off) run += v;
    }
    if (lane == 63) wsum[wv] = run;
    __syncthreads();
    int wpre = 0;
#pragma unroll
    for (int w = 0; w < 8; ++w) wpre += (w < wv) ? wsum[w] : 0;
    int excl = wpre + run - ts;
    lstart[2 * t] = excl;
    lstart[2 * t + 1] = excl + a0;
    lcur[2 * t] = excl;
    lcur[2 * t + 1] = excl + a0;
    // global chunk alloc (contiguous per bucket via cur[] cursors)
    for (int j = t; j < NB; j += 512) {
        int c = lh[j];
        lb[j] = c ? atomicAdd(&cur[j], c) : 0;
    }
    __syncthreads();
    // pass B: re-read + rank into bucket-major LDS stage
    const int mask = (1 << shift) - 1;
    for (int e = lo + t; e < hi; e += 512) {
        int s = src[e];
        int d = dst[e];
        int p = atomicAdd(&lcur[d >> shift], 1);
        stage[p] = (s << shift) | (d & mask);
    }
    __syncthreads();
    // copy-out: each wave streams whole bucket runs -> contiguous global bursts
    for (int j = wv; j < NB; j += 8) {
        int c = lh[j];
        int sb = lstart[j];
        int gb = lb[j];
        for (int i = lane; i < c; i += 64)
            ebuf[gb + i] = stage[sb + i];
    }
}

// dense CSR fill: one block per 128-node bucket. Two streaming passes over the
// bucket's packed ebuf segment; LDS staging -> coalesced full-line csr writes.
__global__ __launch_bounds__(256) void k_fill3(const int* __restrict__ ebuf,
                                               const int* __restrict__ boff, int NB,
                                               int* __restrict__ rs, int* __restrict__ csr,
                                               int N) {
    __shared__ int hist[128];
    __shared__ int offs[129];
    __shared__ int curl[128];
    __shared__ int scn[128];
    __shared__ int stage[FCAP];
    int b = blockIdx.x;
    if (b >= NB) return;
    int lo = boff[b], hi = boff[b + 1];
    int cnt = hi - lo;
    int base = b << 7;
    int t = threadIdx.x;
    for (int i = t; i < 128; i += 256) { hist[i] = 0; curl[i] = 0; }
    __syncthreads();
    // pass 1: count
    for (int e = lo + t; e < hi; e += 256) {
        int v = ebuf[e];
        atomicAdd(&hist[v & 127], 1);
    }
    __syncthreads();
    // parallel exclusive scan of hist -> offs (Hillis-Steele over 128)
    if (t < 128) scn[t] = hist[t];
    __syncthreads();
    for (int off = 1; off < 128; off <<= 1) {
        int v = (t >= off && t < 128) ? scn[t - off] : 0;
        __syncthreads();
        if (t < 128) scn[t] += v;
        __syncthreads();
    }
    if (t < 128) offs[t] = scn[t] - hist[t];
    if (t == 0) offs[128] = scn[127];
    __syncthreads();
    // rs offsets (exact; dst < N so nodes >= N have count 0)
    for (int i = t; i < 128; i += 256) {
        int g = base + i;
        if (g < N) rs[g] = lo + offs[i];
    }
    if (b == NB - 1 && t == 0) rs[N] = hi;
    // pass 2: place
    bool staged = (cnt <= FCAP);
    for (int e = lo + t; e < hi; e += 256) {
        int v = ebuf[e];
        int dl = v & 127;
        int sidx = (int)(((unsigned)v) >> 7);
        int p = offs[dl] + atomicAdd(&curl[dl], 1);
        if (staged) stage[p] = sidx;
        else csr[lo + p] = sidx;
    }
    __syncthreads();
    if (staged)
        for (int i = t; i < cnt; i += 256) csr[lo + i] = stage[i];
}

// temp relation (100k edges): padded one-pass fill
__global__ void k_fill2(const int* __restrict__ src, const int* __restrict__ dst, int E,
                        int* __restrict__ cnt, int* __restrict__ csr, int C,
                        int* __restrict__ ovf, int* __restrict__ ovf_n) {
    int i = blockIdx.x * blockDim.x + threadIdx.x;
    if (i >= E) return;
    int s = src[i];
    int d = dst[i];
    int slot = atomicAdd(&cnt[d], 1);
    if (slot < C) {
        csr[(size_t)d * C + slot] = s;
    } else {
        int p = atomicAdd(ovf_n, 1);
        if (p < VO) { ovf[2 * p] = d; ovf[2 * p + 1] = s; }
    }
}

__global__ void k_pad_x(const float* __restrict__ x, float* __restrict__ x8, int N) {
    int i = blockIdx.x * blockDim.x + threadIdx.x;
    if (i >= N * 8) return;
    int n = i >> 3, c = i & 7;
    x8[i] = (c < 6) ? x[n * 6 + c] : 0.0f;
}

// ---------------- gathers ----------------

// group gather: 8 edges per batch from idxv (lane q of group holds edge base+q
// index), 8 row loads in flight, ONE vmcnt(0). xq = h16 + q*4 (lane's slice).
__device__ inline void gat8_h16(const __half* __restrict__ xq, int idxv, int g8,
                                int base, int cif, float4& acc) {
    int s[8];
#pragma unroll
    for (int j = 0; j < 8; ++j) s[j] = __shfl(idxv, g8 + j, 64);
    const __half* a0 = xq + (size_t)s[0] * 32;
    const __half* a1 = xq + (size_t)s[1] * 32;
    const __half* a2 = xq + (size_t)s[2] * 32;
    const __half* a3 = xq + (size_t)s[3] * 32;
    const __half* a4 = xq + (size_t)s[4] * 32;
    const __half* a5 = xq + (size_t)s[5] * 32;
    const __half* a6 = xq + (size_t)s[6] * 32;
    const __half* a7 = xq + (size_t)s[7] * 32;
    vf2 w0, w1, w2, w3, w4, w5, w6, w7;
    asm volatile(
        "global_load_dwordx2 %0, %8, off\n\t"
        "global_load_dwordx2 %1, %9, off\n\t"
        "global_load_dwordx2 %2, %10, off\n\t"
        "global_load_dwordx2 %3, %11, off\n\t"
        "global_load_dwordx2 %4, %12, off\n\t"
        "global_load_dwordx2 %5, %13, off\n\t"
        "global_load_dwordx2 %6, %14, off\n\t"
        "global_load_dwordx2 %7, %15, off\n\t"
        "s_waitcnt vmcnt(0)"
        : "=&v"(w0), "=&v"(w1), "=&v"(w2), "=&v"(w3),
          "=&v"(w4), "=&v"(w5), "=&v"(w6), "=&v"(w7)
        : "v"(a0), "v"(a1), "v"(a2), "v"(a3), "v"(a4), "v"(a5), "v"(a6), "v"(a7)
        : "memory");
    float4 v0 = cvt8(w0), v1 = cvt8(w1), v2 = cvt8(w2), v3 = cvt8(w3);
    float4 v4 = cvt8(w4), v5 = cvt8(w5), v6 = cvt8(w6), v7 = cvt8(w7);
    if (base + 8 <= cif) {
        acc.x += (v0.x + v1.x) + (v2.x + v3.x) + (v4.x + v5.x) + (v6.x + v7.x);
        acc.y += (v0.y + v1.y) + (v2.y + v3.y) + (v4.y + v5.y) + (v6.y + v7.y);
        acc.z += (v0.z + v1.z) + (v2.z + v3.z) + (v4.z + v5.z) + (v6.z + v7.z);
        acc.w += (v0.w + v1.w) + (v2.w + v3.w) + (v4.w + v5.w) + (v6.w + v7.w);
    } else {
        float4 vv[8] = {v0, v1, v2, v3, v4, v5, v6, v7};
#pragma unroll
        for (int j = 0; j < 8; ++j) {
            float m = (base + j < cif) ? 1.0f : 0.0f;
            acc.x = fmaf(m, vv[j].x, acc.x);
            acc.y = fmaf(m, vv[j].y, acc.y);
            acc.z = fmaf(m, vv[j].z, acc.z);
            acc.w = fmaf(m, vv[j].w, acc.w);
        }
    }
}

// head gather, THREAD-per-node: lane owns full 8-ch fp32 row accumulators.
// Contiguous CSR segment walked in batches of 4 (4 idx + 8 float4 loads).
__global__ __launch_bounds__(256) void k_gather_head(
    const float* __restrict__ x8, const int* __restrict__ csr_i, const int* __restrict__ rs,
    const int* __restrict__ csr_t, const int* __restrict__ cnt_t, int Ct,
    const int* __restrict__ ovf_t, const int* __restrict__ ovfn,
    float* __restrict__ agg8, int N) {
    int n = blockIdx.x * blockDim.x + threadIdx.x;
    if (n >= N) return;
    int e0 = rs[n], e1 = rs[n + 1];
    int cif = e1 - e0;
    int ctf = cnt_t[n], ct = min(ctf, Ct);
    float4 ai0 = make_float4(0.f, 0.f, 0.f, 0.f), ai1 = ai0;
    for (int base = 0; base < cif; base += 4) {
        int sj[4];
#pragma unroll
        for (int j = 0; j < 4; ++j) sj[j] = csr_i[e0 + min(base + j, cif - 1)];
        float4 lo[4], hi[4];
#pragma unroll
        for (int j = 0; j < 4; ++j) {
            const float4* row = (const float4*)(x8 + (size_t)sj[j] * 8);
            lo[j] = row[0];
            hi[j] = row[1];
        }
#pragma unroll
        for (int j = 0; j < 4; ++j) {
            float m = (base + j < cif) ? 1.0f : 0.0f;
            ai0.x = fmaf(m, lo[j].x, ai0.x);
            ai0.y = fmaf(m, lo[j].y, ai0.y);
            ai0.z = fmaf(m, lo[j].z, ai0.z);
            ai0.w = fmaf(m, lo[j].w, ai0.w);
            ai1.x = fmaf(m, hi[j].x, ai1.x);
            ai1.y = fmaf(m, hi[j].y, ai1.y);
            ai1.z = fmaf(m, hi[j].z, ai1.z);
            ai1.w = fmaf(m, hi[j].w, ai1.w);
        }
    }
    float4 at0 = make_float4(0.f, 0.f, 0.f, 0.f), at1 = at0;
    for (int base = 0; base < ct; base += 4) {
        int sj[4];
#pragma unroll
        for (int j = 0; j < 4; ++j) sj[j] = csr_t[(size_t)n * Ct + min(base + j, ct - 1)];
        float4 lo[4], hi[4];
#pragma unroll
        for (int j = 0; j < 4; ++j) {
            const float4* row = (const float4*)(x8 + (size_t)sj[j] * 8);
            lo[j] = row[0];
            hi[j] = row[1];
        }
#pragma unroll
        for (int j = 0; j < 4; ++j) {
            float m = (base + j < ct) ? 1.0f : 0.0f;
            at0.x = fmaf(m, lo[j].x, at0.x);
            at0.y = fmaf(m, lo[j].y, at0.y);
            at0.z = fmaf(m, lo[j].z, at0.z);
            at0.w = fmaf(m, lo[j].w, at0.w);
            at1.x = fmaf(m, hi[j].x, at1.x);
            at1.y = fmaf(m, hi[j].y, at1.y);
            at1.z = fmaf(m, hi[j].z, at1.z);
            at1.w = fmaf(m, hi[j].w, at1.w);
        }
    }
    if (ctf > Ct) {
        int no = min(ovfn[1], VO);
        for (int j = 0; j < no; ++j) {
            int d = ovf_t[2 * j];
            if (d == n) {
                const float4* row = (const float4*)(x8 + (size_t)ovf_t[2 * j + 1] * 8);
                f4add(at0, row[0]);
                f4add(at1, row[1]);
            }
        }
    }
    float inv = 1.0f / (float)max(cif, 1);
    float4* O = (float4*)(agg8 + (size_t)n * 16);
    O[0] = make_float4(ai0.x * inv, ai0.y * inv, ai0.z * inv, ai0.w * inv);
    O[1] = make_float4(ai1.x * inv, ai1.y * inv, ai1.z * inv, ai1.w * inv);
    O[2] = at0;
    O[3] = at1;
}

// hidden gather, GROUP-per-node: 8 lanes per node, 8 nodes per wave.
// lane (q, r): channels 4q..4q+3 of node wavebase+r. No cross-lane reduction.
__global__ __launch_bounds__(256) void k_gather32(
    const __half* __restrict__ h16, const float* __restrict__ hin,
    const int* __restrict__ csr_i, const int* __restrict__ rs,
    const int* __restrict__ csr_t, const int* __restrict__ cnt_t, int Ct,
    const int* __restrict__ ovf_t, const int* __restrict__ ovfn,
    float* __restrict__ agg, int N) {
    int tid = blockIdx.x * blockDim.x + threadIdx.x;
    int lane = tid & 63;
    int q = lane & 7, r = lane >> 3;
    int g8 = lane & 56;                 // group base lane = r*8
    int nbase = (tid >> 6) << 3;        // 8 nodes per wave
    int n = nbase + r;
    bool valid = (n < N);
    // rs[nbase..nbase+8] via lanes 0..8; cnt_t[nbase..nbase+7] via lanes 0..7
    int rv = 0, cv = 0;
    if (lane < 9) rv = rs[min(nbase + lane, N)];
    if (lane < 8) cv = cnt_t[min(nbase + lane, N - 1)];
    int e0 = __shfl(rv, r, 64);
    int e1 = __shfl(rv, r + 1, 64);
    int ctf = __shfl(cv, r, 64);
    int cif = e1 - e0;
    int ct = min(ctf, Ct);
    const __half* xq = h16 + q * 4;     // lane's 8-byte channel slice
    // inter relation (mean)
    float4 ai = make_float4(0.f, 0.f, 0.f, 0.f);
    for (int base = 0; base < cif; base += 8) {
        int idxv = csr_i[min(e0 + base + q, e1 - 1)];
        gat8_h16(xq, idxv, g8, base, cif, ai);
    }
    // temp relation (sum)
    float4 at = make_float4(0.f, 0.f, 0.f, 0.f);
    for (int base = 0; base < ct; base += 8) {
        int idxv = csr_t[(size_t)n * Ct + min(base + q, ct - 1)];
        gat8_h16(xq, idxv, g8, base, ct, at);
    }
    if (valid && ctf > Ct) {
        int no = min(ovfn[1], VO);
        for (int j = 0; j < no; ++j) {
            int d = ovf_t[2 * j];
            if (d == n) {
                int s = ovf_t[2 * j + 1];
                f4add(at, *(const float4*)(hin + (size_t)s * 32 + q * 4));
            }
        }
    }
    if (valid) {
        float inv = 1.0f / (float)max(cif, 1);
        *(float4*)(agg + (size_t)n * 64 + q * 4) =
            make_float4(ai.x * inv, ai.y * inv, ai.z * inv, ai.w * inv);
        *(float4*)(agg + (size_t)n * 64 + 32 + q * 4) = at;
    }
}

// ---------------- per-node GEMM kernels (weights wave-uniform) ----------------

// seg: 32 input channels; OC outputs with row stride STR (W column offset
// already applied by caller). Weights stay SGPR-loaded (W wave-uniform).
template <int OC, int STR>
__device__ inline void gemm_seg2(const float* __restrict__ seg, const float* __restrict__ W,
                                 float* acc) {
#pragma unroll 2
    for (int k4 = 0; k4 < 8; ++k4) {
        float4 a = ((const float4*)seg)[k4];
        float av[4] = {a.x, a.y, a.z, a.w};
#pragma unroll
        for (int i = 0; i < 4; ++i) {
            const float* Wk = W + (k4 * 4 + i) * STR;
#pragma unroll
            for (int c = 0; c < OC; ++c) acc[c] = fmaf(av[i], Wk[c], acc[c]);
        }
    }
}

// 2-way wave split head: wave parity selects output-channel half. acc[16].
__global__ __launch_bounds__(256) void k_gemm_head(
    const float* __restrict__ agg8, const float* __restrict__ x8,
    const float* __restrict__ Wt, const float* __restrict__ Wi, const float* __restrict__ Wr,
    const float* __restrict__ b, float* __restrict__ hout, __half* __restrict__ h16, int N) {
    int tid = blockIdx.x * blockDim.x + threadIdx.x;
    int lane = tid & 63;
    int n = ((tid >> 7) << 6) + lane;
    if (n >= N) return;
    int co = __builtin_amdgcn_readfirstlane(((tid >> 6) & 1) << 4);
    float acc[16];
#pragma unroll
    for (int c = 0; c < 16; ++c) acc[c] = b[co + c];
    float4 ai0 = ((const float4*)(agg8 + (size_t)n * 16))[0];
    float4 ai1 = ((const float4*)(agg8 + (size_t)n * 16))[1];
    float4 at0 = ((const float4*)(agg8 + (size_t)n * 16 + 8))[0];
    float4 at1 = ((const float4*)(agg8 + (size_t)n * 16 + 8))[1];
    float4 xv0 = ((const float4*)(x8 + (size_t)n * 8))[0];
    float4 xv1 = ((const float4*)(x8 + (size_t)n * 8))[1];
    float a_i[6] = {ai0.x, ai0.y, ai0.z, ai0.w, ai1.x, ai1.y};
    float a_t[6] = {at0.x, at0.y, at0.z, at0.w, at1.x, at1.y};
    float a_x[6] = {xv0.x, xv0.y, xv0.z, xv0.w, xv1.x, xv1.y};
#pragma unroll
    for (int k = 0; k < 6; ++k) {
        const float* Wtk = Wt + k * 32 + co;
        const float* Wik = Wi + k * 32 + co;
        const float* Wrk = Wr + k * 32 + co;
#pragma unroll
        for (int c = 0; c < 16; ++c)
            acc[c] = fmaf(a_t[k], Wtk[c], fmaf(a_i[k], Wik[c], fmaf(a_x[k], Wrk[c], acc[c])));
    }
    float rv[16];
#pragma unroll
    for (int c = 0; c < 16; ++c) rv[c] = fmaxf(acc[c], 0.f);
    float* O = hout + (size_t)n * 32 + co;
#pragma unroll
    for (int c4 = 0; c4 < 4; ++c4)
        ((float4*)O)[c4] = make_float4(rv[c4 * 4 + 0], rv[c4 * 4 + 1],
                                       rv[c4 * 4 + 2], rv[c4 * 4 + 3]);
    __half2 hp[8];
#pragma unroll
    for (int i = 0; i < 8; ++i) hp[i] = __float22half2_rn(make_float2(rv[2 * i], rv[2 * i + 1]));
    uint4* D = (uint4*)(h16 + (size_t)n * 32 + co);
    const uint4* S = (const uint4*)hp;
#pragma unroll
    for (int i = 0; i < 2; ++i) D[i] = S[i];
}

// wave-pair split: wave parity selects output-channel half (co SGPR-uniform),
// node n = 64*(wavepair) + lane. acc[16] -> no spill, 2x waves in flight.
__global__ __launch_bounds__(256) void k_gemm_blk(
    const float* __restrict__ agg, const float* __restrict__ hin,
    const float* __restrict__ Wt, const float* __restrict__ Wi, const float* __restrict__ Wr,
    const float* __restrict__ b, float* __restrict__ hout, __half* __restrict__ h16, int N) {
    int tid = blockIdx.x * blockDim.x + threadIdx.x;
    int lane = tid & 63;
    int n = ((tid >> 7) << 6) + lane;
    if (n >= N) return;
    int co = __builtin_amdgcn_readfirstlane(((tid >> 6) & 1) << 4);
    float acc[16];
#pragma unroll
    for (int c = 0; c < 16; ++c) acc[c] = b[co + c];
    const float* Ai = agg + (size_t)n * 64;
    const float* At = Ai + 32;
    const float* H = hin + (size_t)n * 32;
    gemm_seg2<16, 32>(At, Wt + co, acc);
    gemm_seg2<16, 32>(Ai, Wi + co, acc);
    gemm_seg2<16, 32>(H, Wr + co, acc);
    const float* Hc = H + co;
    float rv[16];
#pragma unroll
    for (int c4 = 0; c4 < 4; ++c4) {
        float4 hv = ((const float4*)Hc)[c4];
        rv[c4 * 4 + 0] = fmaxf(acc[c4 * 4 + 0], 0.f) + hv.x;
        rv[c4 * 4 + 1] = fmaxf(acc[c4 * 4 + 1], 0.f) + hv.y;
        rv[c4 * 4 + 2] = fmaxf(acc[c4 * 4 + 2], 0.f) + hv.z;
        rv[c4 * 4 + 3] = fmaxf(acc[c4 * 4 + 3], 0.f) + hv.w;
    }
    float* O = hout + (size_t)n * 32 + co;
#pragma unroll
    for (int c4 = 0; c4 < 4; ++c4)
        ((float4*)O)[c4] = make_float4(rv[c4 * 4 + 0], rv[c4 * 4 + 1],
                                       rv[c4 * 4 + 2], rv[c4 * 4 + 3]);
    __half2 hp[8];
#pragma unroll
    for (int i = 0; i < 8; ++i) hp[i] = __float22half2_rn(make_float2(rv[2 * i], rv[2 * i + 1]));
    uint4* D = (uint4*)(h16 + (size_t)n * 32 + co);
    const uint4* S = (const uint4*)hp;
#pragma unroll
    for (int i = 0; i < 2; ++i) D[i] = S[i];
}

// 4-way wave split: wave&3 selects 16-channel output slice of 64. acc[16].
__global__ __launch_bounds__(256) void k_gemm_last(
    const float* __restrict__ agg, const float* __restrict__ hin,
    const float* __restrict__ Wt, const float* __restrict__ Wi, const float* __restrict__ Wr,
    const float* __restrict__ b, const float* __restrict__ proj, float* __restrict__ out, int N) {
    int tid = blockIdx.x * blockDim.x + threadIdx.x;
    int lane = tid & 63;
    int w = tid >> 6;
    int n = ((w >> 2) << 6) + lane;
    if (n >= N) return;
    int co = __builtin_amdgcn_readfirstlane((w & 3) << 4);
    float acc[16];
#pragma unroll
    for (int c = 0; c < 16; ++c) acc[c] = b[co + c];
    const float* Ai = agg + (size_t)n * 64;
    const float* At = Ai + 32;
    const float* H = hin + (size_t)n * 32;
    gemm_seg2<16, 64>(At, Wt + co, acc);
    gemm_seg2<16, 64>(Ai, Wi + co, acc);
    gemm_seg2<16, 64>(H, Wr + co, acc);
#pragma unroll
    for (int c = 0; c < 16; ++c) acc[c] = fmaxf(acc[c], 0.f);
    gemm_seg2<16, 64>(H, proj + co, acc);
    float* O = out + (size_t)n * 64 + co;
#pragma unroll
    for (int c4 = 0; c4 < 4; ++c4)
        ((float4*)O)[c4] = make_float4(acc[c4 * 4 + 0], acc[c4 * 4 + 1],
                                       acc[c4 * 4 + 2], acc[c4 * 4 + 3]);
}

// ---------------- launch ----------------

static inline size_t align256(size_t x) { return (x + 255) & ~(size_t)255; }

extern "C" void kernel_launch(void* const* d_in, const int* in_sizes, int n_in,
                              void* d_out, int out_size, void* d_ws, size_t ws_size,
                              hipStream_t stream) {
    const float* x_stroke = (const float*)d_in[0];
    const int* ei_temp = (const int*)d_in[1];
    const int* ei_inter = (const int*)d_in[2];
    const float* head_Wt = (const float*)d_in[3];
    const float* head_Wi = (const float*)d_in[4];
    const float* head_Wr = (const float*)d_in[5];
    const float* head_b = (const float*)d_in[6];
    const float* blk_Wt = (const float*)d_in[7];
    const float* blk_Wi = (const float*)d_in[8];
    const float* blk_Wr = (const float*)d_in[9];
    const float* blk_b = (const float*)d_in[10];
    const float* last_Wt = (const float*)d_in[11];
    const float* last_Wi = (const float*)d_in[12];
    const float* last_Wr = (const float*)d_in[13];
    const float* last_b = (const float*)d_in[14];
    const float* last_proj = (const float*)d_in[15];

    const int N = in_sizes[0] / 6;
    const int Et = in_sizes[1] / 2;
    const int Ei = in_sizes[2] / 2;

    const int* temp_src = ei_temp;
    const int* temp_dst = ei_temp + Et;
    const int* int_src = ei_inter;
    const int* int_dst = ei_inter + Ei;

    const int shift = 7;                      // 128-node buckets
    const int NB = ((N - 1) >> shift) + 1;    // assumes N <= 131072

    char* p = (char*)d_ws;
    size_t off = 0;
    auto carve = [&](size_t bytes) {
        char* r = p + off;
        off = align256(off + bytes);
        return r;
    };
    // zero-init block: cnt_t, ovfn, gh contiguous -> ONE memset
    int* cnt_t = (int*)carve((size_t)N * 4);
    int* ovfn = (int*)carve(2 * 4);
    int* gh = (int*)carve((size_t)NB * 4);
    size_t zspan = (size_t)((char*)gh + (size_t)NB * 4 - (char*)cnt_t);
    int* ovf_t = (int*)carve((size_t)VO * 8);
    int* boff = (int*)carve((size_t)(NB + 1) * 4);
    int* cur = (int*)carve((size_t)NB * 4);
    int* rs = (int*)carve((size_t)(N + 1) * 4);
    float* x8 = (float*)carve((size_t)N * 8 * 4);
    float* bufA = (float*)carve((size_t)N * 32 * 4);
    float* bufD = (float*)carve((size_t)N * 32 * 4);
    float* agg = (float*)carve((size_t)N * 64 * 4);   // also holds agg8 [N,16]
    __half* h16 = (__half*)carve((size_t)N * 32 * 2); // fp16 gather staging
    int* ebuf = (int*)carve((size_t)Ei * 4);          // packed (src<<7 | dst&127)
    int* csr_i = (int*)carve((size_t)Ei * 4);         // dense
    const int Ct = 16;
    int* csr_t = (int*)carve((size_t)N * Ct * 4);
    (void)ws_size;

    const int B = 256;
    auto blocks = [&](long long work) { return (int)((work + B - 1) / B); };

    hipMemsetAsync(cnt_t, 0, zspan, stream);

    k_hist<<<256, B, 0, stream>>>(int_dst, Ei, gh, NB, shift);
    k_scan_b<<<1, 1024, 0, stream>>>(gh, NB, boff, cur);
    k_scatter<<<(int)((Ei + SCAT_SPAN - 1) / SCAT_SPAN), SCAT_THR, 0, stream>>>(
        int_src, int_dst, Ei, shift, NB, cur, ebuf);
    k_fill3<<<NB, B, 0, stream>>>(ebuf, boff, NB, rs, csr_i, N);
    k_fill2<<<blocks(Et), B, 0, stream>>>(temp_src, temp_dst, Et, cnt_t, csr_t, Ct, ovf_t, &ovfn[1]);
    k_pad_x<<<blocks((long long)N * 8), B, 0, stream>>>(x_stroke, x8, N);

    // wave-split GEMM grids
    const int gw2 = 2 * ((N + 63) >> 6);              // 2 waves per 64 nodes
    const int gblocks2 = ((gw2 << 6) + B - 1) / B;
    const int gw4 = 4 * ((N + 63) >> 6);              // 4 waves per 64 nodes
    const int gblocks4 = ((gw4 << 6) + B - 1) / B;
    // group-per-node gather grid: 8 nodes per wave
    const int gatherW = (N + 7) >> 3;
    const int gatherBlocks = (int)(((long long)gatherW * 64 + B - 1) / B);

    // head
    k_gather_head<<<blocks(N), B, 0, stream>>>(
        x8, csr_i, rs, csr_t, cnt_t, Ct, ovf_t, ovfn, agg, N);
    k_gemm_head<<<gblocks2, B, 0, stream>>>(agg, x8, head_Wt, head_Wi, head_Wr, head_b,
                                            bufA, h16, N);

    // 3 hidden residual blocks
    float* hin = bufA;
    float* hout = bufD;
    for (int i = 0; i < 3; ++i) {
        k_gather32<<<gatherBlocks, B, 0, stream>>>(
            h16, hin, csr_i, rs, csr_t, cnt_t, Ct, ovf_t, ovfn, agg, N);
        k_gemm_blk<<<gblocks2, B, 0, stream>>>(
            agg, hin, blk_Wt + (size_t)i * 32 * 32, blk_Wi + (size_t)i * 32 * 32,
            blk_Wr + (size_t)i * 32 * 32, blk_b + (size_t)i * 32, hout, h16, N);
        float* t = hin; hin = hout; hout = t;
    }

    // last
    k_gather32<<<gatherBlocks, B, 0, stream>>>(
        h16, hin, csr_i, rs, csr_t, cnt_t, Ct, ovf_t, ovfn, agg, N);
    k_gemm_last<<<gblocks4, B, 0, stream>>>(agg, hin, last_Wt, last_Wi, last_Wr, last_b,
                                            last_proj, (float*)d_out, N);
}